// Round 1
// baseline (7911.016 us; speedup 1.0000x reference)
//
#include <hip/hip_runtime.h>
#include <stdint.h>

#define NUSERS  200000
#define NITEMS  100000
#define NTOT    300000
#define DIM     64
#define NNZC    3000000
#define BATCH   4096
#define B64     (BATCH * DIM)
#define EPSP    0.1f
#define INV_TEMP 5.0f   // 1 / 0.2

// ---------------- Threefry-2x32 (JAX-compatible) ----------------
__device__ __forceinline__ uint32_t rotl32(uint32_t v, int r) {
  return (v << r) | (v >> (32 - r));
}

__device__ __forceinline__ void tf2x32(uint32_t k0, uint32_t k1,
                                       uint32_t x0, uint32_t x1,
                                       uint32_t &o0, uint32_t &o1) {
  uint32_t k2 = k0 ^ k1 ^ 0x1BD11BDAu;
#define TFR(r) { x0 += x1; x1 = rotl32(x1, (r)); x1 ^= x0; }
  x0 += k0; x1 += k1;
  TFR(13) TFR(15) TFR(26) TFR(6)
  x0 += k1; x1 += k2 + 1u;
  TFR(17) TFR(29) TFR(16) TFR(24)
  x0 += k2; x1 += k0 + 2u;
  TFR(13) TFR(15) TFR(26) TFR(6)
  x0 += k0; x1 += k1 + 3u;
  TFR(17) TFR(29) TFR(16) TFR(24)
  x0 += k1; x1 += k2 + 4u;
  TFR(13) TFR(15) TFR(26) TFR(6)
  x0 += k2; x1 += k0 + 5u;
#undef TFR
  o0 = x0; o1 = x1;
}

// ---------------- SpMM: wave-per-nnz atomic scatter ----------------
__global__ void spmm_scatter(const float* __restrict__ vals,
                             const int* __restrict__ rows,
                             const int* __restrict__ cols,
                             const float* __restrict__ x,
                             float* __restrict__ y) {
  int gid  = blockIdx.x * blockDim.x + threadIdx.x;
  int w    = gid >> 6;
  int lane = gid & 63;
  if (w >= NNZC) return;
  int r = rows[w], c = cols[w];
  float v = vals[w];
  atomicAdd(&y[(size_t)r * DIM + lane], v * x[(size_t)c * DIM + lane]);
}

// ---------------- SimGCL perturbation (exact JAX threefry noise) ----------------
__global__ void perturb_kernel(float* __restrict__ ego, uint32_t seed, uint32_t hop) {
  int gid = blockIdx.x * blockDim.x + threadIdx.x;   // == row*64 + lane
  if (gid >= NTOT * DIM) return;
  // fold_in(key(seed), hop): threefry2x32 with key (0,seed), count (0,hop)
  uint32_t k0, k1;
  tf2x32(0u, seed, 0u, hop, k0, k1);
  // partitionable random_bits: element e -> threefry2x32(key, hi32(e)=0, lo32(e)=e), bits = o0^o1
  uint32_t b0, b1;
  tf2x32(k0, k1, 0u, (uint32_t)gid, b0, b1);
  uint32_t bits = b0 ^ b1;
  float u = __uint_as_float((bits >> 9) | 0x3F800000u) - 1.0f;  // U[0,1)
  float ss = u * u;
  #pragma unroll
  for (int m = 32; m; m >>= 1) ss += __shfl_xor(ss, m);
  float scale = EPSP / fmaxf(sqrtf(ss), 1e-12f);
  float xv = ego[gid];
  float s = (xv > 0.0f) ? 1.0f : ((xv < 0.0f) ? -1.0f : 0.0f);
  ego[gid] = xv + s * u * scale;
}

// ---------------- gather-accumulate selected rows ----------------
__global__ void gather_add(const float* __restrict__ src,
                           const int* __restrict__ idx,
                           int base, float* __restrict__ dst) {
  int gid = blockIdx.x * blockDim.x + threadIdx.x;
  int b = gid >> 6, d = gid & 63;
  if (b >= BATCH) return;
  int r = base + idx[b];
  dst[gid] += src[(size_t)r * DIM + d];
}

// ---------------- row-normalize (clamp 1e-12) ----------------
__global__ void rownorm_kernel(float* __restrict__ v) {
  int gid = blockIdx.x * blockDim.x + threadIdx.x;
  if ((gid >> 6) >= BATCH) return;
  float x = v[gid];
  float ss = x * x;
  #pragma unroll
  for (int m = 32; m; m >>= 1) ss += __shfl_xor(ss, m);
  v[gid] = x / fmaxf(sqrtf(ss), 1e-12f);
}

// ---------------- InfoNCE: one wave per row i ----------------
__global__ void infonce_kernel(const float* __restrict__ v1,
                               const float* __restrict__ v2,
                               float* __restrict__ acc) {
  __shared__ float v1s[DIM];
  int i = blockIdx.x;
  int t = threadIdx.x;          // blockDim = 64
  v1s[t] = v1[(size_t)i * DIM + t];
  __syncthreads();
  float ttl = 0.0f, pos = 0.0f;
  for (int j = t; j < BATCH; j += 64) {
    const float* row = v2 + (size_t)j * DIM;
    float dot = 0.0f;
    #pragma unroll
    for (int d = 0; d < DIM; ++d) dot += v1s[d] * row[d];
    ttl += expf(dot * INV_TEMP);
    if (j == i) pos = dot;
  }
  #pragma unroll
  for (int m = 32; m; m >>= 1) { ttl += __shfl_xor(ttl, m); pos += __shfl_xor(pos, m); }
  if (t == 0) atomicAdd(acc, -logf(expf(pos * INV_TEMP) / ttl + 1e-5f));
}

// ---------------- BPR rec loss + reg ----------------
__global__ void rec_kernel(const float* __restrict__ ue, const float* __restrict__ pe,
                           const float* __restrict__ ne, float* __restrict__ acc) {
  int gid = blockIdx.x * blockDim.x + threadIdx.x;
  if ((gid >> 6) >= BATCH) return;
  const float third = 1.0f / 3.0f;
  float u = ue[gid] * third, p = pe[gid] * third, n = ne[gid] * third;
  float ps = u * p, ns = u * n, su = u * u, sp = p * p;
  #pragma unroll
  for (int m = 32; m; m >>= 1) {
    ps += __shfl_xor(ps, m); ns += __shfl_xor(ns, m);
    su += __shfl_xor(su, m); sp += __shfl_xor(sp, m);
  }
  if ((gid & 63) == 0) {
    float sig = 1.0f / (1.0f + expf(-(ps - ns)));
    atomicAdd(acc + 0, -logf(1e-5f + sig));
    atomicAdd(acc + 1, su);
    atomicAdd(acc + 2, sp);
  }
}

__global__ void finalize_kernel(const float* __restrict__ acc, float* __restrict__ out) {
  out[0] = acc[0] * (1.0f / BATCH)
         + 1e-4f * (sqrtf(acc[1]) + sqrtf(acc[2]))
         + 0.5f * (acc[3] + acc[4]) * (1.0f / BATCH);
}

extern "C" void kernel_launch(void* const* d_in, const int* in_sizes, int n_in,
                              void* d_out, int out_size, void* d_ws, size_t ws_size,
                              hipStream_t stream) {
  (void)in_sizes; (void)n_in; (void)out_size; (void)ws_size;
  const float* user_embed = (const float*)d_in[0];
  const float* item_embed = (const float*)d_in[1];
  const float* adj_vals   = (const float*)d_in[2];
  const int*   adj_rows   = (const int*)d_in[3];
  const int*   adj_cols   = (const int*)d_in[4];
  const int*   users      = (const int*)d_in[5];
  const int*   pos_items  = (const int*)d_in[6];
  const int*   neg_items  = (const int*)d_in[7];
  float* out = (float*)d_out;

  // workspace layout: two full ping-pong buffers + 7 gathered [4096x64] + 8 scalars
  float* bufA = (float*)d_ws;
  float* bufB = bufA + (size_t)NTOT * DIM;
  float* g    = bufB + (size_t)NTOT * DIM;
  float* g_ue = g + 0 * B64;
  float* g_pe = g + 1 * B64;
  float* g_ne = g + 2 * B64;
  float* g_u1 = g + 3 * B64;
  float* g_i1 = g + 4 * B64;
  float* g_u2 = g + 5 * B64;
  float* g_i2 = g + 6 * B64;
  float* acc  = g + 7 * B64;   // [0]=rec_sum [1]=ssq_ue [2]=ssq_pe [3]=nce_u [4]=nce_i

  hipMemsetAsync(g, 0, ((size_t)7 * B64 + 8) * sizeof(float), stream);

  const int spmm_blocks = (NNZC * 64) / 256;   // 750000
  const int pert_blocks = (NTOT * 64) / 256;   // 75000
  const int gat_blocks  = (BATCH * 64) / 256;  // 1024

  for (int p = 0; p < 3; ++p) {
    // ego0 = concat(user_embed, item_embed)
    hipMemcpyAsync(bufA, user_embed, (size_t)NUSERS * DIM * sizeof(float),
                   hipMemcpyDeviceToDevice, stream);
    hipMemcpyAsync(bufA + (size_t)NUSERS * DIM, item_embed,
                   (size_t)NITEMS * DIM * sizeof(float),
                   hipMemcpyDeviceToDevice, stream);
    float* cur = bufA;
    float* nxt = bufB;
    uint32_t seed = (p == 1) ? 101u : 202u;
    for (uint32_t h = 0; h < 3; ++h) {
      hipMemsetAsync(nxt, 0, (size_t)NTOT * DIM * sizeof(float), stream);
      spmm_scatter<<<spmm_blocks, 256, 0, stream>>>(adj_vals, adj_rows, adj_cols, cur, nxt);
      if (p > 0)
        perturb_kernel<<<pert_blocks, 256, 0, stream>>>(nxt, seed, h);
      if (p == 0) {
        gather_add<<<gat_blocks, 256, 0, stream>>>(nxt, users, 0, g_ue);
        gather_add<<<gat_blocks, 256, 0, stream>>>(nxt, pos_items, NUSERS, g_pe);
        gather_add<<<gat_blocks, 256, 0, stream>>>(nxt, neg_items, NUSERS, g_ne);
      } else if (p == 1) {
        gather_add<<<gat_blocks, 256, 0, stream>>>(nxt, users, 0, g_u1);
        gather_add<<<gat_blocks, 256, 0, stream>>>(nxt, pos_items, NUSERS, g_i1);
      } else {
        gather_add<<<gat_blocks, 256, 0, stream>>>(nxt, users, 0, g_u2);
        gather_add<<<gat_blocks, 256, 0, stream>>>(nxt, pos_items, NUSERS, g_i2);
      }
      float* t = cur; cur = nxt; nxt = t;
    }
  }

  rec_kernel<<<gat_blocks, 256, 0, stream>>>(g_ue, g_pe, g_ne, acc);
  rownorm_kernel<<<gat_blocks, 256, 0, stream>>>(g_u1);
  rownorm_kernel<<<gat_blocks, 256, 0, stream>>>(g_u2);
  rownorm_kernel<<<gat_blocks, 256, 0, stream>>>(g_i1);
  rownorm_kernel<<<gat_blocks, 256, 0, stream>>>(g_i2);
  infonce_kernel<<<BATCH, 64, 0, stream>>>(g_u1, g_u2, acc + 3);
  infonce_kernel<<<BATCH, 64, 0, stream>>>(g_i1, g_i2, acc + 4);
  finalize_kernel<<<1, 1, 0, stream>>>(acc, out);
}

// Round 2
// 4780.272 us; speedup vs baseline: 1.6549x; 1.6549x over previous
//
#include <hip/hip_runtime.h>
#include <stdint.h>

#define NUSERS  200000
#define NITEMS  100000
#define NTOT    300000
#define DIM     64
#define NNZC    3000000
#define BATCH   4096
#define B64     (BATCH * DIM)
#define EPSP    0.1f
#define INV_TEMP 5.0f   // 1 / 0.2
#define SCAN_ELEMS 1024
#define NSCAN_BLOCKS ((NTOT + SCAN_ELEMS - 1) / SCAN_ELEMS)   // 293

// ---------------- Threefry-2x32 (JAX-compatible) ----------------
__device__ __forceinline__ uint32_t rotl32(uint32_t v, int r) {
  return (v << r) | (v >> (32 - r));
}

__device__ __forceinline__ void tf2x32(uint32_t k0, uint32_t k1,
                                       uint32_t x0, uint32_t x1,
                                       uint32_t &o0, uint32_t &o1) {
  uint32_t k2 = k0 ^ k1 ^ 0x1BD11BDAu;
#define TFR(r) { x0 += x1; x1 = rotl32(x1, (r)); x1 ^= x0; }
  x0 += k0; x1 += k1;
  TFR(13) TFR(15) TFR(26) TFR(6)
  x0 += k1; x1 += k2 + 1u;
  TFR(17) TFR(29) TFR(16) TFR(24)
  x0 += k2; x1 += k0 + 2u;
  TFR(13) TFR(15) TFR(26) TFR(6)
  x0 += k0; x1 += k1 + 3u;
  TFR(17) TFR(29) TFR(16) TFR(24)
  x0 += k1; x1 += k2 + 4u;
  TFR(13) TFR(15) TFR(26) TFR(6)
  x0 += k2; x1 += k0 + 5u;
#undef TFR
  o0 = x0; o1 = x1;
}

// ---------------- CSR build ----------------
__global__ void hist_kernel(const int* __restrict__ rows, int* __restrict__ cnt) {
  int i = blockIdx.x * blockDim.x + threadIdx.x;
  if (i < NNZC) atomicAdd(&cnt[rows[i]], 1);
}

// per-block exclusive scan of 1024 counts; block total -> bsums
__global__ void scan_block(const int* __restrict__ cnt, int* __restrict__ rs,
                           int* __restrict__ bsums) {
  __shared__ int tmp[SCAN_ELEMS];
  int base = blockIdx.x * SCAN_ELEMS;
  int t = threadIdx.x;                 // 256 threads
  #pragma unroll
  for (int q = 0; q < 4; ++q) {
    int k = t + q * 256, i = base + k;
    tmp[k] = (i < NTOT) ? cnt[i] : 0;
  }
  __syncthreads();
  for (int off = 1; off < SCAN_ELEMS; off <<= 1) {
    int v[4];
    #pragma unroll
    for (int q = 0; q < 4; ++q) {
      int k = t + q * 256;
      v[q] = (k >= off) ? tmp[k - off] : 0;
    }
    __syncthreads();
    #pragma unroll
    for (int q = 0; q < 4; ++q) tmp[t + q * 256] += v[q];
    __syncthreads();
  }
  #pragma unroll
  for (int q = 0; q < 4; ++q) {
    int k = t + q * 256, i = base + k;
    if (i < NTOT) rs[i] = (k == 0) ? 0 : tmp[k - 1];   // exclusive within block
  }
  if (t == 0) bsums[blockIdx.x] = tmp[SCAN_ELEMS - 1];
}

// single-block exclusive scan of block sums (nb <= 512)
__global__ void scan_sums(int* __restrict__ bsums, int nb) {
  __shared__ int tmp[512];
  int t = threadIdx.x;
  tmp[t] = (t < nb) ? bsums[t] : 0;
  __syncthreads();
  for (int off = 1; off < 512; off <<= 1) {
    int v = (t >= off) ? tmp[t - off] : 0;
    __syncthreads();
    tmp[t] += v;
    __syncthreads();
  }
  if (t < nb) bsums[t] = (t == 0) ? 0 : tmp[t - 1];
}

__global__ void add_offsets(int* __restrict__ rs, const int* __restrict__ bsums) {
  int i = blockIdx.x * blockDim.x + threadIdx.x;
  if (i < NTOT) rs[i] += bsums[i / SCAN_ELEMS];
  if (i == 0) rs[NTOT] = NNZC;
}

__global__ void scatter_csr(const float* __restrict__ vals,
                            const int* __restrict__ rows,
                            const int* __restrict__ cols,
                            int* __restrict__ cursor,
                            float* __restrict__ svals,
                            int* __restrict__ scols) {
  int i = blockIdx.x * blockDim.x + threadIdx.x;
  if (i >= NNZC) return;
  int r = rows[i];
  int pos = atomicAdd(&cursor[r], 1);
  svals[pos] = vals[i];
  scols[pos] = cols[i];
}

// ---------------- CSR SpMM, wave per row, fused perturbation ----------------
// x addr: c < NUSERS -> xa + c*DIM ; else xb + (c-NUSERS)*DIM
template <bool PERT>
__global__ void spmm_csr(const float* __restrict__ svals,
                         const int* __restrict__ scols,
                         const int* __restrict__ rs,
                         const float* __restrict__ xa,
                         const float* __restrict__ xb,
                         float* __restrict__ y,
                         uint32_t seed, uint32_t hop) {
  int gid  = blockIdx.x * blockDim.x + threadIdx.x;
  int r    = gid >> 6;
  int lane = gid & 63;
  if (r >= NTOT) return;
  int s = rs[r], e = rs[r + 1];
  float acc = 0.0f;
  for (int j = s; j < e; ++j) {
    int c   = scols[j];
    float v = svals[j];
    const float* x = (c < NUSERS) ? (xa + (size_t)c * DIM)
                                  : (xb + (size_t)(c - NUSERS) * DIM);
    acc += v * x[lane];
  }
  if (PERT) {
    uint32_t k0, k1, b0, b1;
    tf2x32(0u, seed, 0u, hop, k0, k1);                 // fold_in(key(seed), hop)
    tf2x32(k0, k1, 0u, (uint32_t)gid, b0, b1);         // partitionable bits
    uint32_t bits = b0 ^ b1;
    float u = __uint_as_float((bits >> 9) | 0x3F800000u) - 1.0f;
    float ss = u * u;
    #pragma unroll
    for (int m = 32; m; m >>= 1) ss += __shfl_xor(ss, m);
    float scale = EPSP / fmaxf(sqrtf(ss), 1e-12f);
    float sg = (acc > 0.0f) ? 1.0f : ((acc < 0.0f) ? -1.0f : 0.0f);
    acc += sg * u * scale;
  }
  y[gid] = acc;
}

// ---------------- gather-accumulate selected rows ----------------
__global__ void gather_add(const float* __restrict__ src,
                           const int* __restrict__ idx,
                           int base, float* __restrict__ dst) {
  int gid = blockIdx.x * blockDim.x + threadIdx.x;
  int b = gid >> 6, d = gid & 63;
  if (b >= BATCH) return;
  int r = base + idx[b];
  dst[gid] += src[(size_t)r * DIM + d];
}

// ---------------- row-normalize (clamp 1e-12) ----------------
__global__ void rownorm_kernel(float* __restrict__ v) {
  int gid = blockIdx.x * blockDim.x + threadIdx.x;
  if ((gid >> 6) >= BATCH) return;
  float x = v[gid];
  float ss = x * x;
  #pragma unroll
  for (int m = 32; m; m >>= 1) ss += __shfl_xor(ss, m);
  v[gid] = x / fmaxf(sqrtf(ss), 1e-12f);
}

// ---------------- InfoNCE: one wave per row i ----------------
__global__ void infonce_kernel(const float* __restrict__ v1,
                               const float* __restrict__ v2,
                               float* __restrict__ acc) {
  __shared__ float v1s[DIM];
  int i = blockIdx.x;
  int t = threadIdx.x;          // blockDim = 64
  v1s[t] = v1[(size_t)i * DIM + t];
  __syncthreads();
  float ttl = 0.0f, pos = 0.0f;
  for (int j = t; j < BATCH; j += 64) {
    const float* row = v2 + (size_t)j * DIM;
    float dot = 0.0f;
    #pragma unroll
    for (int d = 0; d < DIM; ++d) dot += v1s[d] * row[d];
    ttl += expf(dot * INV_TEMP);
    if (j == i) pos = dot;
  }
  #pragma unroll
  for (int m = 32; m; m >>= 1) { ttl += __shfl_xor(ttl, m); pos += __shfl_xor(pos, m); }
  if (t == 0) atomicAdd(acc, -logf(expf(pos * INV_TEMP) / ttl + 1e-5f));
}

// ---------------- BPR rec loss + reg ----------------
__global__ void rec_kernel(const float* __restrict__ ue, const float* __restrict__ pe,
                           const float* __restrict__ ne, float* __restrict__ acc) {
  int gid = blockIdx.x * blockDim.x + threadIdx.x;
  if ((gid >> 6) >= BATCH) return;
  const float third = 1.0f / 3.0f;
  float u = ue[gid] * third, p = pe[gid] * third, n = ne[gid] * third;
  float ps = u * p, ns = u * n, su = u * u, sp = p * p;
  #pragma unroll
  for (int m = 32; m; m >>= 1) {
    ps += __shfl_xor(ps, m); ns += __shfl_xor(ns, m);
    su += __shfl_xor(su, m); sp += __shfl_xor(sp, m);
  }
  if ((gid & 63) == 0) {
    float sig = 1.0f / (1.0f + expf(-(ps - ns)));
    atomicAdd(acc + 0, -logf(1e-5f + sig));
    atomicAdd(acc + 1, su);
    atomicAdd(acc + 2, sp);
  }
}

__global__ void finalize_kernel(const float* __restrict__ acc, float* __restrict__ out) {
  out[0] = acc[0] * (1.0f / BATCH)
         + 1e-4f * (sqrtf(acc[1]) + sqrtf(acc[2]))
         + 0.5f * (acc[3] + acc[4]) * (1.0f / BATCH);
}

extern "C" void kernel_launch(void* const* d_in, const int* in_sizes, int n_in,
                              void* d_out, int out_size, void* d_ws, size_t ws_size,
                              hipStream_t stream) {
  (void)in_sizes; (void)n_in; (void)out_size; (void)ws_size;
  const float* user_embed = (const float*)d_in[0];
  const float* item_embed = (const float*)d_in[1];
  const float* adj_vals   = (const float*)d_in[2];
  const int*   adj_rows   = (const int*)d_in[3];
  const int*   adj_cols   = (const int*)d_in[4];
  const int*   users      = (const int*)d_in[5];
  const int*   pos_items  = (const int*)d_in[6];
  const int*   neg_items  = (const int*)d_in[7];
  float* out = (float*)d_out;

  // ---- workspace layout (all 4B elems) ----
  float* bufA  = (float*)d_ws;                         // NTOT*DIM
  float* bufB  = bufA + (size_t)NTOT * DIM;            // NTOT*DIM
  float* svals = bufB + (size_t)NTOT * DIM;            // NNZC
  int*   scols = (int*)(svals + NNZC);                 // NNZC
  int*   rs    = scols + NNZC;                         // NTOT+1
  int*   cursor= rs + (NTOT + 1);                      // NTOT
  int*   bsums = cursor + NTOT;                        // 512
  float* g     = (float*)(bsums + 512);                // 7*B64 + 8
  float* g_ue = g + 0 * B64;
  float* g_pe = g + 1 * B64;
  float* g_ne = g + 2 * B64;
  float* g_u1 = g + 3 * B64;
  float* g_i1 = g + 4 * B64;
  float* g_u2 = g + 5 * B64;
  float* g_i2 = g + 6 * B64;
  float* acc  = g + 7 * B64;   // [0]=rec [1]=ssq_ue [2]=ssq_pe [3]=nce_u [4]=nce_i

  hipMemsetAsync(g, 0, ((size_t)7 * B64 + 8) * sizeof(float), stream);
  hipMemsetAsync(cursor, 0, (size_t)NTOT * sizeof(int), stream);

  // ---- CSR build (amortized over 9 SpMMs) ----
  const int nnz_blocks = (NNZC + 255) / 256;
  hist_kernel<<<nnz_blocks, 256, 0, stream>>>(adj_rows, cursor);
  scan_block<<<NSCAN_BLOCKS, 256, 0, stream>>>(cursor, rs, bsums);
  scan_sums<<<1, 512, 0, stream>>>(bsums, NSCAN_BLOCKS);
  add_offsets<<<(NTOT + 255) / 256, 256, 0, stream>>>(rs, bsums);
  hipMemcpyAsync(cursor, rs, (size_t)NTOT * sizeof(int),
                 hipMemcpyDeviceToDevice, stream);
  scatter_csr<<<nnz_blocks, 256, 0, stream>>>(adj_vals, adj_rows, adj_cols,
                                              cursor, svals, scols);

  const int spmm_blocks = (NTOT * 64) / 256;   // 75000
  const int gat_blocks  = (BATCH * 64) / 256;  // 1024

  for (int p = 0; p < 3; ++p) {
    float* cur = bufA;
    float* nxt = bufB;
    uint32_t seed = (p == 1) ? 101u : 202u;
    for (uint32_t h = 0; h < 3; ++h) {
      // hop 0 reads the virtual concat(user_embed, item_embed) directly
      const float* xa = (h == 0) ? user_embed : cur;
      const float* xb = (h == 0) ? item_embed : (cur + (size_t)NUSERS * DIM);
      if (p == 0)
        spmm_csr<false><<<spmm_blocks, 256, 0, stream>>>(svals, scols, rs, xa, xb,
                                                         nxt, 0u, h);
      else
        spmm_csr<true><<<spmm_blocks, 256, 0, stream>>>(svals, scols, rs, xa, xb,
                                                        nxt, seed, h);
      if (p == 0) {
        gather_add<<<gat_blocks, 256, 0, stream>>>(nxt, users, 0, g_ue);
        gather_add<<<gat_blocks, 256, 0, stream>>>(nxt, pos_items, NUSERS, g_pe);
        gather_add<<<gat_blocks, 256, 0, stream>>>(nxt, neg_items, NUSERS, g_ne);
      } else if (p == 1) {
        gather_add<<<gat_blocks, 256, 0, stream>>>(nxt, users, 0, g_u1);
        gather_add<<<gat_blocks, 256, 0, stream>>>(nxt, pos_items, NUSERS, g_i1);
      } else {
        gather_add<<<gat_blocks, 256, 0, stream>>>(nxt, users, 0, g_u2);
        gather_add<<<gat_blocks, 256, 0, stream>>>(nxt, pos_items, NUSERS, g_i2);
      }
      float* t = cur; cur = nxt; nxt = t;
    }
  }

  rec_kernel<<<gat_blocks, 256, 0, stream>>>(g_ue, g_pe, g_ne, acc);
  rownorm_kernel<<<gat_blocks, 256, 0, stream>>>(g_u1);
  rownorm_kernel<<<gat_blocks, 256, 0, stream>>>(g_u2);
  rownorm_kernel<<<gat_blocks, 256, 0, stream>>>(g_i1);
  rownorm_kernel<<<gat_blocks, 256, 0, stream>>>(g_i2);
  infonce_kernel<<<BATCH, 64, 0, stream>>>(g_u1, g_u2, acc + 3);
  infonce_kernel<<<BATCH, 64, 0, stream>>>(g_i1, g_i2, acc + 4);
  finalize_kernel<<<1, 1, 0, stream>>>(acc, out);
}

// Round 3
// 2629.837 us; speedup vs baseline: 3.0082x; 1.8177x over previous
//
#include <hip/hip_runtime.h>
#include <stdint.h>

#define NUSERS  200000
#define NITEMS  100000
#define NTOT    300000
#define DIM     64
#define NNZC    3000000
#define BATCH   4096
#define B64     (BATCH * DIM)
#define EPSP    0.1f
#define INV_TEMP 5.0f   // 1 / 0.2
#define SCAN_ELEMS 1024
#define NSCAN_BLOCKS ((NTOT + SCAN_ELEMS - 1) / SCAN_ELEMS)   // 293
#define IB 64
#define JB 128
#define LDA 65

// ---------------- Threefry-2x32 (JAX-compatible) ----------------
__device__ __forceinline__ uint32_t rotl32(uint32_t v, int r) {
  return (v << r) | (v >> (32 - r));
}

__device__ __forceinline__ void tf2x32(uint32_t k0, uint32_t k1,
                                       uint32_t x0, uint32_t x1,
                                       uint32_t &o0, uint32_t &o1) {
  uint32_t k2 = k0 ^ k1 ^ 0x1BD11BDAu;
#define TFR(r) { x0 += x1; x1 = rotl32(x1, (r)); x1 ^= x0; }
  x0 += k0; x1 += k1;
  TFR(13) TFR(15) TFR(26) TFR(6)
  x0 += k1; x1 += k2 + 1u;
  TFR(17) TFR(29) TFR(16) TFR(24)
  x0 += k2; x1 += k0 + 2u;
  TFR(13) TFR(15) TFR(26) TFR(6)
  x0 += k0; x1 += k1 + 3u;
  TFR(17) TFR(29) TFR(16) TFR(24)
  x0 += k1; x1 += k2 + 4u;
  TFR(13) TFR(15) TFR(26) TFR(6)
  x0 += k2; x1 += k0 + 5u;
#undef TFR
  o0 = x0; o1 = x1;
}

// ---------------- CSR build ----------------
__global__ void hist_kernel(const int* __restrict__ rows, int* __restrict__ cnt) {
  int i = blockIdx.x * blockDim.x + threadIdx.x;
  if (i < NNZC) atomicAdd(&cnt[rows[i]], 1);
}

__global__ void scan_block(const int* __restrict__ cnt, int* __restrict__ rs,
                           int* __restrict__ bsums) {
  __shared__ int tmp[SCAN_ELEMS];
  int base = blockIdx.x * SCAN_ELEMS;
  int t = threadIdx.x;                 // 256 threads
  #pragma unroll
  for (int q = 0; q < 4; ++q) {
    int k = t + q * 256, i = base + k;
    tmp[k] = (i < NTOT) ? cnt[i] : 0;
  }
  __syncthreads();
  for (int off = 1; off < SCAN_ELEMS; off <<= 1) {
    int v[4];
    #pragma unroll
    for (int q = 0; q < 4; ++q) {
      int k = t + q * 256;
      v[q] = (k >= off) ? tmp[k - off] : 0;
    }
    __syncthreads();
    #pragma unroll
    for (int q = 0; q < 4; ++q) tmp[t + q * 256] += v[q];
    __syncthreads();
  }
  #pragma unroll
  for (int q = 0; q < 4; ++q) {
    int k = t + q * 256, i = base + k;
    if (i < NTOT) rs[i] = (k == 0) ? 0 : tmp[k - 1];
  }
  if (t == 0) bsums[blockIdx.x] = tmp[SCAN_ELEMS - 1];
}

__global__ void scan_sums(int* __restrict__ bsums, int nb) {
  __shared__ int tmp[512];
  int t = threadIdx.x;
  tmp[t] = (t < nb) ? bsums[t] : 0;
  __syncthreads();
  for (int off = 1; off < 512; off <<= 1) {
    int v = (t >= off) ? tmp[t - off] : 0;
    __syncthreads();
    tmp[t] += v;
    __syncthreads();
  }
  if (t < nb) bsums[t] = (t == 0) ? 0 : tmp[t - 1];
}

__global__ void add_offsets(int* __restrict__ rs, const int* __restrict__ bsums) {
  int i = blockIdx.x * blockDim.x + threadIdx.x;
  if (i < NTOT) rs[i] += bsums[i / SCAN_ELEMS];
  if (i == 0) rs[NTOT] = NNZC;
}

__global__ void scatter_csr(const float* __restrict__ vals,
                            const int* __restrict__ rows,
                            const int* __restrict__ cols,
                            int* __restrict__ cursor,
                            float* __restrict__ svals,
                            int* __restrict__ scols) {
  int i = blockIdx.x * blockDim.x + threadIdx.x;
  if (i >= NNZC) return;
  int r = rows[i];
  int pos = atomicAdd(&cursor[r], 1);
  svals[pos] = vals[i];
  scols[pos] = cols[i];
}

// ---------------- CSR SpMM, wave per row, 4x MLP unroll, fused perturbation ----
template <bool PERT>
__global__ void spmm_csr(const float* __restrict__ svals,
                         const int* __restrict__ scols,
                         const int* __restrict__ rs,
                         const float* __restrict__ xa,
                         const float* __restrict__ xb,
                         float* __restrict__ y,
                         uint32_t seed, uint32_t hop) {
  int gid  = blockIdx.x * blockDim.x + threadIdx.x;
  int r    = gid >> 6;
  int lane = gid & 63;
  if (r >= NTOT) return;
  int s = rs[r], e = rs[r + 1];
  float acc = 0.0f;
  int j = s;
#define XPTR(c) ((c) < NUSERS ? xa + (size_t)(c) * DIM : xb + (size_t)((c) - NUSERS) * DIM)
  for (; j + 4 <= e; j += 4) {
    int c0 = scols[j], c1 = scols[j + 1], c2 = scols[j + 2], c3 = scols[j + 3];
    float v0 = svals[j], v1 = svals[j + 1], v2 = svals[j + 2], v3 = svals[j + 3];
    float f0 = XPTR(c0)[lane];
    float f1 = XPTR(c1)[lane];
    float f2 = XPTR(c2)[lane];
    float f3 = XPTR(c3)[lane];
    acc = fmaf(v0, f0, acc); acc = fmaf(v1, f1, acc);
    acc = fmaf(v2, f2, acc); acc = fmaf(v3, f3, acc);
  }
  for (; j < e; ++j) {
    int c = scols[j];
    acc = fmaf(svals[j], XPTR(c)[lane], acc);
  }
#undef XPTR
  if (PERT) {
    uint32_t k0, k1, b0, b1;
    tf2x32(0u, seed, 0u, hop, k0, k1);                 // fold_in(key(seed), hop)
    tf2x32(k0, k1, 0u, (uint32_t)gid, b0, b1);         // partitionable bits
    uint32_t bits = b0 ^ b1;
    float u = __uint_as_float((bits >> 9) | 0x3F800000u) - 1.0f;
    float ss = u * u;
    #pragma unroll
    for (int m = 32; m; m >>= 1) ss += __shfl_xor(ss, m);
    float scale = EPSP / fmaxf(sqrtf(ss), 1e-12f);
    float sg = (acc > 0.0f) ? 1.0f : ((acc < 0.0f) ? -1.0f : 0.0f);
    acc += sg * u * scale;
  }
  y[gid] = acc;
}

// ---------------- gather-accumulate selected rows ----------------
__global__ void gather_add(const float* __restrict__ src,
                           const int* __restrict__ idx,
                           int base, float* __restrict__ dst) {
  int gid = blockIdx.x * blockDim.x + threadIdx.x;
  int b = gid >> 6, d = gid & 63;
  if (b >= BATCH) return;
  int r = base + idx[b];
  dst[gid] += src[(size_t)r * DIM + d];
}

// ---------------- row-normalize (clamp 1e-12) ----------------
__global__ void rownorm_kernel(float* __restrict__ v) {
  int gid = blockIdx.x * blockDim.x + threadIdx.x;
  if ((gid >> 6) >= BATCH) return;
  float x = v[gid];
  float ss = x * x;
  #pragma unroll
  for (int m = 32; m; m >>= 1) ss += __shfl_xor(ss, m);
  v[gid] = x / fmaxf(sqrtf(ss), 1e-12f);
}

// ---------------- InfoNCE phase 1: tiled exp-GEMM row sums --------------------
// grid (BATCH/IB, BATCH/JB), block 256. ttl[i] += sum_j exp(5*dot(v1_i, v2_j))
__global__ __launch_bounds__(256) void nce_ttl(const float* __restrict__ v1,
                                               const float* __restrict__ v2,
                                               float* __restrict__ ttl) {
  __shared__ float s1[IB * LDA];
  __shared__ float s2[JB * LDA];
  __shared__ float tsum[IB];
  int tid = threadIdx.x;
  // stage v1 tile (64 rows x 64) via float4, scalar LDS writes (2-way max)
  const float4* v1v = (const float4*)(v1 + (size_t)blockIdx.x * IB * DIM);
  #pragma unroll
  for (int p = 0; p < 4; ++p) {
    int e = tid + p * 256;          // 0..1023
    int r = e >> 4, q = e & 15;
    float4 f = v1v[e];
    float* d = &s1[r * LDA + q * 4];
    d[0] = f.x; d[1] = f.y; d[2] = f.z; d[3] = f.w;
  }
  const float4* v2v = (const float4*)(v2 + (size_t)blockIdx.y * JB * DIM);
  #pragma unroll
  for (int p = 0; p < 8; ++p) {
    int e = tid + p * 256;          // 0..2047
    int r = e >> 4, q = e & 15;
    float4 f = v2v[e];
    float* d = &s2[r * LDA + q * 4];
    d[0] = f.x; d[1] = f.y; d[2] = f.z; d[3] = f.w;
  }
  if (tid < IB) tsum[tid] = 0.0f;
  __syncthreads();

  int i0 = (tid & 15) * 4;      // 4 i-rows
  int j0 = (tid >> 4) * 8;      // 8 j-rows
  float acc[4][8];
  #pragma unroll
  for (int m = 0; m < 4; ++m)
    #pragma unroll
    for (int n = 0; n < 8; ++n) acc[m][n] = 0.0f;
  #pragma unroll 4
  for (int k = 0; k < DIM; ++k) {
    float a[4], b[8];
    #pragma unroll
    for (int m = 0; m < 4; ++m) a[m] = s1[(i0 + m) * LDA + k];
    #pragma unroll
    for (int n = 0; n < 8; ++n) b[n] = s2[(j0 + n) * LDA + k];
    #pragma unroll
    for (int m = 0; m < 4; ++m)
      #pragma unroll
      for (int n = 0; n < 8; ++n) acc[m][n] = fmaf(a[m], b[n], acc[m][n]);
  }
  #pragma unroll
  for (int m = 0; m < 4; ++m) {
    float ts = 0.0f;
    #pragma unroll
    for (int n = 0; n < 8; ++n) ts += __expf(acc[m][n] * INV_TEMP);
    atomicAdd(&tsum[i0 + m], ts);
  }
  __syncthreads();
  if (tid < IB) atomicAdd(&ttl[blockIdx.x * IB + tid], tsum[tid]);
}

// ---------------- InfoNCE phase 2: diagonal + log --------------------
__global__ void nce_final(const float* __restrict__ v1,
                          const float* __restrict__ v2,
                          const float* __restrict__ ttl,
                          float* __restrict__ acc) {
  int gid = blockIdx.x * blockDim.x + threadIdx.x;
  int i = gid >> 6, lane = gid & 63;
  if (i >= BATCH) return;
  float p = v1[gid] * v2[gid];
  #pragma unroll
  for (int m = 32; m; m >>= 1) p += __shfl_xor(p, m);
  if (lane == 0)
    atomicAdd(acc, -logf(expf(p * INV_TEMP) / ttl[i] + 1e-5f));
}

// ---------------- BPR rec loss + reg ----------------
__global__ void rec_kernel(const float* __restrict__ ue, const float* __restrict__ pe,
                           const float* __restrict__ ne, float* __restrict__ acc) {
  int gid = blockIdx.x * blockDim.x + threadIdx.x;
  if ((gid >> 6) >= BATCH) return;
  const float third = 1.0f / 3.0f;
  float u = ue[gid] * third, p = pe[gid] * third, n = ne[gid] * third;
  float ps = u * p, ns = u * n, su = u * u, sp = p * p;
  #pragma unroll
  for (int m = 32; m; m >>= 1) {
    ps += __shfl_xor(ps, m); ns += __shfl_xor(ns, m);
    su += __shfl_xor(su, m); sp += __shfl_xor(sp, m);
  }
  if ((gid & 63) == 0) {
    float sig = 1.0f / (1.0f + expf(-(ps - ns)));
    atomicAdd(acc + 0, -logf(1e-5f + sig));
    atomicAdd(acc + 1, su);
    atomicAdd(acc + 2, sp);
  }
}

__global__ void finalize_kernel(const float* __restrict__ acc, float* __restrict__ out) {
  out[0] = acc[0] * (1.0f / BATCH)
         + 1e-4f * (sqrtf(acc[1]) + sqrtf(acc[2]))
         + 0.5f * (acc[3] + acc[4]) * (1.0f / BATCH);
}

extern "C" void kernel_launch(void* const* d_in, const int* in_sizes, int n_in,
                              void* d_out, int out_size, void* d_ws, size_t ws_size,
                              hipStream_t stream) {
  (void)in_sizes; (void)n_in; (void)out_size; (void)ws_size;
  const float* user_embed = (const float*)d_in[0];
  const float* item_embed = (const float*)d_in[1];
  const float* adj_vals   = (const float*)d_in[2];
  const int*   adj_rows   = (const int*)d_in[3];
  const int*   adj_cols   = (const int*)d_in[4];
  const int*   users      = (const int*)d_in[5];
  const int*   pos_items  = (const int*)d_in[6];
  const int*   neg_items  = (const int*)d_in[7];
  float* out = (float*)d_out;

  // ---- workspace layout (all 4B elems) ----
  float* bufA  = (float*)d_ws;                         // NTOT*DIM
  float* bufB  = bufA + (size_t)NTOT * DIM;            // NTOT*DIM
  float* svals = bufB + (size_t)NTOT * DIM;            // NNZC
  int*   scols = (int*)(svals + NNZC);                 // NNZC
  int*   rs    = scols + NNZC;                         // NTOT+1
  int*   cursor= rs + (NTOT + 1);                      // NTOT
  int*   bsums = cursor + NTOT;                        // 512
  float* g     = (float*)(bsums + 512);                // 7*B64 + 2*BATCH + 8
  float* g_ue = g + 0 * B64;
  float* g_pe = g + 1 * B64;
  float* g_ne = g + 2 * B64;
  float* g_u1 = g + 3 * B64;
  float* g_i1 = g + 4 * B64;
  float* g_u2 = g + 5 * B64;
  float* g_i2 = g + 6 * B64;
  float* ttl_u = g + 7 * B64;            // BATCH
  float* ttl_i = ttl_u + BATCH;          // BATCH
  float* acc   = ttl_i + BATCH;          // [0]=rec [1]=ssq_ue [2]=ssq_pe [3]=nce_u [4]=nce_i

  hipMemsetAsync(g, 0, ((size_t)7 * B64 + 2 * BATCH + 8) * sizeof(float), stream);
  hipMemsetAsync(cursor, 0, (size_t)NTOT * sizeof(int), stream);

  // ---- CSR build (amortized over 9 SpMMs) ----
  const int nnz_blocks = (NNZC + 255) / 256;
  hist_kernel<<<nnz_blocks, 256, 0, stream>>>(adj_rows, cursor);
  scan_block<<<NSCAN_BLOCKS, 256, 0, stream>>>(cursor, rs, bsums);
  scan_sums<<<1, 512, 0, stream>>>(bsums, NSCAN_BLOCKS);
  add_offsets<<<(NTOT + 255) / 256, 256, 0, stream>>>(rs, bsums);
  hipMemcpyAsync(cursor, rs, (size_t)NTOT * sizeof(int),
                 hipMemcpyDeviceToDevice, stream);
  scatter_csr<<<nnz_blocks, 256, 0, stream>>>(adj_vals, adj_rows, adj_cols,
                                              cursor, svals, scols);

  const int spmm_blocks = (NTOT * 64) / 256;   // 75000
  const int gat_blocks  = (BATCH * 64) / 256;  // 1024

  for (int p = 0; p < 3; ++p) {
    float* cur = bufA;
    float* nxt = bufB;
    uint32_t seed = (p == 1) ? 101u : 202u;
    for (uint32_t h = 0; h < 3; ++h) {
      const float* xa = (h == 0) ? user_embed : cur;
      const float* xb = (h == 0) ? item_embed : (cur + (size_t)NUSERS * DIM);
      if (p == 0)
        spmm_csr<false><<<spmm_blocks, 256, 0, stream>>>(svals, scols, rs, xa, xb,
                                                         nxt, 0u, h);
      else
        spmm_csr<true><<<spmm_blocks, 256, 0, stream>>>(svals, scols, rs, xa, xb,
                                                        nxt, seed, h);
      if (p == 0) {
        gather_add<<<gat_blocks, 256, 0, stream>>>(nxt, users, 0, g_ue);
        gather_add<<<gat_blocks, 256, 0, stream>>>(nxt, pos_items, NUSERS, g_pe);
        gather_add<<<gat_blocks, 256, 0, stream>>>(nxt, neg_items, NUSERS, g_ne);
      } else if (p == 1) {
        gather_add<<<gat_blocks, 256, 0, stream>>>(nxt, users, 0, g_u1);
        gather_add<<<gat_blocks, 256, 0, stream>>>(nxt, pos_items, NUSERS, g_i1);
      } else {
        gather_add<<<gat_blocks, 256, 0, stream>>>(nxt, users, 0, g_u2);
        gather_add<<<gat_blocks, 256, 0, stream>>>(nxt, pos_items, NUSERS, g_i2);
      }
      float* t = cur; cur = nxt; nxt = t;
    }
  }

  rec_kernel<<<gat_blocks, 256, 0, stream>>>(g_ue, g_pe, g_ne, acc);
  rownorm_kernel<<<gat_blocks, 256, 0, stream>>>(g_u1);
  rownorm_kernel<<<gat_blocks, 256, 0, stream>>>(g_u2);
  rownorm_kernel<<<gat_blocks, 256, 0, stream>>>(g_i1);
  rownorm_kernel<<<gat_blocks, 256, 0, stream>>>(g_i2);

  dim3 nce_grid(BATCH / IB, BATCH / JB);
  nce_ttl<<<nce_grid, 256, 0, stream>>>(g_u1, g_u2, ttl_u);
  nce_ttl<<<nce_grid, 256, 0, stream>>>(g_i1, g_i2, ttl_i);
  nce_final<<<gat_blocks, 256, 0, stream>>>(g_u1, g_u2, ttl_u, acc + 3);
  nce_final<<<gat_blocks, 256, 0, stream>>>(g_i1, g_i2, ttl_i, acc + 4);
  finalize_kernel<<<1, 1, 0, stream>>>(acc, out);
}

// Round 4
// 2059.269 us; speedup vs baseline: 3.8417x; 1.2771x over previous
//
#include <hip/hip_runtime.h>
#include <stdint.h>

#define NUSERS  200000
#define NITEMS  100000
#define NTOT    300000
#define DIM     64
#define NNZC    3000000
#define BATCH   4096
#define B64     (BATCH * DIM)
#define EPSP    0.1f
#define INV_TEMP 5.0f   // 1 / 0.2
#define SCAN_ELEMS 1024
#define NSCAN_BLOCKS ((NTOT + SCAN_ELEMS - 1) / SCAN_ELEMS)   // 293
#define IB 64
#define JB 128
#define LDA 65
#define GELEMS ((size_t)7 * B64 + 2 * BATCH + 8)

// ---------------- Threefry-2x32 (JAX-compatible) ----------------
__device__ __forceinline__ uint32_t rotl32(uint32_t v, int r) {
  return (v << r) | (v >> (32 - r));
}

__device__ __forceinline__ void tf2x32(uint32_t k0, uint32_t k1,
                                       uint32_t x0, uint32_t x1,
                                       uint32_t &o0, uint32_t &o1) {
  uint32_t k2 = k0 ^ k1 ^ 0x1BD11BDAu;
#define TFR(r) { x0 += x1; x1 = rotl32(x1, (r)); x1 ^= x0; }
  x0 += k0; x1 += k1;
  TFR(13) TFR(15) TFR(26) TFR(6)
  x0 += k1; x1 += k2 + 1u;
  TFR(17) TFR(29) TFR(16) TFR(24)
  x0 += k2; x1 += k0 + 2u;
  TFR(13) TFR(15) TFR(26) TFR(6)
  x0 += k0; x1 += k1 + 3u;
  TFR(17) TFR(29) TFR(16) TFR(24)
  x0 += k1; x1 += k2 + 4u;
  TFR(13) TFR(15) TFR(26) TFR(6)
  x0 += k2; x1 += k0 + 5u;
#undef TFR
  o0 = x0; o1 = x1;
}

__device__ __forceinline__ float tf_unif(uint32_t k0, uint32_t k1, uint32_t e) {
  uint32_t b0, b1;
  tf2x32(k0, k1, 0u, e, b0, b1);
  return __uint_as_float(((b0 ^ b1) >> 9) | 0x3F800000u) - 1.0f;
}

__device__ __forceinline__ float sgnf(float a) {
  return (a > 0.f) ? 1.f : ((a < 0.f) ? -1.f : 0.f);
}

// ---------------- CSR build ----------------
__global__ void hist_kernel(const int* __restrict__ rows, int* __restrict__ cnt) {
  int i = blockIdx.x * blockDim.x + threadIdx.x;
  if (i < NNZC) atomicAdd(&cnt[rows[i]], 1);
}

__global__ void scan_block(const int* __restrict__ cnt, int* __restrict__ rs,
                           int* __restrict__ bsums) {
  __shared__ int tmp[SCAN_ELEMS];
  int base = blockIdx.x * SCAN_ELEMS;
  int t = threadIdx.x;                 // 256 threads
  #pragma unroll
  for (int q = 0; q < 4; ++q) {
    int k = t + q * 256, i = base + k;
    tmp[k] = (i < NTOT) ? cnt[i] : 0;
  }
  __syncthreads();
  for (int off = 1; off < SCAN_ELEMS; off <<= 1) {
    int v[4];
    #pragma unroll
    for (int q = 0; q < 4; ++q) {
      int k = t + q * 256;
      v[q] = (k >= off) ? tmp[k - off] : 0;
    }
    __syncthreads();
    #pragma unroll
    for (int q = 0; q < 4; ++q) tmp[t + q * 256] += v[q];
    __syncthreads();
  }
  #pragma unroll
  for (int q = 0; q < 4; ++q) {
    int k = t + q * 256, i = base + k;
    if (i < NTOT) rs[i] = (k == 0) ? 0 : tmp[k - 1];
  }
  if (t == 0) bsums[blockIdx.x] = tmp[SCAN_ELEMS - 1];
}

__global__ void scan_sums(int* __restrict__ bsums, int nb) {
  __shared__ int tmp[512];
  int t = threadIdx.x;
  tmp[t] = (t < nb) ? bsums[t] : 0;
  __syncthreads();
  for (int off = 1; off < 512; off <<= 1) {
    int v = (t >= off) ? tmp[t - off] : 0;
    __syncthreads();
    tmp[t] += v;
    __syncthreads();
  }
  if (t < nb) bsums[t] = (t == 0) ? 0 : tmp[t - 1];
}

__global__ void add_offsets(int* __restrict__ rs, const int* __restrict__ bsums) {
  int i = blockIdx.x * blockDim.x + threadIdx.x;
  if (i < NTOT) rs[i] += bsums[i / SCAN_ELEMS];
  if (i == 0) rs[NTOT] = NNZC;
}

// pairs[pos] = {val bits, col * DIM}  (element offset, 32-bit addressable)
__global__ void scatter_csr(const float* __restrict__ vals,
                            const int* __restrict__ rows,
                            const int* __restrict__ cols,
                            int* __restrict__ cursor,
                            int2* __restrict__ pairs) {
  int i = blockIdx.x * blockDim.x + threadIdx.x;
  if (i >= NNZC) return;
  int r = rows[i];
  int pos = atomicAdd(&cursor[r], 1);
  pairs[pos] = make_int2(__float_as_int(vals[i]), cols[i] * DIM);
}

// ---------------- fused 3-branch SpMM, 4 rows/wave, 16 lanes x float4 --------
// y0 = A x0 (clean); y1 = A x1 + noise(101,hop); y2 = A x2 + noise(202,hop)
// HOP0: x1 == x2 == x0, single gather.
template <bool HOP0>
__global__ __launch_bounds__(256) void spmm3(
    const int2* __restrict__ pairs, const int* __restrict__ rs,
    const float* __restrict__ x0, const float* __restrict__ x1,
    const float* __restrict__ x2, float* __restrict__ y0,
    float* __restrict__ y1, float* __restrict__ y2, uint32_t hop) {
  int tid  = threadIdx.x;
  int lane = tid & 63;
  int q    = lane & 15;
  int wave = (blockIdx.x * 256 + tid) >> 6;
  int r    = wave * 4 + (lane >> 4);           // grid exact: no guard needed
  int s    = rs[r];
  int cnt  = rs[r + 1] - s;
  int mc = cnt;
  mc = max(mc, __shfl_xor(mc, 16));
  mc = max(mc, __shfl_xor(mc, 32));
  float a0[4] = {0.f, 0.f, 0.f, 0.f};
  float a1[4] = {0.f, 0.f, 0.f, 0.f};
  float a2[4] = {0.f, 0.f, 0.f, 0.f};
  int grpbase = lane & 48;
  int q4 = q * 4;
  for (int ch = 0; ch < mc; ch += 16) {
    int2 pv = make_int2(0, 0);
    if (ch + q < cnt) pv = pairs[s + ch + q];
    int m = (mc - ch < 16) ? (mc - ch) : 16;
    for (int j = 0; j < m; ++j) {
      int sl = grpbase + j;
      float v = __uint_as_float((unsigned)__shfl(pv.x, sl));
      unsigned o = (unsigned)(__shfl(pv.y, sl) + q4);
      float4 f0 = *(const float4*)(x0 + o);
      a0[0] = fmaf(v, f0.x, a0[0]); a0[1] = fmaf(v, f0.y, a0[1]);
      a0[2] = fmaf(v, f0.z, a0[2]); a0[3] = fmaf(v, f0.w, a0[3]);
      if (!HOP0) {
        float4 f1 = *(const float4*)(x1 + o);
        float4 f2 = *(const float4*)(x2 + o);
        a1[0] = fmaf(v, f1.x, a1[0]); a1[1] = fmaf(v, f1.y, a1[1]);
        a1[2] = fmaf(v, f1.z, a1[2]); a1[3] = fmaf(v, f1.w, a1[3]);
        a2[0] = fmaf(v, f2.x, a2[0]); a2[1] = fmaf(v, f2.y, a2[1]);
        a2[2] = fmaf(v, f2.z, a2[2]); a2[3] = fmaf(v, f2.w, a2[3]);
      }
    }
  }
  // ---- fused SimGCL noise for branches 1,2 ----
  uint32_t kA0, kA1, kB0, kB1;
  tf2x32(0u, 101u, 0u, hop, kA0, kA1);      // uniform -> scalar unit
  tf2x32(0u, 202u, 0u, hop, kB0, kB1);
  int ebase = r * 64 + q4;
  float u1[4], u2[4];
  float ss1 = 0.f, ss2 = 0.f;
  #pragma unroll
  for (int k = 0; k < 4; ++k) {
    u1[k] = tf_unif(kA0, kA1, (uint32_t)(ebase + k));
    u2[k] = tf_unif(kB0, kB1, (uint32_t)(ebase + k));
    ss1 += u1[k] * u1[k];
    ss2 += u2[k] * u2[k];
  }
  #pragma unroll
  for (int msk = 1; msk < 16; msk <<= 1) {
    ss1 += __shfl_xor(ss1, msk);
    ss2 += __shfl_xor(ss2, msk);
  }
  float sc1 = EPSP / fmaxf(sqrtf(ss1), 1e-12f);
  float sc2 = EPSP / fmaxf(sqrtf(ss2), 1e-12f);
  float r0[4], r1[4], r2[4];
  #pragma unroll
  for (int k = 0; k < 4; ++k) {
    float b1v = HOP0 ? a0[k] : a1[k];
    float b2v = HOP0 ? a0[k] : a2[k];
    r0[k] = a0[k];
    r1[k] = b1v + sgnf(b1v) * u1[k] * sc1;
    r2[k] = b2v + sgnf(b2v) * u2[k] * sc2;
  }
  *(float4*)(y0 + ebase) = make_float4(r0[0], r0[1], r0[2], r0[3]);
  *(float4*)(y1 + ebase) = make_float4(r1[0], r1[1], r1[2], r1[3]);
  *(float4*)(y2 + ebase) = make_float4(r2[0], r2[1], r2[2], r2[3]);
}

// ---------------- single-branch SpMM (fallback path) ----------------
template <bool PERT>
__global__ __launch_bounds__(256) void spmm1(
    const int2* __restrict__ pairs, const int* __restrict__ rs,
    const float* __restrict__ x, float* __restrict__ y,
    uint32_t seed, uint32_t hop) {
  int tid  = threadIdx.x;
  int lane = tid & 63;
  int q    = lane & 15;
  int wave = (blockIdx.x * 256 + tid) >> 6;
  int r    = wave * 4 + (lane >> 4);
  int s    = rs[r];
  int cnt  = rs[r + 1] - s;
  int mc = cnt;
  mc = max(mc, __shfl_xor(mc, 16));
  mc = max(mc, __shfl_xor(mc, 32));
  float a0[4] = {0.f, 0.f, 0.f, 0.f};
  int grpbase = lane & 48;
  int q4 = q * 4;
  for (int ch = 0; ch < mc; ch += 16) {
    int2 pv = make_int2(0, 0);
    if (ch + q < cnt) pv = pairs[s + ch + q];
    int m = (mc - ch < 16) ? (mc - ch) : 16;
    for (int j = 0; j < m; ++j) {
      int sl = grpbase + j;
      float v = __uint_as_float((unsigned)__shfl(pv.x, sl));
      unsigned o = (unsigned)(__shfl(pv.y, sl) + q4);
      float4 f0 = *(const float4*)(x + o);
      a0[0] = fmaf(v, f0.x, a0[0]); a0[1] = fmaf(v, f0.y, a0[1]);
      a0[2] = fmaf(v, f0.z, a0[2]); a0[3] = fmaf(v, f0.w, a0[3]);
    }
  }
  int ebase = r * 64 + q4;
  if (PERT) {
    uint32_t k0, k1;
    tf2x32(0u, seed, 0u, hop, k0, k1);
    float u[4], ss = 0.f;
    #pragma unroll
    for (int k = 0; k < 4; ++k) {
      u[k] = tf_unif(k0, k1, (uint32_t)(ebase + k));
      ss += u[k] * u[k];
    }
    #pragma unroll
    for (int msk = 1; msk < 16; msk <<= 1) ss += __shfl_xor(ss, msk);
    float sc = EPSP / fmaxf(sqrtf(ss), 1e-12f);
    #pragma unroll
    for (int k = 0; k < 4; ++k) a0[k] += sgnf(a0[k]) * u[k] * sc;
  }
  *(float4*)(y + ebase) = make_float4(a0[0], a0[1], a0[2], a0[3]);
}

// ---------------- gather all 7 batch selections in one launch ----------------
// g layout: [ue, pe, ne, u1, i1, u2, i2] each B64
__global__ void gather7(const float* __restrict__ y0, const float* __restrict__ y1,
                        const float* __restrict__ y2,
                        const int* __restrict__ users, const int* __restrict__ pos,
                        const int* __restrict__ neg, float* __restrict__ g) {
  int gid = blockIdx.x * blockDim.x + threadIdx.x;   // 7*B64 threads
  int which = gid >> 18;                             // B64 == 1<<18
  int sub = gid & (B64 - 1);
  int b = sub >> 6, d = sub & 63;
  const float* y = (which < 3) ? y0 : ((which < 5) ? y1 : y2);
  const int* idx;
  int base;
  switch (which) {
    case 0: idx = users; base = 0;      break;
    case 1: idx = pos;   base = NUSERS; break;
    case 2: idx = neg;   base = NUSERS; break;
    case 3: idx = users; base = 0;      break;
    case 4: idx = pos;   base = NUSERS; break;
    case 5: idx = users; base = 0;      break;
    default: idx = pos;  base = NUSERS; break;
  }
  g[gid] += y[(size_t)(base + idx[b]) * DIM + d];
}

// ---------------- fallback per-branch gather ----------------
__global__ void gather_add(const float* __restrict__ src,
                           const int* __restrict__ idx,
                           int base, float* __restrict__ dst) {
  int gid = blockIdx.x * blockDim.x + threadIdx.x;
  int b = gid >> 6, d = gid & 63;
  if (b >= BATCH) return;
  int r = base + idx[b];
  dst[gid] += src[(size_t)r * DIM + d];
}

// ---------------- row-normalize (clamp 1e-12) ----------------
__global__ void rownorm_kernel(float* __restrict__ v) {
  int gid = blockIdx.x * blockDim.x + threadIdx.x;
  if ((gid >> 6) >= BATCH) return;
  float x = v[gid];
  float ss = x * x;
  #pragma unroll
  for (int m = 32; m; m >>= 1) ss += __shfl_xor(ss, m);
  v[gid] = x / fmaxf(sqrtf(ss), 1e-12f);
}

// ---------------- InfoNCE phase 1: tiled exp-GEMM row sums --------------------
__global__ __launch_bounds__(256) void nce_ttl(const float* __restrict__ v1,
                                               const float* __restrict__ v2,
                                               float* __restrict__ ttl) {
  __shared__ float s1[IB * LDA];
  __shared__ float s2[JB * LDA];
  __shared__ float tsum[IB];
  int tid = threadIdx.x;
  const float4* v1v = (const float4*)(v1 + (size_t)blockIdx.x * IB * DIM);
  #pragma unroll
  for (int p = 0; p < 4; ++p) {
    int e = tid + p * 256;
    int r = e >> 4, q = e & 15;
    float4 f = v1v[e];
    float* d = &s1[r * LDA + q * 4];
    d[0] = f.x; d[1] = f.y; d[2] = f.z; d[3] = f.w;
  }
  const float4* v2v = (const float4*)(v2 + (size_t)blockIdx.y * JB * DIM);
  #pragma unroll
  for (int p = 0; p < 8; ++p) {
    int e = tid + p * 256;
    int r = e >> 4, q = e & 15;
    float4 f = v2v[e];
    float* d = &s2[r * LDA + q * 4];
    d[0] = f.x; d[1] = f.y; d[2] = f.z; d[3] = f.w;
  }
  if (tid < IB) tsum[tid] = 0.0f;
  __syncthreads();

  int i0 = (tid & 15) * 4;
  int j0 = (tid >> 4) * 8;
  float acc[4][8];
  #pragma unroll
  for (int m = 0; m < 4; ++m)
    #pragma unroll
    for (int n = 0; n < 8; ++n) acc[m][n] = 0.0f;
  #pragma unroll 4
  for (int k = 0; k < DIM; ++k) {
    float a[4], b[8];
    #pragma unroll
    for (int m = 0; m < 4; ++m) a[m] = s1[(i0 + m) * LDA + k];
    #pragma unroll
    for (int n = 0; n < 8; ++n) b[n] = s2[(j0 + n) * LDA + k];
    #pragma unroll
    for (int m = 0; m < 4; ++m)
      #pragma unroll
      for (int n = 0; n < 8; ++n) acc[m][n] = fmaf(a[m], b[n], acc[m][n]);
  }
  #pragma unroll
  for (int m = 0; m < 4; ++m) {
    float ts = 0.0f;
    #pragma unroll
    for (int n = 0; n < 8; ++n) ts += __expf(acc[m][n] * INV_TEMP);
    atomicAdd(&tsum[i0 + m], ts);
  }
  __syncthreads();
  if (tid < IB) atomicAdd(&ttl[blockIdx.x * IB + tid], tsum[tid]);
}

// ---------------- InfoNCE phase 2: diagonal + log --------------------
__global__ void nce_final(const float* __restrict__ v1,
                          const float* __restrict__ v2,
                          const float* __restrict__ ttl,
                          float* __restrict__ acc) {
  int gid = blockIdx.x * blockDim.x + threadIdx.x;
  int i = gid >> 6, lane = gid & 63;
  if (i >= BATCH) return;
  float p = v1[gid] * v2[gid];
  #pragma unroll
  for (int m = 32; m; m >>= 1) p += __shfl_xor(p, m);
  if (lane == 0)
    atomicAdd(acc, -logf(expf(p * INV_TEMP) / ttl[i] + 1e-5f));
}

// ---------------- BPR rec loss + reg ----------------
__global__ void rec_kernel(const float* __restrict__ ue, const float* __restrict__ pe,
                           const float* __restrict__ ne, float* __restrict__ acc) {
  int gid = blockIdx.x * blockDim.x + threadIdx.x;
  if ((gid >> 6) >= BATCH) return;
  const float third = 1.0f / 3.0f;
  float u = ue[gid] * third, p = pe[gid] * third, n = ne[gid] * third;
  float ps = u * p, ns = u * n, su = u * u, sp = p * p;
  #pragma unroll
  for (int m = 32; m; m >>= 1) {
    ps += __shfl_xor(ps, m); ns += __shfl_xor(ns, m);
    su += __shfl_xor(su, m); sp += __shfl_xor(sp, m);
  }
  if ((gid & 63) == 0) {
    float sig = 1.0f / (1.0f + expf(-(ps - ns)));
    atomicAdd(acc + 0, -logf(1e-5f + sig));
    atomicAdd(acc + 1, su);
    atomicAdd(acc + 2, sp);
  }
}

__global__ void finalize_kernel(const float* __restrict__ acc, float* __restrict__ out) {
  out[0] = acc[0] * (1.0f / BATCH)
         + 1e-4f * (sqrtf(acc[1]) + sqrtf(acc[2]))
         + 0.5f * (acc[3] + acc[4]) * (1.0f / BATCH);
}

extern "C" void kernel_launch(void* const* d_in, const int* in_sizes, int n_in,
                              void* d_out, int out_size, void* d_ws, size_t ws_size,
                              hipStream_t stream) {
  (void)in_sizes; (void)n_in; (void)out_size;
  const float* user_embed = (const float*)d_in[0];
  const float* item_embed = (const float*)d_in[1];
  const float* adj_vals   = (const float*)d_in[2];
  const int*   adj_rows   = (const int*)d_in[3];
  const int*   adj_cols   = (const int*)d_in[4];
  const int*   users      = (const int*)d_in[5];
  const int*   pos_items  = (const int*)d_in[6];
  const int*   neg_items  = (const int*)d_in[7];
  float* out = (float*)d_out;

  const size_t bufElems = (size_t)NTOT * DIM;
  const size_t tailBytes = (size_t)NNZC * 8 + GELEMS * 4
                         + ((size_t)(NTOT + 1) + NTOT + 512) * 4;
  const bool fast = ws_size >= 6 * bufElems * 4 + tailBytes;
  const int nbuf = fast ? 6 : 2;

  // ---- workspace layout (16B-aligned regions first) ----
  float* buf0  = (float*)d_ws;                              // nbuf * bufElems
  int2*  pairs = (int2*)(buf0 + (size_t)nbuf * bufElems);   // NNZC
  float* g     = (float*)(pairs + NNZC);                    // GELEMS
  float* g_ue = g + 0 * (size_t)B64;
  float* g_pe = g + 1 * (size_t)B64;
  float* g_ne = g + 2 * (size_t)B64;
  float* g_u1 = g + 3 * (size_t)B64;
  float* g_i1 = g + 4 * (size_t)B64;
  float* g_u2 = g + 5 * (size_t)B64;
  float* g_i2 = g + 6 * (size_t)B64;
  float* ttl_u = g + 7 * (size_t)B64;
  float* ttl_i = ttl_u + BATCH;
  float* acc   = ttl_i + BATCH;       // 8 scalars
  int* rs     = (int*)(g + GELEMS);   // NTOT+1
  int* cursor = rs + (NTOT + 1);      // NTOT
  int* bsums  = cursor + NTOT;        // 512

  hipMemsetAsync(g, 0, GELEMS * sizeof(float), stream);
  hipMemsetAsync(cursor, 0, (size_t)NTOT * sizeof(int), stream);

  // ---- CSR build ----
  const int nnz_blocks = (NNZC + 255) / 256;
  hist_kernel<<<nnz_blocks, 256, 0, stream>>>(adj_rows, cursor);
  scan_block<<<NSCAN_BLOCKS, 256, 0, stream>>>(cursor, rs, bsums);
  scan_sums<<<1, 512, 0, stream>>>(bsums, NSCAN_BLOCKS);
  add_offsets<<<(NTOT + 255) / 256, 256, 0, stream>>>(rs, bsums);
  hipMemcpyAsync(cursor, rs, (size_t)NTOT * sizeof(int),
                 hipMemcpyDeviceToDevice, stream);
  scatter_csr<<<nnz_blocks, 256, 0, stream>>>(adj_vals, adj_rows, adj_cols,
                                              cursor, pairs);

  const int spmm_blocks = NTOT / 16;           // 4 rows per wave, 4 waves/block
  const int gat7_blocks = 7 * B64 / 256;       // 7168
  const int gat_blocks  = B64 / 256;           // 1024

  if (fast) {
    float* E  = buf0;                 // ego0, reused as B0 after hop 0
    float* A0 = buf0 + 1 * bufElems;
    float* A1 = buf0 + 2 * bufElems;
    float* A2 = buf0 + 3 * bufElems;
    float* B1 = buf0 + 4 * bufElems;
    float* B2 = buf0 + 5 * bufElems;
    hipMemcpyAsync(E, user_embed, (size_t)NUSERS * DIM * sizeof(float),
                   hipMemcpyDeviceToDevice, stream);
    hipMemcpyAsync(E + (size_t)NUSERS * DIM, item_embed,
                   (size_t)NITEMS * DIM * sizeof(float),
                   hipMemcpyDeviceToDevice, stream);
    spmm3<true><<<spmm_blocks, 256, 0, stream>>>(pairs, rs, E, E, E,
                                                 A0, A1, A2, 0u);
    gather7<<<gat7_blocks, 256, 0, stream>>>(A0, A1, A2, users, pos_items,
                                             neg_items, g);
    spmm3<false><<<spmm_blocks, 256, 0, stream>>>(pairs, rs, A0, A1, A2,
                                                  E, B1, B2, 1u);
    gather7<<<gat7_blocks, 256, 0, stream>>>(E, B1, B2, users, pos_items,
                                             neg_items, g);
    spmm3<false><<<spmm_blocks, 256, 0, stream>>>(pairs, rs, E, B1, B2,
                                                  A0, A1, A2, 2u);
    gather7<<<gat7_blocks, 256, 0, stream>>>(A0, A1, A2, users, pos_items,
                                             neg_items, g);
  } else {
    float* bufA = buf0;
    float* bufB = buf0 + bufElems;
    for (int p = 0; p < 3; ++p) {
      hipMemcpyAsync(bufA, user_embed, (size_t)NUSERS * DIM * sizeof(float),
                     hipMemcpyDeviceToDevice, stream);
      hipMemcpyAsync(bufA + (size_t)NUSERS * DIM, item_embed,
                     (size_t)NITEMS * DIM * sizeof(float),
                     hipMemcpyDeviceToDevice, stream);
      float* cur = bufA;
      float* nxt = bufB;
      uint32_t seed = (p == 1) ? 101u : 202u;
      for (uint32_t h = 0; h < 3; ++h) {
        if (p == 0)
          spmm1<false><<<spmm_blocks, 256, 0, stream>>>(pairs, rs, cur, nxt, 0u, h);
        else
          spmm1<true><<<spmm_blocks, 256, 0, stream>>>(pairs, rs, cur, nxt, seed, h);
        if (p == 0) {
          gather_add<<<gat_blocks, 256, 0, stream>>>(nxt, users, 0, g_ue);
          gather_add<<<gat_blocks, 256, 0, stream>>>(nxt, pos_items, NUSERS, g_pe);
          gather_add<<<gat_blocks, 256, 0, stream>>>(nxt, neg_items, NUSERS, g_ne);
        } else if (p == 1) {
          gather_add<<<gat_blocks, 256, 0, stream>>>(nxt, users, 0, g_u1);
          gather_add<<<gat_blocks, 256, 0, stream>>>(nxt, pos_items, NUSERS, g_i1);
        } else {
          gather_add<<<gat_blocks, 256, 0, stream>>>(nxt, users, 0, g_u2);
          gather_add<<<gat_blocks, 256, 0, stream>>>(nxt, pos_items, NUSERS, g_i2);
        }
        float* t = cur; cur = nxt; nxt = t;
      }
    }
  }

  rec_kernel<<<gat_blocks, 256, 0, stream>>>(g_ue, g_pe, g_ne, acc);
  rownorm_kernel<<<gat_blocks, 256, 0, stream>>>(g_u1);
  rownorm_kernel<<<gat_blocks, 256, 0, stream>>>(g_u2);
  rownorm_kernel<<<gat_blocks, 256, 0, stream>>>(g_i1);
  rownorm_kernel<<<gat_blocks, 256, 0, stream>>>(g_i2);

  dim3 nce_grid(BATCH / IB, BATCH / JB);
  nce_ttl<<<nce_grid, 256, 0, stream>>>(g_u1, g_u2, ttl_u);
  nce_ttl<<<nce_grid, 256, 0, stream>>>(g_i1, g_i2, ttl_i);
  nce_final<<<gat_blocks, 256, 0, stream>>>(g_u1, g_u2, ttl_u, acc + 3);
  nce_final<<<gat_blocks, 256, 0, stream>>>(g_i1, g_i2, ttl_i, acc + 4);
  finalize_kernel<<<1, 1, 0, stream>>>(acc, out);
}

// Round 5
// 1887.874 us; speedup vs baseline: 4.1904x; 1.0908x over previous
//
#include <hip/hip_runtime.h>
#include <stdint.h>

#define NUSERS  200000
#define NITEMS  100000
#define NTOT    300000
#define DIM     64
#define NU64    (NUSERS * DIM)
#define NNZC    3000000
#define BATCH   4096
#define B64     (BATCH * DIM)
#define EPSP    0.1f
#define INV_TEMP 5.0f   // 1 / 0.2
#define SCAN_ELEMS 1024
#define NSCAN_BLOCKS ((NTOT + SCAN_ELEMS - 1) / SCAN_ELEMS)   // 293
#define IB 64
#define JB 128
#define LDA 65
#define GELEMS ((size_t)7 * B64 + 2 * BATCH + 8)

// ---------------- Threefry-2x32 (JAX-compatible) ----------------
__device__ __forceinline__ uint32_t rotl32(uint32_t v, int r) {
  return (v << r) | (v >> (32 - r));
}

__device__ __forceinline__ void tf2x32(uint32_t k0, uint32_t k1,
                                       uint32_t x0, uint32_t x1,
                                       uint32_t &o0, uint32_t &o1) {
  uint32_t k2 = k0 ^ k1 ^ 0x1BD11BDAu;
#define TFR(r) { x0 += x1; x1 = rotl32(x1, (r)); x1 ^= x0; }
  x0 += k0; x1 += k1;
  TFR(13) TFR(15) TFR(26) TFR(6)
  x0 += k1; x1 += k2 + 1u;
  TFR(17) TFR(29) TFR(16) TFR(24)
  x0 += k2; x1 += k0 + 2u;
  TFR(13) TFR(15) TFR(26) TFR(6)
  x0 += k0; x1 += k1 + 3u;
  TFR(17) TFR(29) TFR(16) TFR(24)
  x0 += k1; x1 += k2 + 4u;
  TFR(13) TFR(15) TFR(26) TFR(6)
  x0 += k2; x1 += k0 + 5u;
#undef TFR
  o0 = x0; o1 = x1;
}

__device__ __forceinline__ float tf_unif(uint32_t k0, uint32_t k1, uint32_t e) {
  uint32_t b0, b1;
  tf2x32(k0, k1, 0u, e, b0, b1);
  return __uint_as_float(((b0 ^ b1) >> 9) | 0x3F800000u) - 1.0f;
}

__device__ __forceinline__ float sgnf(float a) {
  return (a > 0.f) ? 1.f : ((a < 0.f) ? -1.f : 0.f);
}

// ---------------- CSR build ----------------
__global__ void hist_kernel(const int4* __restrict__ rows4, int* __restrict__ cnt) {
  int i = blockIdx.x * blockDim.x + threadIdx.x;
  if (i < NNZC / 4) {
    int4 r = rows4[i];
    atomicAdd(&cnt[r.x], 1);
    atomicAdd(&cnt[r.y], 1);
    atomicAdd(&cnt[r.z], 1);
    atomicAdd(&cnt[r.w], 1);
  }
}

__global__ void scan_block(const int* __restrict__ cnt, int* __restrict__ rs,
                           int* __restrict__ bsums) {
  __shared__ int tmp[SCAN_ELEMS];
  int base = blockIdx.x * SCAN_ELEMS;
  int t = threadIdx.x;                 // 256 threads
  #pragma unroll
  for (int q = 0; q < 4; ++q) {
    int k = t + q * 256, i = base + k;
    tmp[k] = (i < NTOT) ? cnt[i] : 0;
  }
  __syncthreads();
  for (int off = 1; off < SCAN_ELEMS; off <<= 1) {
    int v[4];
    #pragma unroll
    for (int q = 0; q < 4; ++q) {
      int k = t + q * 256;
      v[q] = (k >= off) ? tmp[k - off] : 0;
    }
    __syncthreads();
    #pragma unroll
    for (int q = 0; q < 4; ++q) tmp[t + q * 256] += v[q];
    __syncthreads();
  }
  #pragma unroll
  for (int q = 0; q < 4; ++q) {
    int k = t + q * 256, i = base + k;
    if (i < NTOT) rs[i] = (k == 0) ? 0 : tmp[k - 1];
  }
  if (t == 0) bsums[blockIdx.x] = tmp[SCAN_ELEMS - 1];
}

__global__ void scan_sums(int* __restrict__ bsums, int nb) {
  __shared__ int tmp[512];
  int t = threadIdx.x;
  tmp[t] = (t < nb) ? bsums[t] : 0;
  __syncthreads();
  for (int off = 1; off < 512; off <<= 1) {
    int v = (t >= off) ? tmp[t - off] : 0;
    __syncthreads();
    tmp[t] += v;
    __syncthreads();
  }
  if (t < nb) bsums[t] = (t == 0) ? 0 : tmp[t - 1];
}

__global__ void add_offsets(int* __restrict__ rs, const int* __restrict__ bsums) {
  int i = blockIdx.x * blockDim.x + threadIdx.x;
  if (i < NTOT) rs[i] += bsums[i / SCAN_ELEMS];
  if (i == 0) rs[NTOT] = NNZC;
}

// pairs[pos] = {val bits, col * DIM}; nontemporal store to skip L2 write-allocate
__global__ void scatter_csr(const float* __restrict__ vals,
                            const int* __restrict__ rows,
                            const int* __restrict__ cols,
                            int* __restrict__ cursor,
                            int2* __restrict__ pairs) {
  int i = blockIdx.x * blockDim.x + threadIdx.x;
  if (i >= NNZC) return;
  int r = rows[i];
  int pos = atomicAdd(&cursor[r], 1);
  union { int2 v; long long ll; } u;
  u.v = make_int2(__float_as_int(vals[i]), cols[i] * DIM);
  __builtin_nontemporal_store(u.ll, (long long*)&pairs[pos]);
}

// ---------------- fused 3-branch SpMM, 4 rows/wave, 16 lanes x float4 --------
// HOP0: x1==x2==x0 == virtual concat(xa=user_embed, xb=item_embed); single gather.
template <bool HOP0>
__global__ __launch_bounds__(256) void spmm3(
    const int2* __restrict__ pairs, const int* __restrict__ rs,
    const float* __restrict__ x0, const float* __restrict__ x1,
    const float* __restrict__ x2, const float* __restrict__ xb,
    float* __restrict__ y0, float* __restrict__ y1, float* __restrict__ y2,
    uint32_t hop) {
  int tid  = threadIdx.x;
  int lane = tid & 63;
  int q    = lane & 15;
  int wave = (blockIdx.x * 256 + tid) >> 6;
  int r    = wave * 4 + (lane >> 4);           // grid exact: no guard needed
  int s    = rs[r];
  int cnt  = rs[r + 1] - s;
  int mc = cnt;
  mc = max(mc, __shfl_xor(mc, 16));
  mc = max(mc, __shfl_xor(mc, 32));
  float a0[4] = {0.f, 0.f, 0.f, 0.f};
  float a1[4] = {0.f, 0.f, 0.f, 0.f};
  float a2[4] = {0.f, 0.f, 0.f, 0.f};
  int grpbase = lane & 48;
  int q4 = q * 4;
  for (int ch = 0; ch < mc; ch += 16) {
    int2 pv = make_int2(0, 0);
    if (ch + q < cnt) pv = pairs[s + ch + q];
    int m = (mc - ch < 16) ? (mc - ch) : 16;
    for (int j = 0; j < m; ++j) {
      int sl = grpbase + j;
      float v = __uint_as_float((unsigned)__shfl(pv.x, sl));
      unsigned o = (unsigned)(__shfl(pv.y, sl) + q4);
      if (HOP0) {
        // virtual concat: x0 = user part, xb = item part
        const float4* p4 = (o < (unsigned)NU64)
                         ? (const float4*)(x0 + o)
                         : (const float4*)(xb + (o - (unsigned)NU64));
        float4 f0 = *p4;
        a0[0] = fmaf(v, f0.x, a0[0]); a0[1] = fmaf(v, f0.y, a0[1]);
        a0[2] = fmaf(v, f0.z, a0[2]); a0[3] = fmaf(v, f0.w, a0[3]);
      } else {
        float4 f0 = *(const float4*)(x0 + o);
        float4 f1 = *(const float4*)(x1 + o);
        float4 f2 = *(const float4*)(x2 + o);
        a0[0] = fmaf(v, f0.x, a0[0]); a0[1] = fmaf(v, f0.y, a0[1]);
        a0[2] = fmaf(v, f0.z, a0[2]); a0[3] = fmaf(v, f0.w, a0[3]);
        a1[0] = fmaf(v, f1.x, a1[0]); a1[1] = fmaf(v, f1.y, a1[1]);
        a1[2] = fmaf(v, f1.z, a1[2]); a1[3] = fmaf(v, f1.w, a1[3]);
        a2[0] = fmaf(v, f2.x, a2[0]); a2[1] = fmaf(v, f2.y, a2[1]);
        a2[2] = fmaf(v, f2.z, a2[2]); a2[3] = fmaf(v, f2.w, a2[3]);
      }
    }
  }
  // ---- fused SimGCL noise for branches 1,2 ----
  uint32_t kA0, kA1, kB0, kB1;
  tf2x32(0u, 101u, 0u, hop, kA0, kA1);
  tf2x32(0u, 202u, 0u, hop, kB0, kB1);
  int ebase = r * 64 + q4;
  float u1[4], u2[4];
  float ss1 = 0.f, ss2 = 0.f;
  #pragma unroll
  for (int k = 0; k < 4; ++k) {
    u1[k] = tf_unif(kA0, kA1, (uint32_t)(ebase + k));
    u2[k] = tf_unif(kB0, kB1, (uint32_t)(ebase + k));
    ss1 += u1[k] * u1[k];
    ss2 += u2[k] * u2[k];
  }
  #pragma unroll
  for (int msk = 1; msk < 16; msk <<= 1) {
    ss1 += __shfl_xor(ss1, msk);
    ss2 += __shfl_xor(ss2, msk);
  }
  float sc1 = EPSP / fmaxf(sqrtf(ss1), 1e-12f);
  float sc2 = EPSP / fmaxf(sqrtf(ss2), 1e-12f);
  float r0[4], r1[4], r2[4];
  #pragma unroll
  for (int k = 0; k < 4; ++k) {
    float b1v = HOP0 ? a0[k] : a1[k];
    float b2v = HOP0 ? a0[k] : a2[k];
    r0[k] = a0[k];
    r1[k] = b1v + sgnf(b1v) * u1[k] * sc1;
    r2[k] = b2v + sgnf(b2v) * u2[k] * sc2;
  }
  *(float4*)(y0 + ebase) = make_float4(r0[0], r0[1], r0[2], r0[3]);
  *(float4*)(y1 + ebase) = make_float4(r1[0], r1[1], r1[2], r1[3]);
  *(float4*)(y2 + ebase) = make_float4(r2[0], r2[1], r2[2], r2[3]);
}

// ---------------- single-branch SpMM (fallback path) ----------------
template <bool PERT>
__global__ __launch_bounds__(256) void spmm1(
    const int2* __restrict__ pairs, const int* __restrict__ rs,
    const float* __restrict__ x, float* __restrict__ y,
    uint32_t seed, uint32_t hop) {
  int tid  = threadIdx.x;
  int lane = tid & 63;
  int q    = lane & 15;
  int wave = (blockIdx.x * 256 + tid) >> 6;
  int r    = wave * 4 + (lane >> 4);
  int s    = rs[r];
  int cnt  = rs[r + 1] - s;
  int mc = cnt;
  mc = max(mc, __shfl_xor(mc, 16));
  mc = max(mc, __shfl_xor(mc, 32));
  float a0[4] = {0.f, 0.f, 0.f, 0.f};
  int grpbase = lane & 48;
  int q4 = q * 4;
  for (int ch = 0; ch < mc; ch += 16) {
    int2 pv = make_int2(0, 0);
    if (ch + q < cnt) pv = pairs[s + ch + q];
    int m = (mc - ch < 16) ? (mc - ch) : 16;
    for (int j = 0; j < m; ++j) {
      int sl = grpbase + j;
      float v = __uint_as_float((unsigned)__shfl(pv.x, sl));
      unsigned o = (unsigned)(__shfl(pv.y, sl) + q4);
      float4 f0 = *(const float4*)(x + o);
      a0[0] = fmaf(v, f0.x, a0[0]); a0[1] = fmaf(v, f0.y, a0[1]);
      a0[2] = fmaf(v, f0.z, a0[2]); a0[3] = fmaf(v, f0.w, a0[3]);
    }
  }
  int ebase = r * 64 + q4;
  if (PERT) {
    uint32_t k0, k1;
    tf2x32(0u, seed, 0u, hop, k0, k1);
    float u[4], ss = 0.f;
    #pragma unroll
    for (int k = 0; k < 4; ++k) {
      u[k] = tf_unif(k0, k1, (uint32_t)(ebase + k));
      ss += u[k] * u[k];
    }
    #pragma unroll
    for (int msk = 1; msk < 16; msk <<= 1) ss += __shfl_xor(ss, msk);
    float sc = EPSP / fmaxf(sqrtf(ss), 1e-12f);
    #pragma unroll
    for (int k = 0; k < 4; ++k) a0[k] += sgnf(a0[k]) * u[k] * sc;
  }
  *(float4*)(y + ebase) = make_float4(a0[0], a0[1], a0[2], a0[3]);
}

// ---------------- gather all 7 batch selections in one launch ----------------
__global__ void gather7(const float* __restrict__ y0, const float* __restrict__ y1,
                        const float* __restrict__ y2,
                        const int* __restrict__ users, const int* __restrict__ pos,
                        const int* __restrict__ neg, float* __restrict__ g) {
  int gid = blockIdx.x * blockDim.x + threadIdx.x;   // 7*B64 threads
  int which = gid >> 18;                             // B64 == 1<<18
  int sub = gid & (B64 - 1);
  int b = sub >> 6, d = sub & 63;
  const float* y = (which < 3) ? y0 : ((which < 5) ? y1 : y2);
  const int* idx;
  int base;
  switch (which) {
    case 0: idx = users; base = 0;      break;
    case 1: idx = pos;   base = NUSERS; break;
    case 2: idx = neg;   base = NUSERS; break;
    case 3: idx = users; base = 0;      break;
    case 4: idx = pos;   base = NUSERS; break;
    case 5: idx = users; base = 0;      break;
    default: idx = pos;  base = NUSERS; break;
  }
  g[gid] += y[(size_t)(base + idx[b]) * DIM + d];
}

// ---------------- fallback per-branch gather ----------------
__global__ void gather_add(const float* __restrict__ src,
                           const int* __restrict__ idx,
                           int base, float* __restrict__ dst) {
  int gid = blockIdx.x * blockDim.x + threadIdx.x;
  int b = gid >> 6, d = gid & 63;
  if (b >= BATCH) return;
  int r = base + idx[b];
  dst[gid] += src[(size_t)r * DIM + d];
}

// ---------------- row-normalize (clamp 1e-12) ----------------
__global__ void rownorm_kernel(float* __restrict__ v) {
  int gid = blockIdx.x * blockDim.x + threadIdx.x;
  if ((gid >> 6) >= BATCH) return;
  float x = v[gid];
  float ss = x * x;
  #pragma unroll
  for (int m = 32; m; m >>= 1) ss += __shfl_xor(ss, m);
  v[gid] = x / fmaxf(sqrtf(ss), 1e-12f);
}

// ---------------- InfoNCE phase 1: tiled exp-GEMM row sums --------------------
__global__ __launch_bounds__(256) void nce_ttl(const float* __restrict__ v1,
                                               const float* __restrict__ v2,
                                               float* __restrict__ ttl) {
  __shared__ float s1[IB * LDA];
  __shared__ float s2[JB * LDA];
  __shared__ float tsum[IB];
  int tid = threadIdx.x;
  const float4* v1v = (const float4*)(v1 + (size_t)blockIdx.x * IB * DIM);
  #pragma unroll
  for (int p = 0; p < 4; ++p) {
    int e = tid + p * 256;
    int r = e >> 4, q = e & 15;
    float4 f = v1v[e];
    float* d = &s1[r * LDA + q * 4];
    d[0] = f.x; d[1] = f.y; d[2] = f.z; d[3] = f.w;
  }
  const float4* v2v = (const float4*)(v2 + (size_t)blockIdx.y * JB * DIM);
  #pragma unroll
  for (int p = 0; p < 8; ++p) {
    int e = tid + p * 256;
    int r = e >> 4, q = e & 15;
    float4 f = v2v[e];
    float* d = &s2[r * LDA + q * 4];
    d[0] = f.x; d[1] = f.y; d[2] = f.z; d[3] = f.w;
  }
  if (tid < IB) tsum[tid] = 0.0f;
  __syncthreads();

  int i0 = (tid & 15) * 4;
  int j0 = (tid >> 4) * 8;
  float acc[4][8];
  #pragma unroll
  for (int m = 0; m < 4; ++m)
    #pragma unroll
    for (int n = 0; n < 8; ++n) acc[m][n] = 0.0f;
  #pragma unroll 4
  for (int k = 0; k < DIM; ++k) {
    float a[4], b[8];
    #pragma unroll
    for (int m = 0; m < 4; ++m) a[m] = s1[(i0 + m) * LDA + k];
    #pragma unroll
    for (int n = 0; n < 8; ++n) b[n] = s2[(j0 + n) * LDA + k];
    #pragma unroll
    for (int m = 0; m < 4; ++m)
      #pragma unroll
      for (int n = 0; n < 8; ++n) acc[m][n] = fmaf(a[m], b[n], acc[m][n]);
  }
  #pragma unroll
  for (int m = 0; m < 4; ++m) {
    float ts = 0.0f;
    #pragma unroll
    for (int n = 0; n < 8; ++n) ts += __expf(acc[m][n] * INV_TEMP);
    atomicAdd(&tsum[i0 + m], ts);
  }
  __syncthreads();
  if (tid < IB) atomicAdd(&ttl[blockIdx.x * IB + tid], tsum[tid]);
}

// ---------------- InfoNCE phase 2: diagonal + log, block-reduced --------------
// 64 blocks x 256; grid-stride over rows; 1 atomic per block
__global__ __launch_bounds__(256) void nce_final(const float* __restrict__ v1,
                                                 const float* __restrict__ v2,
                                                 const float* __restrict__ ttl,
                                                 float* __restrict__ acc) {
  __shared__ float red[4];
  int tid = threadIdx.x, lane = tid & 63, wv = tid >> 6;
  int gw = blockIdx.x * 4 + wv;          // 256 waves total
  float l = 0.f;
  for (int r = gw; r < BATCH; r += 256) {
    int gid = r * 64 + lane;
    float p = v1[gid] * v2[gid];
    #pragma unroll
    for (int m = 32; m; m >>= 1) p += __shfl_xor(p, m);
    if (lane == 0) l += -logf(__expf(p * INV_TEMP) / ttl[r] + 1e-5f);
  }
  if (lane == 0) red[wv] = l;
  __syncthreads();
  if (tid == 0) atomicAdd(acc, red[0] + red[1] + red[2] + red[3]);
}

// ---------------- BPR rec loss + reg, block-reduced ----------------
__global__ __launch_bounds__(256) void rec_kernel(const float* __restrict__ ue,
                                                  const float* __restrict__ pe,
                                                  const float* __restrict__ ne,
                                                  float* __restrict__ acc) {
  __shared__ float red[3][4];
  int tid = threadIdx.x, lane = tid & 63, wv = tid >> 6;
  int gw = blockIdx.x * 4 + wv;          // 256 waves total
  const float third = 1.0f / 3.0f;
  float l = 0.f, su = 0.f, sp = 0.f;
  for (int r = gw; r < BATCH; r += 256) {
    int gid = r * 64 + lane;
    float u = ue[gid] * third, p = pe[gid] * third, n = ne[gid] * third;
    float ps = u * p, ns = u * n;
    su += u * u; sp += p * p;
    #pragma unroll
    for (int m = 32; m; m >>= 1) { ps += __shfl_xor(ps, m); ns += __shfl_xor(ns, m); }
    if (lane == 0) {
      float sig = 1.0f / (1.0f + __expf(-(ps - ns)));
      l += -logf(1e-5f + sig);
    }
  }
  #pragma unroll
  for (int m = 32; m; m >>= 1) { su += __shfl_xor(su, m); sp += __shfl_xor(sp, m); }
  if (lane == 0) { red[0][wv] = l; red[1][wv] = su; red[2][wv] = sp; }
  __syncthreads();
  if (tid == 0) {
    atomicAdd(acc + 0, red[0][0] + red[0][1] + red[0][2] + red[0][3]);
    atomicAdd(acc + 1, red[1][0] + red[1][1] + red[1][2] + red[1][3]);
    atomicAdd(acc + 2, red[2][0] + red[2][1] + red[2][2] + red[2][3]);
  }
}

__global__ void finalize_kernel(const float* __restrict__ acc, float* __restrict__ out) {
  out[0] = acc[0] * (1.0f / BATCH)
         + 1e-4f * (sqrtf(acc[1]) + sqrtf(acc[2]))
         + 0.5f * (acc[3] + acc[4]) * (1.0f / BATCH);
}

extern "C" void kernel_launch(void* const* d_in, const int* in_sizes, int n_in,
                              void* d_out, int out_size, void* d_ws, size_t ws_size,
                              hipStream_t stream) {
  (void)in_sizes; (void)n_in; (void)out_size;
  const float* user_embed = (const float*)d_in[0];
  const float* item_embed = (const float*)d_in[1];
  const float* adj_vals   = (const float*)d_in[2];
  const int*   adj_rows   = (const int*)d_in[3];
  const int*   adj_cols   = (const int*)d_in[4];
  const int*   users      = (const int*)d_in[5];
  const int*   pos_items  = (const int*)d_in[6];
  const int*   neg_items  = (const int*)d_in[7];
  float* out = (float*)d_out;

  const size_t bufElems = (size_t)NTOT * DIM;
  const size_t tailBytes = (size_t)NNZC * 8 + GELEMS * 4
                         + ((size_t)(NTOT + 1) + NTOT + 512) * 4;
  const bool fast = ws_size >= 6 * bufElems * 4 + tailBytes;
  const int nbuf = fast ? 6 : 2;

  // ---- workspace layout (16B-aligned regions first) ----
  float* buf0  = (float*)d_ws;                              // nbuf * bufElems
  int2*  pairs = (int2*)(buf0 + (size_t)nbuf * bufElems);   // NNZC
  float* g     = (float*)(pairs + NNZC);                    // GELEMS
  float* g_ue = g + 0 * (size_t)B64;
  float* g_pe = g + 1 * (size_t)B64;
  float* g_ne = g + 2 * (size_t)B64;
  float* g_u1 = g + 3 * (size_t)B64;
  float* g_i1 = g + 4 * (size_t)B64;
  float* g_u2 = g + 5 * (size_t)B64;
  float* g_i2 = g + 6 * (size_t)B64;
  float* ttl_u = g + 7 * (size_t)B64;
  float* ttl_i = ttl_u + BATCH;
  float* acc   = ttl_i + BATCH;       // 8 scalars
  int* rs     = (int*)(g + GELEMS);   // NTOT+1
  int* cursor = rs + (NTOT + 1);      // NTOT
  int* bsums  = cursor + NTOT;        // 512

  hipMemsetAsync(g, 0, GELEMS * sizeof(float), stream);
  hipMemsetAsync(cursor, 0, (size_t)NTOT * sizeof(int), stream);

  // ---- CSR build ----
  const int nnz_blocks = (NNZC + 255) / 256;
  hist_kernel<<<(NNZC / 4 + 255) / 256, 256, 0, stream>>>((const int4*)adj_rows, cursor);
  scan_block<<<NSCAN_BLOCKS, 256, 0, stream>>>(cursor, rs, bsums);
  scan_sums<<<1, 512, 0, stream>>>(bsums, NSCAN_BLOCKS);
  add_offsets<<<(NTOT + 255) / 256, 256, 0, stream>>>(rs, bsums);
  hipMemcpyAsync(cursor, rs, (size_t)NTOT * sizeof(int),
                 hipMemcpyDeviceToDevice, stream);
  scatter_csr<<<nnz_blocks, 256, 0, stream>>>(adj_vals, adj_rows, adj_cols,
                                              cursor, pairs);

  const int spmm_blocks = NTOT / 16;           // 4 rows per wave, 4 waves/block
  const int gat7_blocks = 7 * B64 / 256;       // 7168
  const int gat_blocks  = B64 / 256;           // 1024

  if (fast) {
    float* B0 = buf0;
    float* A0 = buf0 + 1 * bufElems;
    float* A1 = buf0 + 2 * bufElems;
    float* A2 = buf0 + 3 * bufElems;
    float* B1 = buf0 + 4 * bufElems;
    float* B2 = buf0 + 5 * bufElems;
    // hop 0: reads virtual concat directly (no memcpy)
    spmm3<true><<<spmm_blocks, 256, 0, stream>>>(pairs, rs, user_embed, user_embed,
                                                 user_embed, item_embed,
                                                 A0, A1, A2, 0u);
    gather7<<<gat7_blocks, 256, 0, stream>>>(A0, A1, A2, users, pos_items,
                                             neg_items, g);
    spmm3<false><<<spmm_blocks, 256, 0, stream>>>(pairs, rs, A0, A1, A2, nullptr,
                                                  B0, B1, B2, 1u);
    gather7<<<gat7_blocks, 256, 0, stream>>>(B0, B1, B2, users, pos_items,
                                             neg_items, g);
    spmm3<false><<<spmm_blocks, 256, 0, stream>>>(pairs, rs, B0, B1, B2, nullptr,
                                                  A0, A1, A2, 2u);
    gather7<<<gat7_blocks, 256, 0, stream>>>(A0, A1, A2, users, pos_items,
                                             neg_items, g);
  } else {
    float* bufA = buf0;
    float* bufB = buf0 + bufElems;
    for (int p = 0; p < 3; ++p) {
      hipMemcpyAsync(bufA, user_embed, (size_t)NUSERS * DIM * sizeof(float),
                     hipMemcpyDeviceToDevice, stream);
      hipMemcpyAsync(bufA + (size_t)NUSERS * DIM, item_embed,
                     (size_t)NITEMS * DIM * sizeof(float),
                     hipMemcpyDeviceToDevice, stream);
      float* cur = bufA;
      float* nxt = bufB;
      uint32_t seed = (p == 1) ? 101u : 202u;
      for (uint32_t h = 0; h < 3; ++h) {
        if (p == 0)
          spmm1<false><<<spmm_blocks, 256, 0, stream>>>(pairs, rs, cur, nxt, 0u, h);
        else
          spmm1<true><<<spmm_blocks, 256, 0, stream>>>(pairs, rs, cur, nxt, seed, h);
        if (p == 0) {
          gather_add<<<gat_blocks, 256, 0, stream>>>(nxt, users, 0, g_ue);
          gather_add<<<gat_blocks, 256, 0, stream>>>(nxt, pos_items, NUSERS, g_pe);
          gather_add<<<gat_blocks, 256, 0, stream>>>(nxt, neg_items, NUSERS, g_ne);
        } else if (p == 1) {
          gather_add<<<gat_blocks, 256, 0, stream>>>(nxt, users, 0, g_u1);
          gather_add<<<gat_blocks, 256, 0, stream>>>(nxt, pos_items, NUSERS, g_i1);
        } else {
          gather_add<<<gat_blocks, 256, 0, stream>>>(nxt, users, 0, g_u2);
          gather_add<<<gat_blocks, 256, 0, stream>>>(nxt, pos_items, NUSERS, g_i2);
        }
        float* t = cur; cur = nxt; nxt = t;
      }
    }
  }

  rec_kernel<<<64, 256, 0, stream>>>(g_ue, g_pe, g_ne, acc);
  rownorm_kernel<<<gat_blocks, 256, 0, stream>>>(g_u1);
  rownorm_kernel<<<gat_blocks, 256, 0, stream>>>(g_u2);
  rownorm_kernel<<<gat_blocks, 256, 0, stream>>>(g_i1);
  rownorm_kernel<<<gat_blocks, 256, 0, stream>>>(g_i2);

  dim3 nce_grid(BATCH / IB, BATCH / JB);
  nce_ttl<<<nce_grid, 256, 0, stream>>>(g_u1, g_u2, ttl_u);
  nce_ttl<<<nce_grid, 256, 0, stream>>>(g_i1, g_i2, ttl_i);
  nce_final<<<64, 256, 0, stream>>>(g_u1, g_u2, ttl_u, acc + 3);
  nce_final<<<64, 256, 0, stream>>>(g_i1, g_i2, ttl_i, acc + 4);
  finalize_kernel<<<1, 1, 0, stream>>>(acc, out);
}

// Round 6
// 1732.711 us; speedup vs baseline: 4.5657x; 1.0895x over previous
//
#include <hip/hip_runtime.h>
#include <stdint.h>

#define NUSERS  200000
#define NITEMS  100000
#define NTOT    300000
#define DIM     64
#define NU64    (NUSERS * DIM)
#define NNZC    3000000
#define BATCH   4096
#define B64     (BATCH * DIM)
#define EPSP    0.1f
#define INV_TEMP 5.0f   // 1 / 0.2
#define SCAN_ELEMS 1024
#define NSCAN_BLOCKS ((NTOT + SCAN_ELEMS - 1) / SCAN_ELEMS)   // 293
#define IB 64
#define JB 128
#define LDA 65
#define GELEMS ((size_t)7 * B64 + 2 * BATCH + 8)

// ---- binned CSR build params ----
#define BSHIFT 11
#define BROWS  (1 << BSHIFT)                       // 2048 rows per bucket
#define NB     ((NTOT + BROWS - 1) / BROWS)        // 147 buckets
#define CHUNK  4096
#define NCHUNK ((NNZC + CHUNK - 1) / CHUNK)        // 733
#define NH     (NB * NCHUNK)                       // 107751

// ---------------- Threefry-2x32 (JAX-compatible) ----------------
__device__ __forceinline__ uint32_t rotl32(uint32_t v, int r) {
  return (v << r) | (v >> (32 - r));
}

__device__ __forceinline__ void tf2x32(uint32_t k0, uint32_t k1,
                                       uint32_t x0, uint32_t x1,
                                       uint32_t &o0, uint32_t &o1) {
  uint32_t k2 = k0 ^ k1 ^ 0x1BD11BDAu;
#define TFR(r) { x0 += x1; x1 = rotl32(x1, (r)); x1 ^= x0; }
  x0 += k0; x1 += k1;
  TFR(13) TFR(15) TFR(26) TFR(6)
  x0 += k1; x1 += k2 + 1u;
  TFR(17) TFR(29) TFR(16) TFR(24)
  x0 += k2; x1 += k0 + 2u;
  TFR(13) TFR(15) TFR(26) TFR(6)
  x0 += k0; x1 += k1 + 3u;
  TFR(17) TFR(29) TFR(16) TFR(24)
  x0 += k1; x1 += k2 + 4u;
  TFR(13) TFR(15) TFR(26) TFR(6)
  x0 += k2; x1 += k0 + 5u;
#undef TFR
  o0 = x0; o1 = x1;
}

__device__ __forceinline__ float tf_unif(uint32_t k0, uint32_t k1, uint32_t e) {
  uint32_t b0, b1;
  tf2x32(k0, k1, 0u, e, b0, b1);
  return __uint_as_float(((b0 ^ b1) >> 9) | 0x3F800000u) - 1.0f;
}

__device__ __forceinline__ float sgnf(float a) {
  return (a > 0.f) ? 1.f : ((a < 0.f) ? -1.f : 0.f);
}

// ---------------- row-count histogram (for rs) ----------------
__global__ void hist_kernel(const int4* __restrict__ rows4, int* __restrict__ cnt) {
  int i = blockIdx.x * blockDim.x + threadIdx.x;
  if (i < NNZC / 4) {
    int4 r = rows4[i];
    atomicAdd(&cnt[r.x], 1);
    atomicAdd(&cnt[r.y], 1);
    atomicAdd(&cnt[r.z], 1);
    atomicAdd(&cnt[r.w], 1);
  }
}

// ---------------- generic hierarchical exclusive scan ----------------
__global__ void scan_block(const int* __restrict__ cnt, int* __restrict__ out,
                           int* __restrict__ bsums, int n) {
  __shared__ int tmp[SCAN_ELEMS];
  int base = blockIdx.x * SCAN_ELEMS;
  int t = threadIdx.x;                 // 256 threads
  #pragma unroll
  for (int q = 0; q < 4; ++q) {
    int k = t + q * 256, i = base + k;
    tmp[k] = (i < n) ? cnt[i] : 0;
  }
  __syncthreads();
  for (int off = 1; off < SCAN_ELEMS; off <<= 1) {
    int v[4];
    #pragma unroll
    for (int q = 0; q < 4; ++q) {
      int k = t + q * 256;
      v[q] = (k >= off) ? tmp[k - off] : 0;
    }
    __syncthreads();
    #pragma unroll
    for (int q = 0; q < 4; ++q) tmp[t + q * 256] += v[q];
    __syncthreads();
  }
  #pragma unroll
  for (int q = 0; q < 4; ++q) {
    int k = t + q * 256, i = base + k;
    if (i < n) out[i] = (k == 0) ? 0 : tmp[k - 1];
  }
  if (t == 0) bsums[blockIdx.x] = tmp[SCAN_ELEMS - 1];
}

__global__ void scan_sums(int* __restrict__ bsums, int nb) {
  __shared__ int tmp[512];
  int t = threadIdx.x;
  tmp[t] = (t < nb) ? bsums[t] : 0;
  __syncthreads();
  for (int off = 1; off < 512; off <<= 1) {
    int v = (t >= off) ? tmp[t - off] : 0;
    __syncthreads();
    tmp[t] += v;
    __syncthreads();
  }
  if (t < nb) bsums[t] = (t == 0) ? 0 : tmp[t - 1];
}

__global__ void add_offsets(int* __restrict__ out, const int* __restrict__ bsums,
                            int n, int tailIdx, int tailVal) {
  int i = blockIdx.x * blockDim.x + threadIdx.x;
  if (i < n) out[i] += bsums[i / SCAN_ELEMS];
  if (i == 0 && tailIdx >= 0) out[tailIdx] = tailVal;
}

// ---------------- partA: per-chunk bucket histogram ----------------
__global__ __launch_bounds__(256) void partA(const int* __restrict__ rows,
                                             int* __restrict__ Hcnt) {
  __shared__ int cnt[256];
  int c = blockIdx.x, t = threadIdx.x;
  cnt[t] = 0;
  __syncthreads();
  int base = c * CHUNK;
  for (int i = t; i < CHUNK; i += 256) {
    int e = base + i;
    if (e < NNZC) atomicAdd(&cnt[rows[e] >> BSHIFT], 1);
  }
  __syncthreads();
  if (t < NB) Hcnt[t * NCHUNK + c] = cnt[t];
}

// ---------------- partB: LDS-bin chunk, write bucket-contiguous, coalesced ----
__global__ __launch_bounds__(256) void partB(const float* __restrict__ vals,
                                             const int* __restrict__ rows,
                                             const int* __restrict__ cols,
                                             const int* __restrict__ Hofs,
                                             int2* __restrict__ midp,
                                             int* __restrict__ midr) {
  __shared__ int2 stv[CHUNK];     // 32 KB
  __shared__ int  str_[CHUNK];    // 16 KB
  __shared__ int  cnt[256];
  __shared__ int  sc[256];
  __shared__ int  adj[NB];
  int c = blockIdx.x, t = threadIdx.x;
  cnt[t] = 0;
  __syncthreads();
  int base = c * CHUNK;
  for (int i = t; i < CHUNK; i += 256) {
    int e = base + i;
    if (e < NNZC) atomicAdd(&cnt[rows[e] >> BSHIFT], 1);
  }
  __syncthreads();
  // exclusive scan of cnt over 256
  sc[t] = cnt[t];
  __syncthreads();
  for (int off = 1; off < 256; off <<= 1) {
    int u = (t >= off) ? sc[t - off] : 0;
    __syncthreads();
    sc[t] += u;
    __syncthreads();
  }
  int excl = sc[t] - cnt[t];
  cnt[t] = excl;                          // becomes LDS cursor
  if (t < NB) adj[t] = Hofs[t * NCHUNK + c] - excl;
  __syncthreads();
  // stage into LDS ordered by bucket
  for (int i = t; i < CHUNK; i += 256) {
    int e = base + i;
    if (e < NNZC) {
      int r = rows[e];
      int b = r >> BSHIFT;
      int p = atomicAdd(&cnt[b], 1);
      stv[p] = make_int2(__float_as_int(vals[e]), cols[e] * DIM);
      str_[p] = r;
    }
  }
  __syncthreads();
  int n = NNZC - base;
  if (n > CHUNK) n = CHUNK;
  for (int p = t; p < n; p += 256) {
    int r = str_[p];
    int b = r >> BSHIFT;
    int dst = adj[b] + p;
    midp[dst] = stv[p];
    midr[dst] = r;
  }
}

// ---------------- partC: one block per bucket, place via LDS cursors ----------
__global__ __launch_bounds__(256) void partC(const int2* __restrict__ midp,
                                             const int* __restrict__ midr,
                                             const int* __restrict__ Hofs,
                                             const int* __restrict__ rs,
                                             int2* __restrict__ pairs) {
  __shared__ int cur[BROWS];
  int b = blockIdx.x, t = threadIdx.x;
  int row0 = b << BSHIFT;
  for (int i = t; i < BROWS; i += 256) {
    int r = row0 + i;
    cur[i] = (r < NTOT) ? rs[r] : 0;
  }
  __syncthreads();
  int s = Hofs[b * NCHUNK];
  int e = (b + 1 < NB) ? Hofs[(b + 1) * NCHUNK] : NNZC;
  for (int p = s + t; p < e; p += 256) {
    union { long long ll; int2 v; } ur, up;
    int r = midr[p];
    up.v = midp[p];
    int pos = atomicAdd(&cur[r - row0], 1);
    pairs[pos] = up.v;
    (void)ur;
  }
}

// ---------------- fused 3-branch SpMM, 4 rows/wave, 16 lanes x float4 --------
// HOP0: x1==x2==x0 == virtual concat(x0=user_embed, xb=item_embed); single gather.
template <bool HOP0>
__global__ __launch_bounds__(256) void spmm3(
    const int2* __restrict__ pairs, const int* __restrict__ rs,
    const float* __restrict__ x0, const float* __restrict__ x1,
    const float* __restrict__ x2, const float* __restrict__ xb,
    float* __restrict__ y0, float* __restrict__ y1, float* __restrict__ y2,
    uint32_t hop) {
  int tid  = threadIdx.x;
  int lane = tid & 63;
  int q    = lane & 15;
  int wave = (blockIdx.x * 256 + tid) >> 6;
  int r    = wave * 4 + (lane >> 4);           // grid exact: no guard needed
  int s    = rs[r];
  int cnt  = rs[r + 1] - s;
  int mc = cnt;
  mc = max(mc, __shfl_xor(mc, 16));
  mc = max(mc, __shfl_xor(mc, 32));
  float a0[4] = {0.f, 0.f, 0.f, 0.f};
  float a1[4] = {0.f, 0.f, 0.f, 0.f};
  float a2[4] = {0.f, 0.f, 0.f, 0.f};
  int grpbase = lane & 48;
  int q4 = q * 4;
  for (int ch = 0; ch < mc; ch += 16) {
    union { long long ll; int2 v; } u;
    u.ll = 0;
    if (ch + q < cnt)
      u.ll = __builtin_nontemporal_load((const long long*)(pairs + s + ch + q));
    int2 pv = u.v;
    int m = (mc - ch < 16) ? (mc - ch) : 16;
    for (int j = 0; j < m; ++j) {
      int sl = grpbase + j;
      float v = __uint_as_float((unsigned)__shfl(pv.x, sl));
      unsigned o = (unsigned)(__shfl(pv.y, sl) + q4);
      if (HOP0) {
        const float4* p4 = (o < (unsigned)NU64)
                         ? (const float4*)(x0 + o)
                         : (const float4*)(xb + (o - (unsigned)NU64));
        float4 f0 = *p4;
        a0[0] = fmaf(v, f0.x, a0[0]); a0[1] = fmaf(v, f0.y, a0[1]);
        a0[2] = fmaf(v, f0.z, a0[2]); a0[3] = fmaf(v, f0.w, a0[3]);
      } else {
        float4 f0 = *(const float4*)(x0 + o);
        float4 f1 = *(const float4*)(x1 + o);
        float4 f2 = *(const float4*)(x2 + o);
        a0[0] = fmaf(v, f0.x, a0[0]); a0[1] = fmaf(v, f0.y, a0[1]);
        a0[2] = fmaf(v, f0.z, a0[2]); a0[3] = fmaf(v, f0.w, a0[3]);
        a1[0] = fmaf(v, f1.x, a1[0]); a1[1] = fmaf(v, f1.y, a1[1]);
        a1[2] = fmaf(v, f1.z, a1[2]); a1[3] = fmaf(v, f1.w, a1[3]);
        a2[0] = fmaf(v, f2.x, a2[0]); a2[1] = fmaf(v, f2.y, a2[1]);
        a2[2] = fmaf(v, f2.z, a2[2]); a2[3] = fmaf(v, f2.w, a2[3]);
      }
    }
  }
  // ---- fused SimGCL noise for branches 1,2 ----
  uint32_t kA0, kA1, kB0, kB1;
  tf2x32(0u, 101u, 0u, hop, kA0, kA1);
  tf2x32(0u, 202u, 0u, hop, kB0, kB1);
  int ebase = r * 64 + q4;
  float u1[4], u2[4];
  float ss1 = 0.f, ss2 = 0.f;
  #pragma unroll
  for (int k = 0; k < 4; ++k) {
    u1[k] = tf_unif(kA0, kA1, (uint32_t)(ebase + k));
    u2[k] = tf_unif(kB0, kB1, (uint32_t)(ebase + k));
    ss1 += u1[k] * u1[k];
    ss2 += u2[k] * u2[k];
  }
  #pragma unroll
  for (int msk = 1; msk < 16; msk <<= 1) {
    ss1 += __shfl_xor(ss1, msk);
    ss2 += __shfl_xor(ss2, msk);
  }
  float sc1 = EPSP / fmaxf(sqrtf(ss1), 1e-12f);
  float sc2 = EPSP / fmaxf(sqrtf(ss2), 1e-12f);
  float r0[4], r1[4], r2[4];
  #pragma unroll
  for (int k = 0; k < 4; ++k) {
    float b1v = HOP0 ? a0[k] : a1[k];
    float b2v = HOP0 ? a0[k] : a2[k];
    r0[k] = a0[k];
    r1[k] = b1v + sgnf(b1v) * u1[k] * sc1;
    r2[k] = b2v + sgnf(b2v) * u2[k] * sc2;
  }
  *(float4*)(y0 + ebase) = make_float4(r0[0], r0[1], r0[2], r0[3]);
  *(float4*)(y1 + ebase) = make_float4(r1[0], r1[1], r1[2], r1[3]);
  *(float4*)(y2 + ebase) = make_float4(r2[0], r2[1], r2[2], r2[3]);
}

// ---------------- single-branch SpMM (fallback path) ----------------
template <bool PERT>
__global__ __launch_bounds__(256) void spmm1(
    const int2* __restrict__ pairs, const int* __restrict__ rs,
    const float* __restrict__ x, float* __restrict__ y,
    uint32_t seed, uint32_t hop) {
  int tid  = threadIdx.x;
  int lane = tid & 63;
  int q    = lane & 15;
  int wave = (blockIdx.x * 256 + tid) >> 6;
  int r    = wave * 4 + (lane >> 4);
  int s    = rs[r];
  int cnt  = rs[r + 1] - s;
  int mc = cnt;
  mc = max(mc, __shfl_xor(mc, 16));
  mc = max(mc, __shfl_xor(mc, 32));
  float a0[4] = {0.f, 0.f, 0.f, 0.f};
  int grpbase = lane & 48;
  int q4 = q * 4;
  for (int ch = 0; ch < mc; ch += 16) {
    int2 pv = make_int2(0, 0);
    if (ch + q < cnt) pv = pairs[s + ch + q];
    int m = (mc - ch < 16) ? (mc - ch) : 16;
    for (int j = 0; j < m; ++j) {
      int sl = grpbase + j;
      float v = __uint_as_float((unsigned)__shfl(pv.x, sl));
      unsigned o = (unsigned)(__shfl(pv.y, sl) + q4);
      float4 f0 = *(const float4*)(x + o);
      a0[0] = fmaf(v, f0.x, a0[0]); a0[1] = fmaf(v, f0.y, a0[1]);
      a0[2] = fmaf(v, f0.z, a0[2]); a0[3] = fmaf(v, f0.w, a0[3]);
    }
  }
  int ebase = r * 64 + q4;
  if (PERT) {
    uint32_t k0, k1;
    tf2x32(0u, seed, 0u, hop, k0, k1);
    float u[4], ss = 0.f;
    #pragma unroll
    for (int k = 0; k < 4; ++k) {
      u[k] = tf_unif(k0, k1, (uint32_t)(ebase + k));
      ss += u[k] * u[k];
    }
    #pragma unroll
    for (int msk = 1; msk < 16; msk <<= 1) ss += __shfl_xor(ss, msk);
    float sc = EPSP / fmaxf(sqrtf(ss), 1e-12f);
    #pragma unroll
    for (int k = 0; k < 4; ++k) a0[k] += sgnf(a0[k]) * u[k] * sc;
  }
  *(float4*)(y + ebase) = make_float4(a0[0], a0[1], a0[2], a0[3]);
}

// ---------------- gather all 7 batch selections in one launch ----------------
__global__ void gather7(const float* __restrict__ y0, const float* __restrict__ y1,
                        const float* __restrict__ y2,
                        const int* __restrict__ users, const int* __restrict__ pos,
                        const int* __restrict__ neg, float* __restrict__ g) {
  int gid = blockIdx.x * blockDim.x + threadIdx.x;   // 7*B64 threads
  int which = gid >> 18;                             // B64 == 1<<18
  int sub = gid & (B64 - 1);
  int b = sub >> 6, d = sub & 63;
  const float* y = (which < 3) ? y0 : ((which < 5) ? y1 : y2);
  const int* idx;
  int base;
  switch (which) {
    case 0: idx = users; base = 0;      break;
    case 1: idx = pos;   base = NUSERS; break;
    case 2: idx = neg;   base = NUSERS; break;
    case 3: idx = users; base = 0;      break;
    case 4: idx = pos;   base = NUSERS; break;
    case 5: idx = users; base = 0;      break;
    default: idx = pos;  base = NUSERS; break;
  }
  g[gid] += y[(size_t)(base + idx[b]) * DIM + d];
}

// ---------------- fallback per-branch gather ----------------
__global__ void gather_add(const float* __restrict__ src,
                           const int* __restrict__ idx,
                           int base, float* __restrict__ dst) {
  int gid = blockIdx.x * blockDim.x + threadIdx.x;
  int b = gid >> 6, d = gid & 63;
  if (b >= BATCH) return;
  int r = base + idx[b];
  dst[gid] += src[(size_t)r * DIM + d];
}

// ---------------- row-normalize (clamp 1e-12) ----------------
__global__ void rownorm_kernel(float* __restrict__ v) {
  int gid = blockIdx.x * blockDim.x + threadIdx.x;
  if ((gid >> 6) >= BATCH) return;
  float x = v[gid];
  float ss = x * x;
  #pragma unroll
  for (int m = 32; m; m >>= 1) ss += __shfl_xor(ss, m);
  v[gid] = x / fmaxf(sqrtf(ss), 1e-12f);
}

// ---------------- InfoNCE phase 1: tiled exp-GEMM row sums --------------------
__global__ __launch_bounds__(256) void nce_ttl(const float* __restrict__ v1,
                                               const float* __restrict__ v2,
                                               float* __restrict__ ttl) {
  __shared__ float s1[IB * LDA];
  __shared__ float s2[JB * LDA];
  __shared__ float tsum[IB];
  int tid = threadIdx.x;
  const float4* v1v = (const float4*)(v1 + (size_t)blockIdx.x * IB * DIM);
  #pragma unroll
  for (int p = 0; p < 4; ++p) {
    int e = tid + p * 256;
    int r = e >> 4, q = e & 15;
    float4 f = v1v[e];
    float* d = &s1[r * LDA + q * 4];
    d[0] = f.x; d[1] = f.y; d[2] = f.z; d[3] = f.w;
  }
  const float4* v2v = (const float4*)(v2 + (size_t)blockIdx.y * JB * DIM);
  #pragma unroll
  for (int p = 0; p < 8; ++p) {
    int e = tid + p * 256;
    int r = e >> 4, q = e & 15;
    float4 f = v2v[e];
    float* d = &s2[r * LDA + q * 4];
    d[0] = f.x; d[1] = f.y; d[2] = f.z; d[3] = f.w;
  }
  if (tid < IB) tsum[tid] = 0.0f;
  __syncthreads();

  int i0 = (tid & 15) * 4;
  int j0 = (tid >> 4) * 8;
  float acc[4][8];
  #pragma unroll
  for (int m = 0; m < 4; ++m)
    #pragma unroll
    for (int n = 0; n < 8; ++n) acc[m][n] = 0.0f;
  #pragma unroll 4
  for (int k = 0; k < DIM; ++k) {
    float a[4], b[8];
    #pragma unroll
    for (int m = 0; m < 4; ++m) a[m] = s1[(i0 + m) * LDA + k];
    #pragma unroll
    for (int n = 0; n < 8; ++n) b[n] = s2[(j0 + n) * LDA + k];
    #pragma unroll
    for (int m = 0; m < 4; ++m)
      #pragma unroll
      for (int n = 0; n < 8; ++n) acc[m][n] = fmaf(a[m], b[n], acc[m][n]);
  }
  #pragma unroll
  for (int m = 0; m < 4; ++m) {
    float ts = 0.0f;
    #pragma unroll
    for (int n = 0; n < 8; ++n) ts += __expf(acc[m][n] * INV_TEMP);
    atomicAdd(&tsum[i0 + m], ts);
  }
  __syncthreads();
  if (tid < IB) atomicAdd(&ttl[blockIdx.x * IB + tid], tsum[tid]);
}

// ---------------- InfoNCE phase 2: diagonal + log, block-reduced --------------
__global__ __launch_bounds__(256) void nce_final(const float* __restrict__ v1,
                                                 const float* __restrict__ v2,
                                                 const float* __restrict__ ttl,
                                                 float* __restrict__ acc) {
  __shared__ float red[4];
  int tid = threadIdx.x, lane = tid & 63, wv = tid >> 6;
  int gw = blockIdx.x * 4 + wv;          // 256 waves total
  float l = 0.f;
  for (int r = gw; r < BATCH; r += 256) {
    int gid = r * 64 + lane;
    float p = v1[gid] * v2[gid];
    #pragma unroll
    for (int m = 32; m; m >>= 1) p += __shfl_xor(p, m);
    if (lane == 0) l += -logf(__expf(p * INV_TEMP) / ttl[r] + 1e-5f);
  }
  if (lane == 0) red[wv] = l;
  __syncthreads();
  if (tid == 0) atomicAdd(acc, red[0] + red[1] + red[2] + red[3]);
}

// ---------------- BPR rec loss + reg, block-reduced ----------------
__global__ __launch_bounds__(256) void rec_kernel(const float* __restrict__ ue,
                                                  const float* __restrict__ pe,
                                                  const float* __restrict__ ne,
                                                  float* __restrict__ acc) {
  __shared__ float red[3][4];
  int tid = threadIdx.x, lane = tid & 63, wv = tid >> 6;
  int gw = blockIdx.x * 4 + wv;          // 256 waves total
  const float third = 1.0f / 3.0f;
  float l = 0.f, su = 0.f, sp = 0.f;
  for (int r = gw; r < BATCH; r += 256) {
    int gid = r * 64 + lane;
    float u = ue[gid] * third, p = pe[gid] * third, n = ne[gid] * third;
    float ps = u * p, ns = u * n;
    su += u * u; sp += p * p;
    #pragma unroll
    for (int m = 32; m; m >>= 1) { ps += __shfl_xor(ps, m); ns += __shfl_xor(ns, m); }
    if (lane == 0) {
      float sig = 1.0f / (1.0f + __expf(-(ps - ns)));
      l += -logf(1e-5f + sig);
    }
  }
  #pragma unroll
  for (int m = 32; m; m >>= 1) { su += __shfl_xor(su, m); sp += __shfl_xor(sp, m); }
  if (lane == 0) { red[0][wv] = l; red[1][wv] = su; red[2][wv] = sp; }
  __syncthreads();
  if (tid == 0) {
    atomicAdd(acc + 0, red[0][0] + red[0][1] + red[0][2] + red[0][3]);
    atomicAdd(acc + 1, red[1][0] + red[1][1] + red[1][2] + red[1][3]);
    atomicAdd(acc + 2, red[2][0] + red[2][1] + red[2][2] + red[2][3]);
  }
}

__global__ void finalize_kernel(const float* __restrict__ acc, float* __restrict__ out) {
  out[0] = acc[0] * (1.0f / BATCH)
         + 1e-4f * (sqrtf(acc[1]) + sqrtf(acc[2]))
         + 0.5f * (acc[3] + acc[4]) * (1.0f / BATCH);
}

extern "C" void kernel_launch(void* const* d_in, const int* in_sizes, int n_in,
                              void* d_out, int out_size, void* d_ws, size_t ws_size,
                              hipStream_t stream) {
  (void)in_sizes; (void)n_in; (void)out_size;
  const float* user_embed = (const float*)d_in[0];
  const float* item_embed = (const float*)d_in[1];
  const float* adj_vals   = (const float*)d_in[2];
  const int*   adj_rows   = (const int*)d_in[3];
  const int*   adj_cols   = (const int*)d_in[4];
  const int*   users      = (const int*)d_in[5];
  const int*   pos_items  = (const int*)d_in[6];
  const int*   neg_items  = (const int*)d_in[7];
  float* out = (float*)d_out;

  const size_t bufElems = (size_t)NTOT * DIM;
  const size_t tailBytes = (size_t)NNZC * 8 + GELEMS * 4
                         + ((size_t)(NTOT + 1) + NTOT + 512) * 4;
  const bool fast = ws_size >= 6 * bufElems * 4 + tailBytes;
  const int nbuf = fast ? 6 : 2;

  // ---- workspace layout ----
  float* buf0  = (float*)d_ws;                              // nbuf * bufElems
  int2*  pairs = (int2*)(buf0 + (size_t)nbuf * bufElems);   // NNZC
  float* g     = (float*)(pairs + NNZC);                    // GELEMS
  float* g_ue = g + 0 * (size_t)B64;
  float* g_pe = g + 1 * (size_t)B64;
  float* g_ne = g + 2 * (size_t)B64;
  float* g_u1 = g + 3 * (size_t)B64;
  float* g_i1 = g + 4 * (size_t)B64;
  float* g_u2 = g + 5 * (size_t)B64;
  float* g_i2 = g + 6 * (size_t)B64;
  float* ttl_u = g + 7 * (size_t)B64;
  float* ttl_i = ttl_u + BATCH;
  float* acc   = ttl_i + BATCH;       // 8 scalars
  int* rs     = (int*)(g + GELEMS);   // NTOT+1
  int* cursor = rs + (NTOT + 1);      // NTOT (row-count scratch)
  int* bsums  = cursor + NTOT;        // 512

  // build-time scratch aliased into buf0 (free until first spmm)
  int2* midp = (int2*)buf0;           // NNZC int2 = 24 MB
  int*  midr = (int*)(midp + NNZC);   // NNZC int  = 12 MB
  int*  Hcnt = midr + NNZC;           // NH
  int*  Hofs = Hcnt + NH;             // NH   (total < 76.8 MB = bufElems*4B)

  hipMemsetAsync(g, 0, GELEMS * sizeof(float), stream);
  hipMemsetAsync(cursor, 0, (size_t)NTOT * sizeof(int), stream);

  // ---- CSR build: rs via hist+scan; pairs via binned two-pass partition ----
  hist_kernel<<<(NNZC / 4 + 255) / 256, 256, 0, stream>>>((const int4*)adj_rows, cursor);
  scan_block<<<NSCAN_BLOCKS, 256, 0, stream>>>(cursor, rs, bsums, NTOT);
  scan_sums<<<1, 512, 0, stream>>>(bsums, NSCAN_BLOCKS);
  add_offsets<<<(NTOT + 255) / 256, 256, 0, stream>>>(rs, bsums, NTOT, NTOT, NNZC);

  partA<<<NCHUNK, 256, 0, stream>>>(adj_rows, Hcnt);
  const int nhb = (NH + SCAN_ELEMS - 1) / SCAN_ELEMS;       // 106
  scan_block<<<nhb, 256, 0, stream>>>(Hcnt, Hofs, bsums, NH);
  scan_sums<<<1, 512, 0, stream>>>(bsums, nhb);
  add_offsets<<<(NH + 255) / 256, 256, 0, stream>>>(Hofs, bsums, NH, -1, 0);

  partB<<<NCHUNK, 256, 0, stream>>>(adj_vals, adj_rows, adj_cols, Hofs, midp, midr);
  partC<<<NB, 256, 0, stream>>>(midp, midr, Hofs, rs, pairs);

  const int spmm_blocks = NTOT / 16;           // 4 rows per wave, 4 waves/block
  const int gat7_blocks = 7 * B64 / 256;       // 7168
  const int gat_blocks  = B64 / 256;           // 1024

  if (fast) {
    float* B0 = buf0;
    float* A0 = buf0 + 1 * bufElems;
    float* A1 = buf0 + 2 * bufElems;
    float* A2 = buf0 + 3 * bufElems;
    float* B1 = buf0 + 4 * bufElems;
    float* B2 = buf0 + 5 * bufElems;
    // hop 0: reads virtual concat directly (no memcpy)
    spmm3<true><<<spmm_blocks, 256, 0, stream>>>(pairs, rs, user_embed, user_embed,
                                                 user_embed, item_embed,
                                                 A0, A1, A2, 0u);
    gather7<<<gat7_blocks, 256, 0, stream>>>(A0, A1, A2, users, pos_items,
                                             neg_items, g);
    spmm3<false><<<spmm_blocks, 256, 0, stream>>>(pairs, rs, A0, A1, A2, nullptr,
                                                  B0, B1, B2, 1u);
    gather7<<<gat7_blocks, 256, 0, stream>>>(B0, B1, B2, users, pos_items,
                                             neg_items, g);
    spmm3<false><<<spmm_blocks, 256, 0, stream>>>(pairs, rs, B0, B1, B2, nullptr,
                                                  A0, A1, A2, 2u);
    gather7<<<gat7_blocks, 256, 0, stream>>>(A0, A1, A2, users, pos_items,
                                             neg_items, g);
  } else {
    float* bufA = buf0;
    float* bufB = buf0 + bufElems;
    for (int p = 0; p < 3; ++p) {
      hipMemcpyAsync(bufA, user_embed, (size_t)NUSERS * DIM * sizeof(float),
                     hipMemcpyDeviceToDevice, stream);
      hipMemcpyAsync(bufA + (size_t)NUSERS * DIM, item_embed,
                     (size_t)NITEMS * DIM * sizeof(float),
                     hipMemcpyDeviceToDevice, stream);
      float* cur = bufA;
      float* nxt = bufB;
      uint32_t seed = (p == 1) ? 101u : 202u;
      for (uint32_t h = 0; h < 3; ++h) {
        if (p == 0)
          spmm1<false><<<spmm_blocks, 256, 0, stream>>>(pairs, rs, cur, nxt, 0u, h);
        else
          spmm1<true><<<spmm_blocks, 256, 0, stream>>>(pairs, rs, cur, nxt, seed, h);
        if (p == 0) {
          gather_add<<<gat_blocks, 256, 0, stream>>>(nxt, users, 0, g_ue);
          gather_add<<<gat_blocks, 256, 0, stream>>>(nxt, pos_items, NUSERS, g_pe);
          gather_add<<<gat_blocks, 256, 0, stream>>>(nxt, neg_items, NUSERS, g_ne);
        } else if (p == 1) {
          gather_add<<<gat_blocks, 256, 0, stream>>>(nxt, users, 0, g_u1);
          gather_add<<<gat_blocks, 256, 0, stream>>>(nxt, pos_items, NUSERS, g_i1);
        } else {
          gather_add<<<gat_blocks, 256, 0, stream>>>(nxt, users, 0, g_u2);
          gather_add<<<gat_blocks, 256, 0, stream>>>(nxt, pos_items, NUSERS, g_i2);
        }
        float* t = cur; cur = nxt; nxt = t;
      }
    }
  }

  rec_kernel<<<64, 256, 0, stream>>>(g_ue, g_pe, g_ne, acc);
  rownorm_kernel<<<gat_blocks, 256, 0, stream>>>(g_u1);
  rownorm_kernel<<<gat_blocks, 256, 0, stream>>>(g_u2);
  rownorm_kernel<<<gat_blocks, 256, 0, stream>>>(g_i1);
  rownorm_kernel<<<gat_blocks, 256, 0, stream>>>(g_i2);

  dim3 nce_grid(BATCH / IB, BATCH / JB);
  nce_ttl<<<nce_grid, 256, 0, stream>>>(g_u1, g_u2, ttl_u);
  nce_ttl<<<nce_grid, 256, 0, stream>>>(g_i1, g_i2, ttl_i);
  nce_final<<<64, 256, 0, stream>>>(g_u1, g_u2, ttl_u, acc + 3);
  nce_final<<<64, 256, 0, stream>>>(g_i1, g_i2, ttl_i, acc + 4);
  finalize_kernel<<<1, 1, 0, stream>>>(acc, out);
}

// Round 7
// 1181.625 us; speedup vs baseline: 6.6950x; 1.4664x over previous
//
#include <hip/hip_runtime.h>
#include <stdint.h>

#define NUSERS  200000
#define NITEMS  100000
#define NTOT    300000
#define DIM     64
#define NU64    (NUSERS * DIM)
#define NNZC    3000000
#define BATCH   4096
#define B64     (BATCH * DIM)
#define EPSP    0.1f
#define INV_TEMP 5.0f   // 1 / 0.2
#define SCAN_ELEMS 1024
#define NSCAN_BLOCKS ((NTOT + SCAN_ELEMS - 1) / SCAN_ELEMS)   // 293
#define IB 64
#define JB 128
#define LDA 65
#define GELEMS ((size_t)7 * B64 + 2 * BATCH + 8)

// ---- binned CSR build params ----
#define BSHIFT 11
#define BROWS  (1 << BSHIFT)                       // 2048 rows per bucket
#define NB     ((NTOT + BROWS - 1) / BROWS)        // 147 buckets
#define CHUNK  4096
#define NCHUNK ((NNZC + CHUNK - 1) / CHUNK)        // 733
#define NH     (NB * NCHUNK)                       // 107751

// ---------------- Threefry-2x32 (JAX-compatible) ----------------
__device__ __forceinline__ uint32_t rotl32(uint32_t v, int r) {
  return (v << r) | (v >> (32 - r));
}

__device__ __forceinline__ void tf2x32(uint32_t k0, uint32_t k1,
                                       uint32_t x0, uint32_t x1,
                                       uint32_t &o0, uint32_t &o1) {
  uint32_t k2 = k0 ^ k1 ^ 0x1BD11BDAu;
#define TFR(r) { x0 += x1; x1 = rotl32(x1, (r)); x1 ^= x0; }
  x0 += k0; x1 += k1;
  TFR(13) TFR(15) TFR(26) TFR(6)
  x0 += k1; x1 += k2 + 1u;
  TFR(17) TFR(29) TFR(16) TFR(24)
  x0 += k2; x1 += k0 + 2u;
  TFR(13) TFR(15) TFR(26) TFR(6)
  x0 += k0; x1 += k1 + 3u;
  TFR(17) TFR(29) TFR(16) TFR(24)
  x0 += k1; x1 += k2 + 4u;
  TFR(13) TFR(15) TFR(26) TFR(6)
  x0 += k2; x1 += k0 + 5u;
#undef TFR
  o0 = x0; o1 = x1;
}

__device__ __forceinline__ float tf_unif(uint32_t k0, uint32_t k1, uint32_t e) {
  uint32_t b0, b1;
  tf2x32(k0, k1, 0u, e, b0, b1);
  return __uint_as_float(((b0 ^ b1) >> 9) | 0x3F800000u) - 1.0f;
}

__device__ __forceinline__ float sgnf(float a) {
  return (a > 0.f) ? 1.f : ((a < 0.f) ? -1.f : 0.f);
}

// ---------------- row-count histogram (for rs) ----------------
__global__ void hist_kernel(const int4* __restrict__ rows4, int* __restrict__ cnt) {
  int i = blockIdx.x * blockDim.x + threadIdx.x;
  if (i < NNZC / 4) {
    int4 r = rows4[i];
    atomicAdd(&cnt[r.x], 1);
    atomicAdd(&cnt[r.y], 1);
    atomicAdd(&cnt[r.z], 1);
    atomicAdd(&cnt[r.w], 1);
  }
}

// ---------------- generic hierarchical exclusive scan ----------------
__global__ void scan_block(const int* __restrict__ cnt, int* __restrict__ out,
                           int* __restrict__ bsums, int n) {
  __shared__ int tmp[SCAN_ELEMS];
  int base = blockIdx.x * SCAN_ELEMS;
  int t = threadIdx.x;                 // 256 threads
  #pragma unroll
  for (int q = 0; q < 4; ++q) {
    int k = t + q * 256, i = base + k;
    tmp[k] = (i < n) ? cnt[i] : 0;
  }
  __syncthreads();
  for (int off = 1; off < SCAN_ELEMS; off <<= 1) {
    int v[4];
    #pragma unroll
    for (int q = 0; q < 4; ++q) {
      int k = t + q * 256;
      v[q] = (k >= off) ? tmp[k - off] : 0;
    }
    __syncthreads();
    #pragma unroll
    for (int q = 0; q < 4; ++q) tmp[t + q * 256] += v[q];
    __syncthreads();
  }
  #pragma unroll
  for (int q = 0; q < 4; ++q) {
    int k = t + q * 256, i = base + k;
    if (i < n) out[i] = (k == 0) ? 0 : tmp[k - 1];
  }
  if (t == 0) bsums[blockIdx.x] = tmp[SCAN_ELEMS - 1];
}

__global__ void scan_sums(int* __restrict__ bsums, int nb) {
  __shared__ int tmp[512];
  int t = threadIdx.x;
  tmp[t] = (t < nb) ? bsums[t] : 0;
  __syncthreads();
  for (int off = 1; off < 512; off <<= 1) {
    int v = (t >= off) ? tmp[t - off] : 0;
    __syncthreads();
    tmp[t] += v;
    __syncthreads();
  }
  if (t < nb) bsums[t] = (t == 0) ? 0 : tmp[t - 1];
}

__global__ void add_offsets(int* __restrict__ out, const int* __restrict__ bsums,
                            int n, int tailIdx, int tailVal) {
  int i = blockIdx.x * blockDim.x + threadIdx.x;
  if (i < n) out[i] += bsums[i / SCAN_ELEMS];
  if (i == 0 && tailIdx >= 0) out[tailIdx] = tailVal;
}

// ---------------- partA: per-chunk bucket histogram ----------------
__global__ __launch_bounds__(256) void partA(const int* __restrict__ rows,
                                             int* __restrict__ Hcnt) {
  __shared__ int cnt[256];
  int c = blockIdx.x, t = threadIdx.x;
  cnt[t] = 0;
  __syncthreads();
  int base = c * CHUNK;
  for (int i = t; i < CHUNK; i += 256) {
    int e = base + i;
    if (e < NNZC) atomicAdd(&cnt[rows[e] >> BSHIFT], 1);
  }
  __syncthreads();
  if (t < NB) Hcnt[t * NCHUNK + c] = cnt[t];
}

// ---------------- partB: LDS-bin chunk, write bucket-contiguous, coalesced ----
__global__ __launch_bounds__(256) void partB(const float* __restrict__ vals,
                                             const int* __restrict__ rows,
                                             const int* __restrict__ cols,
                                             const int* __restrict__ Hofs,
                                             int2* __restrict__ midp,
                                             int* __restrict__ midr) {
  __shared__ int2 stv[CHUNK];     // 32 KB
  __shared__ int  str_[CHUNK];    // 16 KB
  __shared__ int  cnt[256];
  __shared__ int  sc[256];
  __shared__ int  adj[NB];
  int c = blockIdx.x, t = threadIdx.x;
  cnt[t] = 0;
  __syncthreads();
  int base = c * CHUNK;
  for (int i = t; i < CHUNK; i += 256) {
    int e = base + i;
    if (e < NNZC) atomicAdd(&cnt[rows[e] >> BSHIFT], 1);
  }
  __syncthreads();
  sc[t] = cnt[t];
  __syncthreads();
  for (int off = 1; off < 256; off <<= 1) {
    int u = (t >= off) ? sc[t - off] : 0;
    __syncthreads();
    sc[t] += u;
    __syncthreads();
  }
  int excl = sc[t] - cnt[t];
  cnt[t] = excl;                          // becomes LDS cursor
  if (t < NB) adj[t] = Hofs[t * NCHUNK + c] - excl;
  __syncthreads();
  for (int i = t; i < CHUNK; i += 256) {
    int e = base + i;
    if (e < NNZC) {
      int r = rows[e];
      int b = r >> BSHIFT;
      int p = atomicAdd(&cnt[b], 1);
      stv[p] = make_int2(__float_as_int(vals[e]), cols[e] * DIM);
      str_[p] = r;
    }
  }
  __syncthreads();
  int n = NNZC - base;
  if (n > CHUNK) n = CHUNK;
  for (int p = t; p < n; p += 256) {
    int r = str_[p];
    int b = r >> BSHIFT;
    int dst = adj[b] + p;
    midp[dst] = stv[p];
    midr[dst] = r;
  }
}

// ---------------- partC: one block per bucket, place via LDS cursors ----------
__global__ __launch_bounds__(256) void partC(const int2* __restrict__ midp,
                                             const int* __restrict__ midr,
                                             const int* __restrict__ Hofs,
                                             const int* __restrict__ rs,
                                             int2* __restrict__ pairs) {
  __shared__ int cur[BROWS];
  int b = blockIdx.x, t = threadIdx.x;
  int row0 = b << BSHIFT;
  for (int i = t; i < BROWS; i += 256) {
    int r = row0 + i;
    cur[i] = (r < NTOT) ? rs[r] : 0;
  }
  __syncthreads();
  int s = Hofs[b * NCHUNK];
  int e = (b + 1 < NB) ? Hofs[(b + 1) * NCHUNK] : NNZC;
  for (int p = s + t; p < e; p += 256) {
    int r = midr[p];
    int2 v = midp[p];
    int pos = atomicAdd(&cur[r - row0], 1);
    pairs[pos] = v;
  }
}

// ---------------- full SpMM, 4 rows/wave, 16 lanes x float4 ----------------
// HOP0: x is the user part, xb the item part of the virtual concat.
// PERT: add SimGCL noise(seed, hop) to the output.
template <bool PERT, bool HOP0>
__global__ __launch_bounds__(256) void spmm_hop(
    const int2* __restrict__ pairs, const int* __restrict__ rs,
    const float* __restrict__ x, const float* __restrict__ xb,
    float* __restrict__ y, uint32_t seed, uint32_t hop) {
  int tid  = threadIdx.x;
  int lane = tid & 63;
  int q    = lane & 15;
  int wave = (blockIdx.x * 256 + tid) >> 6;
  int r    = wave * 4 + (lane >> 4);           // grid exact
  int s    = rs[r];
  int cnt  = rs[r + 1] - s;
  int mc = cnt;
  mc = max(mc, __shfl_xor(mc, 16));
  mc = max(mc, __shfl_xor(mc, 32));
  float a0[4] = {0.f, 0.f, 0.f, 0.f};
  int grpbase = lane & 48;
  int q4 = q * 4;
  for (int ch = 0; ch < mc; ch += 16) {
    union { long long ll; int2 v; } u;
    u.ll = 0;
    if (ch + q < cnt)
      u.ll = __builtin_nontemporal_load((const long long*)(pairs + s + ch + q));
    int2 pv = u.v;
    int m = (mc - ch < 16) ? (mc - ch) : 16;
    for (int j = 0; j < m; ++j) {
      int sl = grpbase + j;
      float v = __uint_as_float((unsigned)__shfl(pv.x, sl));
      unsigned o = (unsigned)(__shfl(pv.y, sl) + q4);
      const float4* p4;
      if (HOP0)
        p4 = (o < (unsigned)NU64) ? (const float4*)(x + o)
                                  : (const float4*)(xb + (o - (unsigned)NU64));
      else
        p4 = (const float4*)(x + o);
      float4 f0 = *p4;
      a0[0] = fmaf(v, f0.x, a0[0]); a0[1] = fmaf(v, f0.y, a0[1]);
      a0[2] = fmaf(v, f0.z, a0[2]); a0[3] = fmaf(v, f0.w, a0[3]);
    }
  }
  int ebase = r * 64 + q4;
  if (PERT) {
    uint32_t k0, k1;
    tf2x32(0u, seed, 0u, hop, k0, k1);
    float u[4], ss = 0.f;
    #pragma unroll
    for (int k = 0; k < 4; ++k) {
      u[k] = tf_unif(k0, k1, (uint32_t)(ebase + k));
      ss += u[k] * u[k];
    }
    #pragma unroll
    for (int msk = 1; msk < 16; msk <<= 1) ss += __shfl_xor(ss, msk);
    float sc = EPSP / fmaxf(sqrtf(ss), 1e-12f);
    #pragma unroll
    for (int k = 0; k < 4; ++k) a0[k] += sgnf(a0[k]) * u[k] * sc;
  }
  *(float4*)(y + ebase) = make_float4(a0[0], a0[1], a0[2], a0[3]);
}

// ---------------- in-place hop-0 noise apply / swap ----------------
// REVERT=false: A += sgn(A)*u(seedAdd,0)*sc        (branch-1 view)
// REVERT=true : A = (A - n(seedRm,0)) + n(seedAdd,0)   (branch-1 -> branch-2)
template <bool REVERT>
__global__ __launch_bounds__(256) void perturb(float* __restrict__ A,
                                               uint32_t seedRm, uint32_t seedAdd) {
  int tid  = threadIdx.x;
  int lane = tid & 63;
  int q    = lane & 15;
  int wave = (blockIdx.x * 256 + tid) >> 6;
  int r    = wave * 4 + (lane >> 4);
  int ebase = r * 64 + q * 4;
  float4 a4 = *(float4*)(A + ebase);
  float av[4] = {a4.x, a4.y, a4.z, a4.w};
  if (REVERT) {
    uint32_t k0, k1;
    tf2x32(0u, seedRm, 0u, 0u, k0, k1);
    float u[4], ss = 0.f;
    #pragma unroll
    for (int k = 0; k < 4; ++k) {
      u[k] = tf_unif(k0, k1, (uint32_t)(ebase + k));
      ss += u[k] * u[k];
    }
    #pragma unroll
    for (int msk = 1; msk < 16; msk <<= 1) ss += __shfl_xor(ss, msk);
    float sc = EPSP / fmaxf(sqrtf(ss), 1e-12f);
    #pragma unroll
    for (int k = 0; k < 4; ++k) av[k] -= sgnf(av[k]) * u[k] * sc;  // sign preserved
  }
  {
    uint32_t k0, k1;
    tf2x32(0u, seedAdd, 0u, 0u, k0, k1);
    float u[4], ss = 0.f;
    #pragma unroll
    for (int k = 0; k < 4; ++k) {
      u[k] = tf_unif(k0, k1, (uint32_t)(ebase + k));
      ss += u[k] * u[k];
    }
    #pragma unroll
    for (int msk = 1; msk < 16; msk <<= 1) ss += __shfl_xor(ss, msk);
    float sc = EPSP / fmaxf(sqrtf(ss), 1e-12f);
    #pragma unroll
    for (int k = 0; k < 4; ++k) av[k] += sgnf(av[k]) * u[k] * sc;
  }
  *(float4*)(A + ebase) = make_float4(av[0], av[1], av[2], av[3]);
}

// ---------------- multi-segment gather-accumulate ----------------
// blockIdx.y = segment; each segment: g_out[b*64+d] += src[(base+idx[b])*64+d]
__global__ void gatherM(const float* __restrict__ src,
                        const int* __restrict__ i0, const int* __restrict__ i1,
                        const int* __restrict__ i2,
                        float* __restrict__ o0, float* __restrict__ o1,
                        float* __restrict__ o2,
                        int b0, int b1, int b2) {
  int seg = blockIdx.y;
  const int* idx = (seg == 0) ? i0 : ((seg == 1) ? i1 : i2);
  float* o = (seg == 0) ? o0 : ((seg == 1) ? o1 : o2);
  int base = (seg == 0) ? b0 : ((seg == 1) ? b1 : b2);
  int gid = blockIdx.x * blockDim.x + threadIdx.x;
  int b = gid >> 6, d = gid & 63;
  o[gid] += src[(size_t)(base + idx[b]) * DIM + d];
}

// ---------------- hop-2 gathered SpMM (+fused row noise), accumulate ----------
// Only the 4096 gathered rows per segment are computed.
template <bool PERT>
__global__ __launch_bounds__(256) void hop2g(
    const int2* __restrict__ pairs, const int* __restrict__ rs,
    const float* __restrict__ x,
    const int* __restrict__ i0, const int* __restrict__ i1,
    const int* __restrict__ i2,
    float* __restrict__ o0, float* __restrict__ o1, float* __restrict__ o2,
    int b0, int b1, int b2, uint32_t seed) {
  int seg = blockIdx.y;
  const int* idx = (seg == 0) ? i0 : ((seg == 1) ? i1 : i2);
  float* o = (seg == 0) ? o0 : ((seg == 1) ? o1 : o2);
  int base = (seg == 0) ? b0 : ((seg == 1) ? b1 : b2);
  int tid  = threadIdx.x;
  int lane = tid & 63;
  int q    = lane & 15;
  int slot = blockIdx.x * 16 + (tid >> 6) * 4 + (lane >> 4);   // 0..4095
  int row  = base + idx[slot];
  int s    = rs[row];
  int cnt  = rs[row + 1] - s;
  int mc = cnt;
  mc = max(mc, __shfl_xor(mc, 16));
  mc = max(mc, __shfl_xor(mc, 32));
  float a0[4] = {0.f, 0.f, 0.f, 0.f};
  int grpbase = lane & 48;
  int q4 = q * 4;
  for (int ch = 0; ch < mc; ch += 16) {
    int2 pv = make_int2(0, 0);
    if (ch + q < cnt) pv = pairs[s + ch + q];
    int m = (mc - ch < 16) ? (mc - ch) : 16;
    for (int j = 0; j < m; ++j) {
      int sl = grpbase + j;
      float v = __uint_as_float((unsigned)__shfl(pv.x, sl));
      unsigned of = (unsigned)(__shfl(pv.y, sl) + q4);
      float4 f0 = *(const float4*)(x + of);
      a0[0] = fmaf(v, f0.x, a0[0]); a0[1] = fmaf(v, f0.y, a0[1]);
      a0[2] = fmaf(v, f0.z, a0[2]); a0[3] = fmaf(v, f0.w, a0[3]);
    }
  }
  if (PERT) {
    uint32_t k0, k1;
    tf2x32(0u, seed, 0u, 2u, k0, k1);          // hop 2 noise
    int en = row * 64 + q4;                    // element ids use the GLOBAL row
    float u[4], ss = 0.f;
    #pragma unroll
    for (int k = 0; k < 4; ++k) {
      u[k] = tf_unif(k0, k1, (uint32_t)(en + k));
      ss += u[k] * u[k];
    }
    #pragma unroll
    for (int msk = 1; msk < 16; msk <<= 1) ss += __shfl_xor(ss, msk);
    float sc = EPSP / fmaxf(sqrtf(ss), 1e-12f);
    #pragma unroll
    for (int k = 0; k < 4; ++k) a0[k] += sgnf(a0[k]) * u[k] * sc;
  }
  int og = slot * 64 + q4;
  float4 cur = *(float4*)(o + og);
  cur.x += a0[0]; cur.y += a0[1]; cur.z += a0[2]; cur.w += a0[3];
  *(float4*)(o + og) = cur;
}

// ---------------- row-normalize (clamp 1e-12) ----------------
__global__ void rownorm_kernel(float* __restrict__ v) {
  int gid = blockIdx.x * blockDim.x + threadIdx.x;
  if ((gid >> 6) >= BATCH) return;
  float x = v[gid];
  float ss = x * x;
  #pragma unroll
  for (int m = 32; m; m >>= 1) ss += __shfl_xor(ss, m);
  v[gid] = x / fmaxf(sqrtf(ss), 1e-12f);
}

// ---------------- InfoNCE phase 1: tiled exp-GEMM row sums --------------------
__global__ __launch_bounds__(256) void nce_ttl(const float* __restrict__ v1,
                                               const float* __restrict__ v2,
                                               float* __restrict__ ttl) {
  __shared__ float s1[IB * LDA];
  __shared__ float s2[JB * LDA];
  __shared__ float tsum[IB];
  int tid = threadIdx.x;
  const float4* v1v = (const float4*)(v1 + (size_t)blockIdx.x * IB * DIM);
  #pragma unroll
  for (int p = 0; p < 4; ++p) {
    int e = tid + p * 256;
    int r = e >> 4, q = e & 15;
    float4 f = v1v[e];
    float* d = &s1[r * LDA + q * 4];
    d[0] = f.x; d[1] = f.y; d[2] = f.z; d[3] = f.w;
  }
  const float4* v2v = (const float4*)(v2 + (size_t)blockIdx.y * JB * DIM);
  #pragma unroll
  for (int p = 0; p < 8; ++p) {
    int e = tid + p * 256;
    int r = e >> 4, q = e & 15;
    float4 f = v2v[e];
    float* d = &s2[r * LDA + q * 4];
    d[0] = f.x; d[1] = f.y; d[2] = f.z; d[3] = f.w;
  }
  if (tid < IB) tsum[tid] = 0.0f;
  __syncthreads();

  int i0 = (tid & 15) * 4;
  int j0 = (tid >> 4) * 8;
  float acc[4][8];
  #pragma unroll
  for (int m = 0; m < 4; ++m)
    #pragma unroll
    for (int n = 0; n < 8; ++n) acc[m][n] = 0.0f;
  #pragma unroll 4
  for (int k = 0; k < DIM; ++k) {
    float a[4], b[8];
    #pragma unroll
    for (int m = 0; m < 4; ++m) a[m] = s1[(i0 + m) * LDA + k];
    #pragma unroll
    for (int n = 0; n < 8; ++n) b[n] = s2[(j0 + n) * LDA + k];
    #pragma unroll
    for (int m = 0; m < 4; ++m)
      #pragma unroll
      for (int n = 0; n < 8; ++n) acc[m][n] = fmaf(a[m], b[n], acc[m][n]);
  }
  #pragma unroll
  for (int m = 0; m < 4; ++m) {
    float ts = 0.0f;
    #pragma unroll
    for (int n = 0; n < 8; ++n) ts += __expf(acc[m][n] * INV_TEMP);
    atomicAdd(&tsum[i0 + m], ts);
  }
  __syncthreads();
  if (tid < IB) atomicAdd(&ttl[blockIdx.x * IB + tid], tsum[tid]);
}

// ---------------- InfoNCE phase 2: diagonal + log, block-reduced --------------
__global__ __launch_bounds__(256) void nce_final(const float* __restrict__ v1,
                                                 const float* __restrict__ v2,
                                                 const float* __restrict__ ttl,
                                                 float* __restrict__ acc) {
  __shared__ float red[4];
  int tid = threadIdx.x, lane = tid & 63, wv = tid >> 6;
  int gw = blockIdx.x * 4 + wv;          // 256 waves total
  float l = 0.f;
  for (int r = gw; r < BATCH; r += 256) {
    int gid = r * 64 + lane;
    float p = v1[gid] * v2[gid];
    #pragma unroll
    for (int m = 32; m; m >>= 1) p += __shfl_xor(p, m);
    if (lane == 0) l += -logf(__expf(p * INV_TEMP) / ttl[r] + 1e-5f);
  }
  if (lane == 0) red[wv] = l;
  __syncthreads();
  if (tid == 0) atomicAdd(acc, red[0] + red[1] + red[2] + red[3]);
}

// ---------------- BPR rec loss + reg, block-reduced ----------------
__global__ __launch_bounds__(256) void rec_kernel(const float* __restrict__ ue,
                                                  const float* __restrict__ pe,
                                                  const float* __restrict__ ne,
                                                  float* __restrict__ acc) {
  __shared__ float red[3][4];
  int tid = threadIdx.x, lane = tid & 63, wv = tid >> 6;
  int gw = blockIdx.x * 4 + wv;          // 256 waves total
  const float third = 1.0f / 3.0f;
  float l = 0.f, su = 0.f, sp = 0.f;
  for (int r = gw; r < BATCH; r += 256) {
    int gid = r * 64 + lane;
    float u = ue[gid] * third, p = pe[gid] * third, n = ne[gid] * third;
    float ps = u * p, ns = u * n;
    su += u * u; sp += p * p;
    #pragma unroll
    for (int m = 32; m; m >>= 1) { ps += __shfl_xor(ps, m); ns += __shfl_xor(ns, m); }
    if (lane == 0) {
      float sig = 1.0f / (1.0f + __expf(-(ps - ns)));
      l += -logf(1e-5f + sig);
    }
  }
  #pragma unroll
  for (int m = 32; m; m >>= 1) { su += __shfl_xor(su, m); sp += __shfl_xor(sp, m); }
  if (lane == 0) { red[0][wv] = l; red[1][wv] = su; red[2][wv] = sp; }
  __syncthreads();
  if (tid == 0) {
    atomicAdd(acc + 0, red[0][0] + red[0][1] + red[0][2] + red[0][3]);
    atomicAdd(acc + 1, red[1][0] + red[1][1] + red[1][2] + red[1][3]);
    atomicAdd(acc + 2, red[2][0] + red[2][1] + red[2][2] + red[2][3]);
  }
}

__global__ void finalize_kernel(const float* __restrict__ acc, float* __restrict__ out) {
  out[0] = acc[0] * (1.0f / BATCH)
         + 1e-4f * (sqrtf(acc[1]) + sqrtf(acc[2]))
         + 0.5f * (acc[3] + acc[4]) * (1.0f / BATCH);
}

extern "C" void kernel_launch(void* const* d_in, const int* in_sizes, int n_in,
                              void* d_out, int out_size, void* d_ws, size_t ws_size,
                              hipStream_t stream) {
  (void)in_sizes; (void)n_in; (void)out_size; (void)ws_size;
  const float* user_embed = (const float*)d_in[0];
  const float* item_embed = (const float*)d_in[1];
  const float* adj_vals   = (const float*)d_in[2];
  const int*   adj_rows   = (const int*)d_in[3];
  const int*   adj_cols   = (const int*)d_in[4];
  const int*   users      = (const int*)d_in[5];
  const int*   pos_items  = (const int*)d_in[6];
  const int*   neg_items  = (const int*)d_in[7];
  float* out = (float*)d_out;

  const size_t bufElems = (size_t)NTOT * DIM;

  // ---- workspace layout (2 full buffers; total ~187 MB — proven to fit) ----
  float* A     = (float*)d_ws;                    // bufElems
  float* B     = A + bufElems;                    // bufElems
  int2*  pairs = (int2*)(B + bufElems);           // NNZC
  float* g     = (float*)(pairs + NNZC);          // GELEMS
  float* g_ue = g + 0 * (size_t)B64;
  float* g_pe = g + 1 * (size_t)B64;
  float* g_ne = g + 2 * (size_t)B64;
  float* g_u1 = g + 3 * (size_t)B64;
  float* g_i1 = g + 4 * (size_t)B64;
  float* g_u2 = g + 5 * (size_t)B64;
  float* g_i2 = g + 6 * (size_t)B64;
  float* ttl_u = g + 7 * (size_t)B64;
  float* ttl_i = ttl_u + BATCH;
  float* acc   = ttl_i + BATCH;       // 8 scalars
  int* rs     = (int*)(g + GELEMS);   // NTOT+1
  int* cursor = rs + (NTOT + 1);      // NTOT (row-count scratch)
  int* bsums  = cursor + NTOT;        // 512

  // build-time scratch aliased into A (free until first spmm; ~37 MB < 76.8 MB)
  int2* midp = (int2*)A;              // NNZC int2
  int*  midr = (int*)(midp + NNZC);   // NNZC int
  int*  Hcnt = midr + NNZC;           // NH
  int*  Hofs = Hcnt + NH;             // NH

  hipMemsetAsync(g, 0, GELEMS * sizeof(float), stream);
  hipMemsetAsync(cursor, 0, (size_t)NTOT * sizeof(int), stream);

  // ---- CSR build: rs via hist+scan; pairs via binned two-pass partition ----
  hist_kernel<<<(NNZC / 4 + 255) / 256, 256, 0, stream>>>((const int4*)adj_rows, cursor);
  scan_block<<<NSCAN_BLOCKS, 256, 0, stream>>>(cursor, rs, bsums, NTOT);
  scan_sums<<<1, 512, 0, stream>>>(bsums, NSCAN_BLOCKS);
  add_offsets<<<(NTOT + 255) / 256, 256, 0, stream>>>(rs, bsums, NTOT, NTOT, NNZC);

  partA<<<NCHUNK, 256, 0, stream>>>(adj_rows, Hcnt);
  const int nhb = (NH + SCAN_ELEMS - 1) / SCAN_ELEMS;
  scan_block<<<nhb, 256, 0, stream>>>(Hcnt, Hofs, bsums, NH);
  scan_sums<<<1, 512, 0, stream>>>(bsums, nhb);
  add_offsets<<<(NH + 255) / 256, 256, 0, stream>>>(Hofs, bsums, NH, -1, 0);

  partB<<<NCHUNK, 256, 0, stream>>>(adj_vals, adj_rows, adj_cols, Hofs, midp, midr);
  partC<<<NB, 256, 0, stream>>>(midp, midr, Hofs, rs, pairs);

  const int spmm_blocks = NTOT / 16;           // 18750
  dim3 gat3(B64 / 256, 3), gat2(B64 / 256, 2);
  dim3 h2g3(BATCH / 16, 3), h2g2(BATCH / 16, 2);

  // ---- branch 0 (clean) ----
  spmm_hop<false, true><<<spmm_blocks, 256, 0, stream>>>(
      pairs, rs, user_embed, item_embed, A, 0u, 0u);            // hop0 -> A
  gatherM<<<gat3, 256, 0, stream>>>(A, users, pos_items, neg_items,
                                    g_ue, g_pe, g_ne, 0, NUSERS, NUSERS);
  spmm_hop<false, false><<<spmm_blocks, 256, 0, stream>>>(
      pairs, rs, A, nullptr, B, 0u, 0u);                        // hop1 -> B
  gatherM<<<gat3, 256, 0, stream>>>(B, users, pos_items, neg_items,
                                    g_ue, g_pe, g_ne, 0, NUSERS, NUSERS);
  hop2g<false><<<h2g3, 256, 0, stream>>>(pairs, rs, B, users, pos_items, neg_items,
                                         g_ue, g_pe, g_ne, 0, NUSERS, NUSERS, 0u);

  // ---- branch 1 (seed 101) ----
  perturb<false><<<spmm_blocks, 256, 0, stream>>>(A, 0u, 101u); // A = hop0 + n(101,0)
  gatherM<<<gat2, 256, 0, stream>>>(A, users, pos_items, nullptr,
                                    g_u1, g_i1, nullptr, 0, NUSERS, 0);
  spmm_hop<true, false><<<spmm_blocks, 256, 0, stream>>>(
      pairs, rs, A, nullptr, B, 101u, 1u);                      // hop1 + n(101,1)
  gatherM<<<gat2, 256, 0, stream>>>(B, users, pos_items, nullptr,
                                    g_u1, g_i1, nullptr, 0, NUSERS, 0);
  hop2g<true><<<h2g2, 256, 0, stream>>>(pairs, rs, B, users, pos_items, nullptr,
                                        g_u1, g_i1, nullptr, 0, NUSERS, 0, 101u);

  // ---- branch 2 (seed 202) ----
  perturb<true><<<spmm_blocks, 256, 0, stream>>>(A, 101u, 202u); // swap noise views
  gatherM<<<gat2, 256, 0, stream>>>(A, users, pos_items, nullptr,
                                    g_u2, g_i2, nullptr, 0, NUSERS, 0);
  spmm_hop<true, false><<<spmm_blocks, 256, 0, stream>>>(
      pairs, rs, A, nullptr, B, 202u, 1u);
  gatherM<<<gat2, 256, 0, stream>>>(B, users, pos_items, nullptr,
                                    g_u2, g_i2, nullptr, 0, NUSERS, 0);
  hop2g<true><<<h2g2, 256, 0, stream>>>(pairs, rs, B, users, pos_items, nullptr,
                                        g_u2, g_i2, nullptr, 0, NUSERS, 0, 202u);

  // ---- losses ----
  rec_kernel<<<64, 256, 0, stream>>>(g_ue, g_pe, g_ne, acc);
  rownorm_kernel<<<B64 / 256, 256, 0, stream>>>(g_u1);
  rownorm_kernel<<<B64 / 256, 256, 0, stream>>>(g_u2);
  rownorm_kernel<<<B64 / 256, 256, 0, stream>>>(g_i1);
  rownorm_kernel<<<B64 / 256, 256, 0, stream>>>(g_i2);

  dim3 nce_grid(BATCH / IB, BATCH / JB);
  nce_ttl<<<nce_grid, 256, 0, stream>>>(g_u1, g_u2, ttl_u);
  nce_ttl<<<nce_grid, 256, 0, stream>>>(g_i1, g_i2, ttl_i);
  nce_final<<<64, 256, 0, stream>>>(g_u1, g_u2, ttl_u, acc + 3);
  nce_final<<<64, 256, 0, stream>>>(g_i1, g_i2, ttl_i, acc + 4);
  finalize_kernel<<<1, 1, 0, stream>>>(acc, out);
}

// Round 8
// 1110.343 us; speedup vs baseline: 7.1248x; 1.0642x over previous
//
#include <hip/hip_runtime.h>
#include <stdint.h>

#define NUSERS  200000
#define NITEMS  100000
#define NTOT    300000
#define DIM     64
#define NU64    (NUSERS * DIM)
#define NNZC    3000000
#define BATCH   4096
#define B64     (BATCH * DIM)
#define EPSP    0.1f
#define INV_TEMP 5.0f   // 1 / 0.2
#define SCAN_ELEMS 1024
#define NSCAN_BLOCKS ((NTOT + SCAN_ELEMS - 1) / SCAN_ELEMS)   // 293
#define IB 64
#define JB 128
#define LDA 65
#define GELEMS ((size_t)7 * B64 + 2 * BATCH + 8)

// ---- binned CSR build params ----
#define BSHIFT 11
#define BROWS  (1 << BSHIFT)                       // 2048 rows per bucket
#define NB     ((NTOT + BROWS - 1) / BROWS)        // 147 buckets
#define CHUNK  4096
#define NCHUNK ((NNZC + CHUNK - 1) / CHUNK)        // 733
#define NH     (NB * NCHUNK)                       // 107751

// ---------------- Threefry-2x32 (JAX-compatible) ----------------
__device__ __forceinline__ uint32_t rotl32(uint32_t v, int r) {
  return (v << r) | (v >> (32 - r));
}

__device__ __forceinline__ void tf2x32(uint32_t k0, uint32_t k1,
                                       uint32_t x0, uint32_t x1,
                                       uint32_t &o0, uint32_t &o1) {
  uint32_t k2 = k0 ^ k1 ^ 0x1BD11BDAu;
#define TFR(r) { x0 += x1; x1 = rotl32(x1, (r)); x1 ^= x0; }
  x0 += k0; x1 += k1;
  TFR(13) TFR(15) TFR(26) TFR(6)
  x0 += k1; x1 += k2 + 1u;
  TFR(17) TFR(29) TFR(16) TFR(24)
  x0 += k2; x1 += k0 + 2u;
  TFR(13) TFR(15) TFR(26) TFR(6)
  x0 += k0; x1 += k1 + 3u;
  TFR(17) TFR(29) TFR(16) TFR(24)
  x0 += k1; x1 += k2 + 4u;
  TFR(13) TFR(15) TFR(26) TFR(6)
  x0 += k2; x1 += k0 + 5u;
#undef TFR
  o0 = x0; o1 = x1;
}

__device__ __forceinline__ float tf_unif(uint32_t k0, uint32_t k1, uint32_t e) {
  uint32_t b0, b1;
  tf2x32(k0, k1, 0u, e, b0, b1);
  return __uint_as_float(((b0 ^ b1) >> 9) | 0x3F800000u) - 1.0f;
}

__device__ __forceinline__ float sgnf(float a) {
  return (a > 0.f) ? 1.f : ((a < 0.f) ? -1.f : 0.f);
}

// ---------------- fused per-row histogram + per-chunk bucket histogram -------
__global__ __launch_bounds__(256) void fhist(const int* __restrict__ rows,
                                             int* __restrict__ cnt,
                                             int* __restrict__ Hcnt) {
  __shared__ int bc[NB];
  int c = blockIdx.x, t = threadIdx.x;
  for (int i = t; i < NB; i += 256) bc[i] = 0;
  __syncthreads();
  int base = c * CHUNK;
  for (int i = t; i < CHUNK; i += 256) {
    int e = base + i;
    if (e < NNZC) {
      int r = rows[e];
      atomicAdd(&cnt[r], 1);
      atomicAdd(&bc[r >> BSHIFT], 1);
    }
  }
  __syncthreads();
  for (int i = t; i < NB; i += 256) Hcnt[i * NCHUNK + c] = bc[i];
}

// ---------------- generic hierarchical exclusive scan ----------------
__global__ void scan_block(const int* __restrict__ cnt, int* __restrict__ out,
                           int* __restrict__ bsums, int n) {
  __shared__ int tmp[SCAN_ELEMS];
  int base = blockIdx.x * SCAN_ELEMS;
  int t = threadIdx.x;                 // 256 threads
  #pragma unroll
  for (int q = 0; q < 4; ++q) {
    int k = t + q * 256, i = base + k;
    tmp[k] = (i < n) ? cnt[i] : 0;
  }
  __syncthreads();
  for (int off = 1; off < SCAN_ELEMS; off <<= 1) {
    int v[4];
    #pragma unroll
    for (int q = 0; q < 4; ++q) {
      int k = t + q * 256;
      v[q] = (k >= off) ? tmp[k - off] : 0;
    }
    __syncthreads();
    #pragma unroll
    for (int q = 0; q < 4; ++q) tmp[t + q * 256] += v[q];
    __syncthreads();
  }
  #pragma unroll
  for (int q = 0; q < 4; ++q) {
    int k = t + q * 256, i = base + k;
    if (i < n) out[i] = (k == 0) ? 0 : tmp[k - 1];
  }
  if (t == 0) bsums[blockIdx.x] = tmp[SCAN_ELEMS - 1];
}

__global__ void scan_sums(int* __restrict__ bsums, int nb) {
  __shared__ int tmp[512];
  int t = threadIdx.x;
  tmp[t] = (t < nb) ? bsums[t] : 0;
  __syncthreads();
  for (int off = 1; off < 512; off <<= 1) {
    int v = (t >= off) ? tmp[t - off] : 0;
    __syncthreads();
    tmp[t] += v;
    __syncthreads();
  }
  if (t < nb) bsums[t] = (t == 0) ? 0 : tmp[t - 1];
}

__global__ void add_offsets(int* __restrict__ out, const int* __restrict__ bsums,
                            int n, int tailIdx, int tailVal) {
  int i = blockIdx.x * blockDim.x + threadIdx.x;
  if (i < n) out[i] += bsums[i / SCAN_ELEMS];
  if (i == 0 && tailIdx >= 0) out[tailIdx] = tailVal;
}

// ---------------- partB: LDS-bin chunk, write bucket-contiguous, coalesced ----
__global__ __launch_bounds__(256) void partB(const float* __restrict__ vals,
                                             const int* __restrict__ rows,
                                             const int* __restrict__ cols,
                                             const int* __restrict__ Hofs,
                                             int2* __restrict__ midp,
                                             int* __restrict__ midr) {
  __shared__ int2 stv[CHUNK];     // 32 KB
  __shared__ int  str_[CHUNK];    // 16 KB
  __shared__ int  cnt[256];
  __shared__ int  sc[256];
  __shared__ int  adj[NB];
  int c = blockIdx.x, t = threadIdx.x;
  cnt[t] = 0;
  __syncthreads();
  int base = c * CHUNK;
  for (int i = t; i < CHUNK; i += 256) {
    int e = base + i;
    if (e < NNZC) atomicAdd(&cnt[rows[e] >> BSHIFT], 1);
  }
  __syncthreads();
  sc[t] = cnt[t];
  __syncthreads();
  for (int off = 1; off < 256; off <<= 1) {
    int u = (t >= off) ? sc[t - off] : 0;
    __syncthreads();
    sc[t] += u;
    __syncthreads();
  }
  int excl = sc[t] - cnt[t];
  cnt[t] = excl;                          // becomes LDS cursor
  if (t < NB) adj[t] = Hofs[t * NCHUNK + c] - excl;
  __syncthreads();
  for (int i = t; i < CHUNK; i += 256) {
    int e = base + i;
    if (e < NNZC) {
      int r = rows[e];
      int b = r >> BSHIFT;
      int p = atomicAdd(&cnt[b], 1);
      stv[p] = make_int2(__float_as_int(vals[e]), cols[e] * DIM);
      str_[p] = r;
    }
  }
  __syncthreads();
  int n = NNZC - base;
  if (n > CHUNK) n = CHUNK;
  for (int p = t; p < n; p += 256) {
    int r = str_[p];
    int b = r >> BSHIFT;
    int dst = adj[b] + p;
    midp[dst] = stv[p];
    midr[dst] = r;
  }
}

// ---------------- partC: one block per bucket, place via LDS cursors ----------
__global__ __launch_bounds__(256) void partC(const int2* __restrict__ midp,
                                             const int* __restrict__ midr,
                                             const int* __restrict__ Hofs,
                                             const int* __restrict__ rs,
                                             int2* __restrict__ pairs) {
  __shared__ int cur[BROWS];
  int b = blockIdx.x, t = threadIdx.x;
  int row0 = b << BSHIFT;
  for (int i = t; i < BROWS; i += 256) {
    int r = row0 + i;
    cur[i] = (r < NTOT) ? rs[r] : 0;
  }
  __syncthreads();
  int s = Hofs[b * NCHUNK];
  int e = (b + 1 < NB) ? Hofs[(b + 1) * NCHUNK] : NNZC;
  for (int p = s + t; p < e; p += 256) {
    int r = midr[p];
    int2 v = midp[p];
    int pos = atomicAdd(&cur[r - row0], 1);
    pairs[pos] = v;
  }
}

// ---------------- full SpMM, 4 rows/wave, 16 lanes x float4 ----------------
// Decode: all 16 lanes of a group load pairs[j] directly (same-address VMEM
// broadcast, L1-hot stream) — no shuffles, deep MLP via 8-wide chunks.
template <bool PERT, bool HOP0>
__global__ __launch_bounds__(256) void spmm_hop(
    const int2* __restrict__ pairs, const int* __restrict__ rs,
    const float* __restrict__ x, const float* __restrict__ xb,
    float* __restrict__ y, uint32_t seed, uint32_t hop) {
  int tid  = threadIdx.x;
  int lane = tid & 63;
  int q    = lane & 15;
  int wave = (blockIdx.x * 256 + tid) >> 6;
  int r    = wave * 4 + (lane >> 4);           // grid exact
  int s    = rs[r];
  int e    = rs[r + 1];
  int q4 = q * 4;
  float a0[4] = {0.f, 0.f, 0.f, 0.f};
  for (int j = s; j < e; j += 8) {
    int2 p[8];
    #pragma unroll
    for (int k = 0; k < 8; ++k)
      p[k] = (j + k < e) ? pairs[j + k] : make_int2(0, 0);
    #pragma unroll
    for (int k = 0; k < 8; ++k) {
      float v = __int_as_float(p[k].x);
      unsigned o = (unsigned)(p[k].y + q4);
      const float4* p4;
      if (HOP0)
        p4 = (o < (unsigned)NU64) ? (const float4*)(x + o)
                                  : (const float4*)(xb + (o - (unsigned)NU64));
      else
        p4 = (const float4*)(x + o);
      float4 f = *p4;
      a0[0] = fmaf(v, f.x, a0[0]); a0[1] = fmaf(v, f.y, a0[1]);
      a0[2] = fmaf(v, f.z, a0[2]); a0[3] = fmaf(v, f.w, a0[3]);
    }
  }
  int ebase = r * 64 + q4;
  if (PERT) {
    uint32_t k0, k1;
    tf2x32(0u, seed, 0u, hop, k0, k1);
    float u[4], ss = 0.f;
    #pragma unroll
    for (int k = 0; k < 4; ++k) {
      u[k] = tf_unif(k0, k1, (uint32_t)(ebase + k));
      ss += u[k] * u[k];
    }
    #pragma unroll
    for (int msk = 1; msk < 16; msk <<= 1) ss += __shfl_xor(ss, msk);
    float sc = EPSP / fmaxf(sqrtf(ss), 1e-12f);
    #pragma unroll
    for (int k = 0; k < 4; ++k) a0[k] += sgnf(a0[k]) * u[k] * sc;
  }
  *(float4*)(y + ebase) = make_float4(a0[0], a0[1], a0[2], a0[3]);
}

// ---------------- in-place hop-0 noise apply / swap ----------------
template <bool REVERT>
__global__ __launch_bounds__(256) void perturb(float* __restrict__ A,
                                               uint32_t seedRm, uint32_t seedAdd) {
  int tid  = threadIdx.x;
  int lane = tid & 63;
  int q    = lane & 15;
  int wave = (blockIdx.x * 256 + tid) >> 6;
  int r    = wave * 4 + (lane >> 4);
  int ebase = r * 64 + q * 4;
  float4 a4 = *(float4*)(A + ebase);
  float av[4] = {a4.x, a4.y, a4.z, a4.w};
  if (REVERT) {
    uint32_t k0, k1;
    tf2x32(0u, seedRm, 0u, 0u, k0, k1);
    float u[4], ss = 0.f;
    #pragma unroll
    for (int k = 0; k < 4; ++k) {
      u[k] = tf_unif(k0, k1, (uint32_t)(ebase + k));
      ss += u[k] * u[k];
    }
    #pragma unroll
    for (int msk = 1; msk < 16; msk <<= 1) ss += __shfl_xor(ss, msk);
    float sc = EPSP / fmaxf(sqrtf(ss), 1e-12f);
    #pragma unroll
    for (int k = 0; k < 4; ++k) av[k] -= sgnf(av[k]) * u[k] * sc;  // sign preserved
  }
  {
    uint32_t k0, k1;
    tf2x32(0u, seedAdd, 0u, 0u, k0, k1);
    float u[4], ss = 0.f;
    #pragma unroll
    for (int k = 0; k < 4; ++k) {
      u[k] = tf_unif(k0, k1, (uint32_t)(ebase + k));
      ss += u[k] * u[k];
    }
    #pragma unroll
    for (int msk = 1; msk < 16; msk <<= 1) ss += __shfl_xor(ss, msk);
    float sc = EPSP / fmaxf(sqrtf(ss), 1e-12f);
    #pragma unroll
    for (int k = 0; k < 4; ++k) av[k] += sgnf(av[k]) * u[k] * sc;
  }
  *(float4*)(A + ebase) = make_float4(av[0], av[1], av[2], av[3]);
}

// ---------------- multi-segment gather-accumulate ----------------
__global__ void gatherM(const float* __restrict__ src,
                        const int* __restrict__ i0, const int* __restrict__ i1,
                        const int* __restrict__ i2,
                        float* __restrict__ o0, float* __restrict__ o1,
                        float* __restrict__ o2,
                        int b0, int b1, int b2) {
  int seg = blockIdx.y;
  const int* idx = (seg == 0) ? i0 : ((seg == 1) ? i1 : i2);
  float* o = (seg == 0) ? o0 : ((seg == 1) ? o1 : o2);
  int base = (seg == 0) ? b0 : ((seg == 1) ? b1 : b2);
  int gid = blockIdx.x * blockDim.x + threadIdx.x;
  int b = gid >> 6, d = gid & 63;
  o[gid] += src[(size_t)(base + idx[b]) * DIM + d];
}

// ---------------- hop-2 gathered SpMM (+fused row noise [+norm]) -------------
// Last accumulation per branch; NORM fuses the final row-normalize.
template <bool PERT, bool NORM>
__global__ __launch_bounds__(256) void hop2g(
    const int2* __restrict__ pairs, const int* __restrict__ rs,
    const float* __restrict__ x,
    const int* __restrict__ i0, const int* __restrict__ i1,
    const int* __restrict__ i2,
    float* __restrict__ o0, float* __restrict__ o1, float* __restrict__ o2,
    int b0, int b1, int b2, uint32_t seed) {
  int seg = blockIdx.y;
  const int* idx = (seg == 0) ? i0 : ((seg == 1) ? i1 : i2);
  float* o = (seg == 0) ? o0 : ((seg == 1) ? o1 : o2);
  int base = (seg == 0) ? b0 : ((seg == 1) ? b1 : b2);
  int tid  = threadIdx.x;
  int lane = tid & 63;
  int q    = lane & 15;
  int q4 = q * 4;
  int slot = blockIdx.x * 16 + (tid >> 6) * 4 + (lane >> 4);   // 0..4095
  int row  = base + idx[slot];
  int s    = rs[row];
  int e    = rs[row + 1];
  float a0[4] = {0.f, 0.f, 0.f, 0.f};
  for (int j = s; j < e; j += 8) {
    int2 p[8];
    #pragma unroll
    for (int k = 0; k < 8; ++k)
      p[k] = (j + k < e) ? pairs[j + k] : make_int2(0, 0);
    #pragma unroll
    for (int k = 0; k < 8; ++k) {
      float v = __int_as_float(p[k].x);
      unsigned of = (unsigned)(p[k].y + q4);
      float4 f = *(const float4*)(x + of);
      a0[0] = fmaf(v, f.x, a0[0]); a0[1] = fmaf(v, f.y, a0[1]);
      a0[2] = fmaf(v, f.z, a0[2]); a0[3] = fmaf(v, f.w, a0[3]);
    }
  }
  if (PERT) {
    uint32_t k0, k1;
    tf2x32(0u, seed, 0u, 2u, k0, k1);          // hop 2 noise
    int en = row * 64 + q4;                    // element ids use the GLOBAL row
    float u[4], ss = 0.f;
    #pragma unroll
    for (int k = 0; k < 4; ++k) {
      u[k] = tf_unif(k0, k1, (uint32_t)(en + k));
      ss += u[k] * u[k];
    }
    #pragma unroll
    for (int msk = 1; msk < 16; msk <<= 1) ss += __shfl_xor(ss, msk);
    float sc = EPSP / fmaxf(sqrtf(ss), 1e-12f);
    #pragma unroll
    for (int k = 0; k < 4; ++k) a0[k] += sgnf(a0[k]) * u[k] * sc;
  }
  int og = slot * 64 + q4;
  float4 cur = *(float4*)(o + og);
  float rv[4] = {cur.x + a0[0], cur.y + a0[1], cur.z + a0[2], cur.w + a0[3]};
  if (NORM) {
    float ss = rv[0]*rv[0] + rv[1]*rv[1] + rv[2]*rv[2] + rv[3]*rv[3];
    #pragma unroll
    for (int msk = 1; msk < 16; msk <<= 1) ss += __shfl_xor(ss, msk);
    float inv = 1.0f / fmaxf(sqrtf(ss), 1e-12f);
    #pragma unroll
    for (int k = 0; k < 4; ++k) rv[k] *= inv;
  }
  *(float4*)(o + og) = make_float4(rv[0], rv[1], rv[2], rv[3]);
}

// ---------------- InfoNCE phase 1: tiled exp-GEMM row sums (both branches) ----
__global__ __launch_bounds__(256) void nce_ttl(
    const float* __restrict__ u1, const float* __restrict__ u2,
    float* __restrict__ tu,
    const float* __restrict__ w1, const float* __restrict__ w2,
    float* __restrict__ tw) {
  const float* v1 = (blockIdx.z == 0) ? u1 : w1;
  const float* v2 = (blockIdx.z == 0) ? u2 : w2;
  float* ttl      = (blockIdx.z == 0) ? tu : tw;
  __shared__ float s1[IB * LDA];
  __shared__ float s2[JB * LDA];
  __shared__ float tsum[IB];
  int tid = threadIdx.x;
  const float4* v1v = (const float4*)(v1 + (size_t)blockIdx.x * IB * DIM);
  #pragma unroll
  for (int p = 0; p < 4; ++p) {
    int e = tid + p * 256;
    int r = e >> 4, q = e & 15;
    float4 f = v1v[e];
    float* d = &s1[r * LDA + q * 4];
    d[0] = f.x; d[1] = f.y; d[2] = f.z; d[3] = f.w;
  }
  const float4* v2v = (const float4*)(v2 + (size_t)blockIdx.y * JB * DIM);
  #pragma unroll
  for (int p = 0; p < 8; ++p) {
    int e = tid + p * 256;
    int r = e >> 4, q = e & 15;
    float4 f = v2v[e];
    float* d = &s2[r * LDA + q * 4];
    d[0] = f.x; d[1] = f.y; d[2] = f.z; d[3] = f.w;
  }
  if (tid < IB) tsum[tid] = 0.0f;
  __syncthreads();

  int i0 = (tid & 15) * 4;
  int j0 = (tid >> 4) * 8;
  float acc[4][8];
  #pragma unroll
  for (int m = 0; m < 4; ++m)
    #pragma unroll
    for (int n = 0; n < 8; ++n) acc[m][n] = 0.0f;
  #pragma unroll 4
  for (int k = 0; k < DIM; ++k) {
    float a[4], b[8];
    #pragma unroll
    for (int m = 0; m < 4; ++m) a[m] = s1[(i0 + m) * LDA + k];
    #pragma unroll
    for (int n = 0; n < 8; ++n) b[n] = s2[(j0 + n) * LDA + k];
    #pragma unroll
    for (int m = 0; m < 4; ++m)
      #pragma unroll
      for (int n = 0; n < 8; ++n) acc[m][n] = fmaf(a[m], b[n], acc[m][n]);
  }
  #pragma unroll
  for (int m = 0; m < 4; ++m) {
    float ts = 0.0f;
    #pragma unroll
    for (int n = 0; n < 8; ++n) ts += __expf(acc[m][n] * INV_TEMP);
    atomicAdd(&tsum[i0 + m], ts);
  }
  __syncthreads();
  if (tid < IB) atomicAdd(&ttl[blockIdx.x * IB + tid], tsum[tid]);
}

// ---------------- InfoNCE phase 2: diagonal + log, block-reduced --------------
__global__ __launch_bounds__(256) void nce_final(const float* __restrict__ v1,
                                                 const float* __restrict__ v2,
                                                 const float* __restrict__ ttl,
                                                 float* __restrict__ acc) {
  __shared__ float red[4];
  int tid = threadIdx.x, lane = tid & 63, wv = tid >> 6;
  int gw = blockIdx.x * 4 + wv;          // 256 waves total
  float l = 0.f;
  for (int r = gw; r < BATCH; r += 256) {
    int gid = r * 64 + lane;
    float p = v1[gid] * v2[gid];
    #pragma unroll
    for (int m = 32; m; m >>= 1) p += __shfl_xor(p, m);
    if (lane == 0) l += -logf(__expf(p * INV_TEMP) / ttl[r] + 1e-5f);
  }
  if (lane == 0) red[wv] = l;
  __syncthreads();
  if (tid == 0) atomicAdd(acc, red[0] + red[1] + red[2] + red[3]);
}

// ---------------- BPR rec loss + reg, block-reduced ----------------
__global__ __launch_bounds__(256) void rec_kernel(const float* __restrict__ ue,
                                                  const float* __restrict__ pe,
                                                  const float* __restrict__ ne,
                                                  float* __restrict__ acc) {
  __shared__ float red[3][4];
  int tid = threadIdx.x, lane = tid & 63, wv = tid >> 6;
  int gw = blockIdx.x * 4 + wv;          // 256 waves total
  const float third = 1.0f / 3.0f;
  float l = 0.f, su = 0.f, sp = 0.f;
  for (int r = gw; r < BATCH; r += 256) {
    int gid = r * 64 + lane;
    float u = ue[gid] * third, p = pe[gid] * third, n = ne[gid] * third;
    float ps = u * p, ns = u * n;
    su += u * u; sp += p * p;
    #pragma unroll
    for (int m = 32; m; m >>= 1) { ps += __shfl_xor(ps, m); ns += __shfl_xor(ns, m); }
    if (lane == 0) {
      float sig = 1.0f / (1.0f + __expf(-(ps - ns)));
      l += -logf(1e-5f + sig);
    }
  }
  #pragma unroll
  for (int m = 32; m; m >>= 1) { su += __shfl_xor(su, m); sp += __shfl_xor(sp, m); }
  if (lane == 0) { red[0][wv] = l; red[1][wv] = su; red[2][wv] = sp; }
  __syncthreads();
  if (tid == 0) {
    atomicAdd(acc + 0, red[0][0] + red[0][1] + red[0][2] + red[0][3]);
    atomicAdd(acc + 1, red[1][0] + red[1][1] + red[1][2] + red[1][3]);
    atomicAdd(acc + 2, red[2][0] + red[2][1] + red[2][2] + red[2][3]);
  }
}

__global__ void finalize_kernel(const float* __restrict__ acc, float* __restrict__ out) {
  out[0] = acc[0] * (1.0f / BATCH)
         + 1e-4f * (sqrtf(acc[1]) + sqrtf(acc[2]))
         + 0.5f * (acc[3] + acc[4]) * (1.0f / BATCH);
}

extern "C" void kernel_launch(void* const* d_in, const int* in_sizes, int n_in,
                              void* d_out, int out_size, void* d_ws, size_t ws_size,
                              hipStream_t stream) {
  (void)in_sizes; (void)n_in; (void)out_size; (void)ws_size;
  const float* user_embed = (const float*)d_in[0];
  const float* item_embed = (const float*)d_in[1];
  const float* adj_vals   = (const float*)d_in[2];
  const int*   adj_rows   = (const int*)d_in[3];
  const int*   adj_cols   = (const int*)d_in[4];
  const int*   users      = (const int*)d_in[5];
  const int*   pos_items  = (const int*)d_in[6];
  const int*   neg_items  = (const int*)d_in[7];
  float* out = (float*)d_out;

  const size_t bufElems = (size_t)NTOT * DIM;

  // ---- workspace layout (2 full buffers; ~190 MB — proven to fit r7) ----
  float* A     = (float*)d_ws;                    // bufElems
  float* B     = A + bufElems;                    // bufElems
  int2*  pairs = (int2*)(B + bufElems);           // NNZC
  float* g     = (float*)(pairs + NNZC);          // GELEMS
  float* g_ue = g + 0 * (size_t)B64;
  float* g_pe = g + 1 * (size_t)B64;
  float* g_ne = g + 2 * (size_t)B64;
  float* g_u1 = g + 3 * (size_t)B64;
  float* g_i1 = g + 4 * (size_t)B64;
  float* g_u2 = g + 5 * (size_t)B64;
  float* g_i2 = g + 6 * (size_t)B64;
  float* ttl_u = g + 7 * (size_t)B64;
  float* ttl_i = ttl_u + BATCH;
  float* acc   = ttl_i + BATCH;       // 8 scalars
  int* rs     = (int*)(g + GELEMS);   // NTOT+1
  int* cursor = rs + (NTOT + 1);      // NTOT (row-count scratch)
  int* bsums  = cursor + NTOT;        // 512

  // build-time scratch aliased into A (free until first spmm)
  int2* midp = (int2*)A;              // NNZC int2
  int*  midr = (int*)(midp + NNZC);   // NNZC int
  int*  Hcnt = midr + NNZC;           // NH
  int*  Hofs = Hcnt + NH;             // NH

  hipMemsetAsync(g, 0, GELEMS * sizeof(float), stream);
  hipMemsetAsync(cursor, 0, (size_t)NTOT * sizeof(int), stream);

  // ---- CSR build: fused hist, scans, binned two-pass partition ----
  fhist<<<NCHUNK, 256, 0, stream>>>(adj_rows, cursor, Hcnt);
  scan_block<<<NSCAN_BLOCKS, 256, 0, stream>>>(cursor, rs, bsums, NTOT);
  scan_sums<<<1, 512, 0, stream>>>(bsums, NSCAN_BLOCKS);
  add_offsets<<<(NTOT + 255) / 256, 256, 0, stream>>>(rs, bsums, NTOT, NTOT, NNZC);
  const int nhb = (NH + SCAN_ELEMS - 1) / SCAN_ELEMS;
  scan_block<<<nhb, 256, 0, stream>>>(Hcnt, Hofs, bsums, NH);
  scan_sums<<<1, 512, 0, stream>>>(bsums, nhb);
  add_offsets<<<(NH + 255) / 256, 256, 0, stream>>>(Hofs, bsums, NH, -1, 0);
  partB<<<NCHUNK, 256, 0, stream>>>(adj_vals, adj_rows, adj_cols, Hofs, midp, midr);
  partC<<<NB, 256, 0, stream>>>(midp, midr, Hofs, rs, pairs);

  const int spmm_blocks = NTOT / 16;           // 18750
  dim3 gat3(B64 / 256, 3), gat2(B64 / 256, 2);
  dim3 h2g3(BATCH / 16, 3), h2g2(BATCH / 16, 2);

  // ---- branch 0 (clean) ----
  spmm_hop<false, true><<<spmm_blocks, 256, 0, stream>>>(
      pairs, rs, user_embed, item_embed, A, 0u, 0u);            // hop0 -> A
  gatherM<<<gat3, 256, 0, stream>>>(A, users, pos_items, neg_items,
                                    g_ue, g_pe, g_ne, 0, NUSERS, NUSERS);
  spmm_hop<false, false><<<spmm_blocks, 256, 0, stream>>>(
      pairs, rs, A, nullptr, B, 0u, 0u);                        // hop1 -> B
  gatherM<<<gat3, 256, 0, stream>>>(B, users, pos_items, neg_items,
                                    g_ue, g_pe, g_ne, 0, NUSERS, NUSERS);
  hop2g<false, false><<<h2g3, 256, 0, stream>>>(
      pairs, rs, B, users, pos_items, neg_items,
      g_ue, g_pe, g_ne, 0, NUSERS, NUSERS, 0u);

  // ---- branch 1 (seed 101) ----
  perturb<false><<<spmm_blocks, 256, 0, stream>>>(A, 0u, 101u); // A = hop0 + n(101,0)
  gatherM<<<gat2, 256, 0, stream>>>(A, users, pos_items, nullptr,
                                    g_u1, g_i1, nullptr, 0, NUSERS, 0);
  spmm_hop<true, false><<<spmm_blocks, 256, 0, stream>>>(
      pairs, rs, A, nullptr, B, 101u, 1u);                      // hop1 + n(101,1)
  gatherM<<<gat2, 256, 0, stream>>>(B, users, pos_items, nullptr,
                                    g_u1, g_i1, nullptr, 0, NUSERS, 0);
  hop2g<true, true><<<h2g2, 256, 0, stream>>>(
      pairs, rs, B, users, pos_items, nullptr,
      g_u1, g_i1, nullptr, 0, NUSERS, 0, 101u);                 // + fused rownorm

  // ---- branch 2 (seed 202) ----
  perturb<true><<<spmm_blocks, 256, 0, stream>>>(A, 101u, 202u); // swap noise views
  gatherM<<<gat2, 256, 0, stream>>>(A, users, pos_items, nullptr,
                                    g_u2, g_i2, nullptr, 0, NUSERS, 0);
  spmm_hop<true, false><<<spmm_blocks, 256, 0, stream>>>(
      pairs, rs, A, nullptr, B, 202u, 1u);
  gatherM<<<gat2, 256, 0, stream>>>(B, users, pos_items, nullptr,
                                    g_u2, g_i2, nullptr, 0, NUSERS, 0);
  hop2g<true, true><<<h2g2, 256, 0, stream>>>(
      pairs, rs, B, users, pos_items, nullptr,
      g_u2, g_i2, nullptr, 0, NUSERS, 0, 202u);                 // + fused rownorm

  // ---- losses ----
  rec_kernel<<<64, 256, 0, stream>>>(g_ue, g_pe, g_ne, acc);
  dim3 nce_grid(BATCH / IB, BATCH / JB, 2);
  nce_ttl<<<nce_grid, 256, 0, stream>>>(g_u1, g_u2, ttl_u, g_i1, g_i2, ttl_i);
  nce_final<<<64, 256, 0, stream>>>(g_u1, g_u2, ttl_u, acc + 3);
  nce_final<<<64, 256, 0, stream>>>(g_i1, g_i2, ttl_i, acc + 4);
  finalize_kernel<<<1, 1, 0, stream>>>(acc, out);
}

// Round 9
// 1024.935 us; speedup vs baseline: 7.7186x; 1.0833x over previous
//
#include <hip/hip_runtime.h>
#include <stdint.h>

#define NUSERS  200000
#define NITEMS  100000
#define NTOT    300000
#define DIM     64
#define NU64    (NUSERS * DIM)
#define NNZC    3000000
#define BATCH   4096
#define B64     (BATCH * DIM)
#define EPSP    0.1f
#define INV_TEMP 5.0f   // 1 / 0.2
#define SCAN_ELEMS 1024
#define NSCAN_BLOCKS ((NTOT + SCAN_ELEMS - 1) / SCAN_ELEMS)   // 293
#define IB 64
#define JB 128
#define LDA 65
#define GELEMS ((size_t)7 * B64 + 2 * BATCH + 8)

// ---- binned CSR build params ----
#define BSHIFT 11
#define BROWS  (1 << BSHIFT)                       // 2048 rows per bucket
#define NB     ((NTOT + BROWS - 1) / BROWS)        // 147 buckets
#define CHUNK  4096
#define NCHUNK ((NNZC + CHUNK - 1) / CHUNK)        // 733
#define NH     (NB * NCHUNK)                       // 107751

// ---------------- bf16 storage helpers (RNE) ----------------
__device__ __forceinline__ float b2f(unsigned short h) {
  return __uint_as_float(((uint32_t)h) << 16);
}
__device__ __forceinline__ unsigned short f2b(float f) {
  uint32_t b = __float_as_uint(f);
  uint32_t r = b + 0x7FFFu + ((b >> 16) & 1u);
  return (unsigned short)(r >> 16);
}

// ---------------- Threefry-2x32 (JAX-compatible) ----------------
__device__ __forceinline__ uint32_t rotl32(uint32_t v, int r) {
  return (v << r) | (v >> (32 - r));
}

__device__ __forceinline__ void tf2x32(uint32_t k0, uint32_t k1,
                                       uint32_t x0, uint32_t x1,
                                       uint32_t &o0, uint32_t &o1) {
  uint32_t k2 = k0 ^ k1 ^ 0x1BD11BDAu;
#define TFR(r) { x0 += x1; x1 = rotl32(x1, (r)); x1 ^= x0; }
  x0 += k0; x1 += k1;
  TFR(13) TFR(15) TFR(26) TFR(6)
  x0 += k1; x1 += k2 + 1u;
  TFR(17) TFR(29) TFR(16) TFR(24)
  x0 += k2; x1 += k0 + 2u;
  TFR(13) TFR(15) TFR(26) TFR(6)
  x0 += k0; x1 += k1 + 3u;
  TFR(17) TFR(29) TFR(16) TFR(24)
  x0 += k1; x1 += k2 + 4u;
  TFR(13) TFR(15) TFR(26) TFR(6)
  x0 += k2; x1 += k0 + 5u;
#undef TFR
  o0 = x0; o1 = x1;
}

__device__ __forceinline__ float tf_unif(uint32_t k0, uint32_t k1, uint32_t e) {
  uint32_t b0, b1;
  tf2x32(k0, k1, 0u, e, b0, b1);
  return __uint_as_float(((b0 ^ b1) >> 9) | 0x3F800000u) - 1.0f;
}

__device__ __forceinline__ float sgnf(float a) {
  return (a > 0.f) ? 1.f : ((a < 0.f) ? -1.f : 0.f);
}

// ---------------- fused per-row histogram + per-chunk bucket histogram -------
__global__ __launch_bounds__(256) void fhist(const int* __restrict__ rows,
                                             int* __restrict__ cnt,
                                             int* __restrict__ Hcnt) {
  __shared__ int bc[NB];
  int c = blockIdx.x, t = threadIdx.x;
  for (int i = t; i < NB; i += 256) bc[i] = 0;
  __syncthreads();
  int base = c * CHUNK;
  for (int i = t; i < CHUNK; i += 256) {
    int e = base + i;
    if (e < NNZC) {
      int r = rows[e];
      atomicAdd(&cnt[r], 1);
      atomicAdd(&bc[r >> BSHIFT], 1);
    }
  }
  __syncthreads();
  for (int i = t; i < NB; i += 256) Hcnt[i * NCHUNK + c] = bc[i];
}

// ---------------- generic hierarchical exclusive scan ----------------
__global__ void scan_block(const int* __restrict__ cnt, int* __restrict__ out,
                           int* __restrict__ bsums, int n) {
  __shared__ int tmp[SCAN_ELEMS];
  int base = blockIdx.x * SCAN_ELEMS;
  int t = threadIdx.x;                 // 256 threads
  #pragma unroll
  for (int q = 0; q < 4; ++q) {
    int k = t + q * 256, i = base + k;
    tmp[k] = (i < n) ? cnt[i] : 0;
  }
  __syncthreads();
  for (int off = 1; off < SCAN_ELEMS; off <<= 1) {
    int v[4];
    #pragma unroll
    for (int q = 0; q < 4; ++q) {
      int k = t + q * 256;
      v[q] = (k >= off) ? tmp[k - off] : 0;
    }
    __syncthreads();
    #pragma unroll
    for (int q = 0; q < 4; ++q) tmp[t + q * 256] += v[q];
    __syncthreads();
  }
  #pragma unroll
  for (int q = 0; q < 4; ++q) {
    int k = t + q * 256, i = base + k;
    if (i < n) out[i] = (k == 0) ? 0 : tmp[k - 1];
  }
  if (t == 0) bsums[blockIdx.x] = tmp[SCAN_ELEMS - 1];
}

__global__ void scan_sums(int* __restrict__ bsums, int nb) {
  __shared__ int tmp[512];
  int t = threadIdx.x;
  tmp[t] = (t < nb) ? bsums[t] : 0;
  __syncthreads();
  for (int off = 1; off < 512; off <<= 1) {
    int v = (t >= off) ? tmp[t - off] : 0;
    __syncthreads();
    tmp[t] += v;
    __syncthreads();
  }
  if (t < nb) bsums[t] = (t == 0) ? 0 : tmp[t - 1];
}

__global__ void add_offsets(int* __restrict__ out, const int* __restrict__ bsums,
                            int n, int tailIdx, int tailVal) {
  int i = blockIdx.x * blockDim.x + threadIdx.x;
  if (i < n) out[i] += bsums[i / SCAN_ELEMS];
  if (i == 0 && tailIdx >= 0) out[tailIdx] = tailVal;
}

// ---------------- partB: LDS-bin chunk, write bucket-contiguous, coalesced ----
__global__ __launch_bounds__(256) void partB(const float* __restrict__ vals,
                                             const int* __restrict__ rows,
                                             const int* __restrict__ cols,
                                             const int* __restrict__ Hofs,
                                             int2* __restrict__ midp,
                                             int* __restrict__ midr) {
  __shared__ int2 stv[CHUNK];     // 32 KB
  __shared__ int  str_[CHUNK];    // 16 KB
  __shared__ int  cnt[256];
  __shared__ int  sc[256];
  __shared__ int  adj[NB];
  int c = blockIdx.x, t = threadIdx.x;
  cnt[t] = 0;
  __syncthreads();
  int base = c * CHUNK;
  for (int i = t; i < CHUNK; i += 256) {
    int e = base + i;
    if (e < NNZC) atomicAdd(&cnt[rows[e] >> BSHIFT], 1);
  }
  __syncthreads();
  sc[t] = cnt[t];
  __syncthreads();
  for (int off = 1; off < 256; off <<= 1) {
    int u = (t >= off) ? sc[t - off] : 0;
    __syncthreads();
    sc[t] += u;
    __syncthreads();
  }
  int excl = sc[t] - cnt[t];
  cnt[t] = excl;                          // becomes LDS cursor
  if (t < NB) adj[t] = Hofs[t * NCHUNK + c] - excl;
  __syncthreads();
  for (int i = t; i < CHUNK; i += 256) {
    int e = base + i;
    if (e < NNZC) {
      int r = rows[e];
      int b = r >> BSHIFT;
      int p = atomicAdd(&cnt[b], 1);
      stv[p] = make_int2(__float_as_int(vals[e]), cols[e] * DIM);
      str_[p] = r;
    }
  }
  __syncthreads();
  int n = NNZC - base;
  if (n > CHUNK) n = CHUNK;
  for (int p = t; p < n; p += 256) {
    int r = str_[p];
    int b = r >> BSHIFT;
    int dst = adj[b] + p;
    midp[dst] = stv[p];
    midr[dst] = r;
  }
}

// ---------------- partC: one block per bucket, place via LDS cursors ----------
__global__ __launch_bounds__(256) void partC(const int2* __restrict__ midp,
                                             const int* __restrict__ midr,
                                             const int* __restrict__ Hofs,
                                             const int* __restrict__ rs,
                                             int2* __restrict__ pairs) {
  __shared__ int cur[BROWS];
  int b = blockIdx.x, t = threadIdx.x;
  int row0 = b << BSHIFT;
  for (int i = t; i < BROWS; i += 256) {
    int r = row0 + i;
    cur[i] = (r < NTOT) ? rs[r] : 0;
  }
  __syncthreads();
  int s = Hofs[b * NCHUNK];
  int e = (b + 1 < NB) ? Hofs[(b + 1) * NCHUNK] : NNZC;
  for (int p = s + t; p < e; p += 256) {
    int r = midr[p];
    int2 v = midp[p];
    int pos = atomicAdd(&cur[r - row0], 1);
    pairs[pos] = v;
  }
}

// ---------------- full SpMM, 4 rows/wave, 16 lanes ----------------
// HOP0 reads the f32 virtual concat; otherwise reads bf16 x. Output bf16.
template <bool PERT, bool HOP0>
__global__ __launch_bounds__(256) void spmm_hop(
    const int2* __restrict__ pairs, const int* __restrict__ rs,
    const float* __restrict__ xf, const float* __restrict__ xfb,
    const unsigned short* __restrict__ x,
    unsigned short* __restrict__ y, uint32_t seed, uint32_t hop) {
  int tid  = threadIdx.x;
  int lane = tid & 63;
  int q    = lane & 15;
  int wave = (blockIdx.x * 256 + tid) >> 6;
  int r    = wave * 4 + (lane >> 4);           // grid exact
  int s    = rs[r];
  int e    = rs[r + 1];
  int q4 = q * 4;
  float a0[4] = {0.f, 0.f, 0.f, 0.f};
  for (int j = s; j < e; j += 8) {
    int2 p[8];
    #pragma unroll
    for (int k = 0; k < 8; ++k)
      p[k] = (j + k < e) ? pairs[j + k] : make_int2(0, 0);
    #pragma unroll
    for (int k = 0; k < 8; ++k) {
      float v = __int_as_float(p[k].x);
      unsigned o = (unsigned)(p[k].y + q4);
      if (HOP0) {
        const float4* p4 = (o < (unsigned)NU64)
                         ? (const float4*)(xf + o)
                         : (const float4*)(xfb + (o - (unsigned)NU64));
        float4 f = *p4;
        a0[0] = fmaf(v, f.x, a0[0]); a0[1] = fmaf(v, f.y, a0[1]);
        a0[2] = fmaf(v, f.z, a0[2]); a0[3] = fmaf(v, f.w, a0[3]);
      } else {
        ushort4 h = *(const ushort4*)(x + o);
        a0[0] = fmaf(v, b2f(h.x), a0[0]); a0[1] = fmaf(v, b2f(h.y), a0[1]);
        a0[2] = fmaf(v, b2f(h.z), a0[2]); a0[3] = fmaf(v, b2f(h.w), a0[3]);
      }
    }
  }
  int ebase = r * 64 + q4;
  if (PERT) {
    uint32_t k0, k1;
    tf2x32(0u, seed, 0u, hop, k0, k1);
    float u[4], ss = 0.f;
    #pragma unroll
    for (int k = 0; k < 4; ++k) {
      u[k] = tf_unif(k0, k1, (uint32_t)(ebase + k));
      ss += u[k] * u[k];
    }
    #pragma unroll
    for (int msk = 1; msk < 16; msk <<= 1) ss += __shfl_xor(ss, msk);
    float sc = EPSP / fmaxf(sqrtf(ss), 1e-12f);
    #pragma unroll
    for (int k = 0; k < 4; ++k) a0[k] += sgnf(a0[k]) * u[k] * sc;
  }
  ushort4 st;
  st.x = f2b(a0[0]); st.y = f2b(a0[1]); st.z = f2b(a0[2]); st.w = f2b(a0[3]);
  *(ushort4*)(y + ebase) = st;
}

// ---------------- in-place hop-0 noise apply / swap (bf16 buffer) -------------
template <bool REVERT>
__global__ __launch_bounds__(256) void perturb(unsigned short* __restrict__ A,
                                               uint32_t seedRm, uint32_t seedAdd) {
  int tid  = threadIdx.x;
  int lane = tid & 63;
  int q    = lane & 15;
  int wave = (blockIdx.x * 256 + tid) >> 6;
  int r    = wave * 4 + (lane >> 4);
  int ebase = r * 64 + q * 4;
  ushort4 h4 = *(ushort4*)(A + ebase);
  float av[4] = {b2f(h4.x), b2f(h4.y), b2f(h4.z), b2f(h4.w)};
  if (REVERT) {
    uint32_t k0, k1;
    tf2x32(0u, seedRm, 0u, 0u, k0, k1);
    float u[4], ss = 0.f;
    #pragma unroll
    for (int k = 0; k < 4; ++k) {
      u[k] = tf_unif(k0, k1, (uint32_t)(ebase + k));
      ss += u[k] * u[k];
    }
    #pragma unroll
    for (int msk = 1; msk < 16; msk <<= 1) ss += __shfl_xor(ss, msk);
    float sc = EPSP / fmaxf(sqrtf(ss), 1e-12f);
    #pragma unroll
    for (int k = 0; k < 4; ++k) av[k] -= sgnf(av[k]) * u[k] * sc;  // sign preserved
  }
  {
    uint32_t k0, k1;
    tf2x32(0u, seedAdd, 0u, 0u, k0, k1);
    float u[4], ss = 0.f;
    #pragma unroll
    for (int k = 0; k < 4; ++k) {
      u[k] = tf_unif(k0, k1, (uint32_t)(ebase + k));
      ss += u[k] * u[k];
    }
    #pragma unroll
    for (int msk = 1; msk < 16; msk <<= 1) ss += __shfl_xor(ss, msk);
    float sc = EPSP / fmaxf(sqrtf(ss), 1e-12f);
    #pragma unroll
    for (int k = 0; k < 4; ++k) av[k] += sgnf(av[k]) * u[k] * sc;
  }
  ushort4 st;
  st.x = f2b(av[0]); st.y = f2b(av[1]); st.z = f2b(av[2]); st.w = f2b(av[3]);
  *(ushort4*)(A + ebase) = st;
}

// ---------------- multi-segment gather-accumulate (bf16 src, f32 acc) ---------
__global__ void gatherM(const unsigned short* __restrict__ src,
                        const int* __restrict__ i0, const int* __restrict__ i1,
                        const int* __restrict__ i2,
                        float* __restrict__ o0, float* __restrict__ o1,
                        float* __restrict__ o2,
                        int b0, int b1, int b2) {
  int seg = blockIdx.y;
  const int* idx = (seg == 0) ? i0 : ((seg == 1) ? i1 : i2);
  float* o = (seg == 0) ? o0 : ((seg == 1) ? o1 : o2);
  int base = (seg == 0) ? b0 : ((seg == 1) ? b1 : b2);
  int gid = blockIdx.x * blockDim.x + threadIdx.x;
  int b = gid >> 6, d = gid & 63;
  o[gid] += b2f(src[(size_t)(base + idx[b]) * DIM + d]);
}

// ---------------- hop-2 gathered SpMM (+fused row noise [+norm]) -------------
template <bool PERT, bool NORM>
__global__ __launch_bounds__(256) void hop2g(
    const int2* __restrict__ pairs, const int* __restrict__ rs,
    const unsigned short* __restrict__ x,
    const int* __restrict__ i0, const int* __restrict__ i1,
    const int* __restrict__ i2,
    float* __restrict__ o0, float* __restrict__ o1, float* __restrict__ o2,
    int b0, int b1, int b2, uint32_t seed) {
  int seg = blockIdx.y;
  const int* idx = (seg == 0) ? i0 : ((seg == 1) ? i1 : i2);
  float* o = (seg == 0) ? o0 : ((seg == 1) ? o1 : o2);
  int base = (seg == 0) ? b0 : ((seg == 1) ? b1 : b2);
  int tid  = threadIdx.x;
  int lane = tid & 63;
  int q    = lane & 15;
  int q4 = q * 4;
  int slot = blockIdx.x * 16 + (tid >> 6) * 4 + (lane >> 4);   // 0..4095
  int row  = base + idx[slot];
  int s    = rs[row];
  int e    = rs[row + 1];
  float a0[4] = {0.f, 0.f, 0.f, 0.f};
  for (int j = s; j < e; j += 8) {
    int2 p[8];
    #pragma unroll
    for (int k = 0; k < 8; ++k)
      p[k] = (j + k < e) ? pairs[j + k] : make_int2(0, 0);
    #pragma unroll
    for (int k = 0; k < 8; ++k) {
      float v = __int_as_float(p[k].x);
      unsigned of = (unsigned)(p[k].y + q4);
      ushort4 h = *(const ushort4*)(x + of);
      a0[0] = fmaf(v, b2f(h.x), a0[0]); a0[1] = fmaf(v, b2f(h.y), a0[1]);
      a0[2] = fmaf(v, b2f(h.z), a0[2]); a0[3] = fmaf(v, b2f(h.w), a0[3]);
    }
  }
  if (PERT) {
    uint32_t k0, k1;
    tf2x32(0u, seed, 0u, 2u, k0, k1);          // hop 2 noise
    int en = row * 64 + q4;                    // element ids use the GLOBAL row
    float u[4], ss = 0.f;
    #pragma unroll
    for (int k = 0; k < 4; ++k) {
      u[k] = tf_unif(k0, k1, (uint32_t)(en + k));
      ss += u[k] * u[k];
    }
    #pragma unroll
    for (int msk = 1; msk < 16; msk <<= 1) ss += __shfl_xor(ss, msk);
    float sc = EPSP / fmaxf(sqrtf(ss), 1e-12f);
    #pragma unroll
    for (int k = 0; k < 4; ++k) a0[k] += sgnf(a0[k]) * u[k] * sc;
  }
  int og = slot * 64 + q4;
  float4 cur = *(float4*)(o + og);
  float rv[4] = {cur.x + a0[0], cur.y + a0[1], cur.z + a0[2], cur.w + a0[3]};
  if (NORM) {
    float ss = rv[0]*rv[0] + rv[1]*rv[1] + rv[2]*rv[2] + rv[3]*rv[3];
    #pragma unroll
    for (int msk = 1; msk < 16; msk <<= 1) ss += __shfl_xor(ss, msk);
    float inv = 1.0f / fmaxf(sqrtf(ss), 1e-12f);
    #pragma unroll
    for (int k = 0; k < 4; ++k) rv[k] *= inv;
  }
  *(float4*)(o + og) = make_float4(rv[0], rv[1], rv[2], rv[3]);
}

// ---------------- InfoNCE phase 1: tiled exp-GEMM row sums (both branches) ----
__global__ __launch_bounds__(256) void nce_ttl(
    const float* __restrict__ u1, const float* __restrict__ u2,
    float* __restrict__ tu,
    const float* __restrict__ w1, const float* __restrict__ w2,
    float* __restrict__ tw) {
  const float* v1 = (blockIdx.z == 0) ? u1 : w1;
  const float* v2 = (blockIdx.z == 0) ? u2 : w2;
  float* ttl      = (blockIdx.z == 0) ? tu : tw;
  __shared__ float s1[IB * LDA];
  __shared__ float s2[JB * LDA];
  __shared__ float tsum[IB];
  int tid = threadIdx.x;
  const float4* v1v = (const float4*)(v1 + (size_t)blockIdx.x * IB * DIM);
  #pragma unroll
  for (int p = 0; p < 4; ++p) {
    int e = tid + p * 256;
    int r = e >> 4, q = e & 15;
    float4 f = v1v[e];
    float* d = &s1[r * LDA + q * 4];
    d[0] = f.x; d[1] = f.y; d[2] = f.z; d[3] = f.w;
  }
  const float4* v2v = (const float4*)(v2 + (size_t)blockIdx.y * JB * DIM);
  #pragma unroll
  for (int p = 0; p < 8; ++p) {
    int e = tid + p * 256;
    int r = e >> 4, q = e & 15;
    float4 f = v2v[e];
    float* d = &s2[r * LDA + q * 4];
    d[0] = f.x; d[1] = f.y; d[2] = f.z; d[3] = f.w;
  }
  if (tid < IB) tsum[tid] = 0.0f;
  __syncthreads();

  int i0 = (tid & 15) * 4;
  int j0 = (tid >> 4) * 8;
  float acc[4][8];
  #pragma unroll
  for (int m = 0; m < 4; ++m)
    #pragma unroll
    for (int n = 0; n < 8; ++n) acc[m][n] = 0.0f;
  #pragma unroll 4
  for (int k = 0; k < DIM; ++k) {
    float a[4], b[8];
    #pragma unroll
    for (int m = 0; m < 4; ++m) a[m] = s1[(i0 + m) * LDA + k];
    #pragma unroll
    for (int n = 0; n < 8; ++n) b[n] = s2[(j0 + n) * LDA + k];
    #pragma unroll
    for (int m = 0; m < 4; ++m)
      #pragma unroll
      for (int n = 0; n < 8; ++n) acc[m][n] = fmaf(a[m], b[n], acc[m][n]);
  }
  #pragma unroll
  for (int m = 0; m < 4; ++m) {
    float ts = 0.0f;
    #pragma unroll
    for (int n = 0; n < 8; ++n) ts += __expf(acc[m][n] * INV_TEMP);
    atomicAdd(&tsum[i0 + m], ts);
  }
  __syncthreads();
  if (tid < IB) atomicAdd(&ttl[blockIdx.x * IB + tid], tsum[tid]);
}

// ---------------- InfoNCE phase 2: diagonal + log, block-reduced --------------
__global__ __launch_bounds__(256) void nce_final(const float* __restrict__ v1,
                                                 const float* __restrict__ v2,
                                                 const float* __restrict__ ttl,
                                                 float* __restrict__ acc) {
  __shared__ float red[4];
  int tid = threadIdx.x, lane = tid & 63, wv = tid >> 6;
  int gw = blockIdx.x * 4 + wv;          // 256 waves total
  float l = 0.f;
  for (int r = gw; r < BATCH; r += 256) {
    int gid = r * 64 + lane;
    float p = v1[gid] * v2[gid];
    #pragma unroll
    for (int m = 32; m; m >>= 1) p += __shfl_xor(p, m);
    if (lane == 0) l += -logf(__expf(p * INV_TEMP) / ttl[r] + 1e-5f);
  }
  if (lane == 0) red[wv] = l;
  __syncthreads();
  if (tid == 0) atomicAdd(acc, red[0] + red[1] + red[2] + red[3]);
}

// ---------------- BPR rec loss + reg, block-reduced ----------------
__global__ __launch_bounds__(256) void rec_kernel(const float* __restrict__ ue,
                                                  const float* __restrict__ pe,
                                                  const float* __restrict__ ne,
                                                  float* __restrict__ acc) {
  __shared__ float red[3][4];
  int tid = threadIdx.x, lane = tid & 63, wv = tid >> 6;
  int gw = blockIdx.x * 4 + wv;          // 256 waves total
  const float third = 1.0f / 3.0f;
  float l = 0.f, su = 0.f, sp = 0.f;
  for (int r = gw; r < BATCH; r += 256) {
    int gid = r * 64 + lane;
    float u = ue[gid] * third, p = pe[gid] * third, n = ne[gid] * third;
    float ps = u * p, ns = u * n;
    su += u * u; sp += p * p;
    #pragma unroll
    for (int m = 32; m; m >>= 1) { ps += __shfl_xor(ps, m); ns += __shfl_xor(ns, m); }
    if (lane == 0) {
      float sig = 1.0f / (1.0f + __expf(-(ps - ns)));
      l += -logf(1e-5f + sig);
    }
  }
  #pragma unroll
  for (int m = 32; m; m >>= 1) { su += __shfl_xor(su, m); sp += __shfl_xor(sp, m); }
  if (lane == 0) { red[0][wv] = l; red[1][wv] = su; red[2][wv] = sp; }
  __syncthreads();
  if (tid == 0) {
    atomicAdd(acc + 0, red[0][0] + red[0][1] + red[0][2] + red[0][3]);
    atomicAdd(acc + 1, red[1][0] + red[1][1] + red[1][2] + red[1][3]);
    atomicAdd(acc + 2, red[2][0] + red[2][1] + red[2][2] + red[2][3]);
  }
}

__global__ void finalize_kernel(const float* __restrict__ acc, float* __restrict__ out) {
  out[0] = acc[0] * (1.0f / BATCH)
         + 1e-4f * (sqrtf(acc[1]) + sqrtf(acc[2]))
         + 0.5f * (acc[3] + acc[4]) * (1.0f / BATCH);
}

extern "C" void kernel_launch(void* const* d_in, const int* in_sizes, int n_in,
                              void* d_out, int out_size, void* d_ws, size_t ws_size,
                              hipStream_t stream) {
  (void)in_sizes; (void)n_in; (void)out_size; (void)ws_size;
  const float* user_embed = (const float*)d_in[0];
  const float* item_embed = (const float*)d_in[1];
  const float* adj_vals   = (const float*)d_in[2];
  const int*   adj_rows   = (const int*)d_in[3];
  const int*   adj_cols   = (const int*)d_in[4];
  const int*   users      = (const int*)d_in[5];
  const int*   pos_items  = (const int*)d_in[6];
  const int*   neg_items  = (const int*)d_in[7];
  float* out = (float*)d_out;

  const size_t bufElems = (size_t)NTOT * DIM;

  // ---- workspace layout (bf16 hop buffers: 2 × 38.4 MB) ----
  unsigned short* A = (unsigned short*)d_ws;      // bufElems bf16
  unsigned short* B = A + bufElems;               // bufElems bf16
  int2*  pairs = (int2*)(B + bufElems);           // NNZC
  float* g     = (float*)(pairs + NNZC);          // GELEMS
  float* g_ue = g + 0 * (size_t)B64;
  float* g_pe = g + 1 * (size_t)B64;
  float* g_ne = g + 2 * (size_t)B64;
  float* g_u1 = g + 3 * (size_t)B64;
  float* g_i1 = g + 4 * (size_t)B64;
  float* g_u2 = g + 5 * (size_t)B64;
  float* g_i2 = g + 6 * (size_t)B64;
  float* ttl_u = g + 7 * (size_t)B64;
  float* ttl_i = ttl_u + BATCH;
  float* acc   = ttl_i + BATCH;       // 8 scalars
  int* rs     = (int*)(g + GELEMS);   // NTOT+1
  int* cursor = rs + (NTOT + 1);      // NTOT (row-count scratch)
  int* bsums  = cursor + NTOT;        // 512

  // build-time scratch aliased into A+B region (36.9 MB < 76.8 MB available)
  int2* midp = (int2*)A;              // NNZC int2
  int*  midr = (int*)(midp + NNZC);   // NNZC int
  int*  Hcnt = midr + NNZC;           // NH
  int*  Hofs = Hcnt + NH;             // NH

  hipMemsetAsync(g, 0, GELEMS * sizeof(float), stream);
  hipMemsetAsync(cursor, 0, (size_t)NTOT * sizeof(int), stream);

  // ---- CSR build: fused hist, scans, binned two-pass partition ----
  fhist<<<NCHUNK, 256, 0, stream>>>(adj_rows, cursor, Hcnt);
  scan_block<<<NSCAN_BLOCKS, 256, 0, stream>>>(cursor, rs, bsums, NTOT);
  scan_sums<<<1, 512, 0, stream>>>(bsums, NSCAN_BLOCKS);
  add_offsets<<<(NTOT + 255) / 256, 256, 0, stream>>>(rs, bsums, NTOT, NTOT, NNZC);
  const int nhb = (NH + SCAN_ELEMS - 1) / SCAN_ELEMS;
  scan_block<<<nhb, 256, 0, stream>>>(Hcnt, Hofs, bsums, NH);
  scan_sums<<<1, 512, 0, stream>>>(bsums, nhb);
  add_offsets<<<(NH + 255) / 256, 256, 0, stream>>>(Hofs, bsums, NH, -1, 0);
  partB<<<NCHUNK, 256, 0, stream>>>(adj_vals, adj_rows, adj_cols, Hofs, midp, midr);
  partC<<<NB, 256, 0, stream>>>(midp, midr, Hofs, rs, pairs);

  const int spmm_blocks = NTOT / 16;           // 18750
  dim3 gat3(B64 / 256, 3), gat2(B64 / 256, 2);
  dim3 h2g3(BATCH / 16, 3), h2g2(BATCH / 16, 2);

  // ---- branch 0 (clean) ----
  spmm_hop<false, true><<<spmm_blocks, 256, 0, stream>>>(
      pairs, rs, user_embed, item_embed, nullptr, A, 0u, 0u);   // hop0 -> A
  gatherM<<<gat3, 256, 0, stream>>>(A, users, pos_items, neg_items,
                                    g_ue, g_pe, g_ne, 0, NUSERS, NUSERS);
  spmm_hop<false, false><<<spmm_blocks, 256, 0, stream>>>(
      pairs, rs, nullptr, nullptr, A, B, 0u, 0u);               // hop1 -> B
  gatherM<<<gat3, 256, 0, stream>>>(B, users, pos_items, neg_items,
                                    g_ue, g_pe, g_ne, 0, NUSERS, NUSERS);
  hop2g<false, false><<<h2g3, 256, 0, stream>>>(
      pairs, rs, B, users, pos_items, neg_items,
      g_ue, g_pe, g_ne, 0, NUSERS, NUSERS, 0u);

  // ---- branch 1 (seed 101) ----
  perturb<false><<<spmm_blocks, 256, 0, stream>>>(A, 0u, 101u); // A = hop0 + n(101,0)
  gatherM<<<gat2, 256, 0, stream>>>(A, users, pos_items, nullptr,
                                    g_u1, g_i1, nullptr, 0, NUSERS, 0);
  spmm_hop<true, false><<<spmm_blocks, 256, 0, stream>>>(
      pairs, rs, nullptr, nullptr, A, B, 101u, 1u);             // hop1 + n(101,1)
  gatherM<<<gat2, 256, 0, stream>>>(B, users, pos_items, nullptr,
                                    g_u1, g_i1, nullptr, 0, NUSERS, 0);
  hop2g<true, true><<<h2g2, 256, 0, stream>>>(
      pairs, rs, B, users, pos_items, nullptr,
      g_u1, g_i1, nullptr, 0, NUSERS, 0, 101u);                 // + fused rownorm

  // ---- branch 2 (seed 202) ----
  perturb<true><<<spmm_blocks, 256, 0, stream>>>(A, 101u, 202u); // swap noise views
  gatherM<<<gat2, 256, 0, stream>>>(A, users, pos_items, nullptr,
                                    g_u2, g_i2, nullptr, 0, NUSERS, 0);
  spmm_hop<true, false><<<spmm_blocks, 256, 0, stream>>>(
      pairs, rs, nullptr, nullptr, A, B, 202u, 1u);
  gatherM<<<gat2, 256, 0, stream>>>(B, users, pos_items, nullptr,
                                    g_u2, g_i2, nullptr, 0, NUSERS, 0);
  hop2g<true, true><<<h2g2, 256, 0, stream>>>(
      pairs, rs, B, users, pos_items, nullptr,
      g_u2, g_i2, nullptr, 0, NUSERS, 0, 202u);                 // + fused rownorm

  // ---- losses ----
  rec_kernel<<<64, 256, 0, stream>>>(g_ue, g_pe, g_ne, acc);
  dim3 nce_grid(BATCH / IB, BATCH / JB, 2);
  nce_ttl<<<nce_grid, 256, 0, stream>>>(g_u1, g_u2, ttl_u, g_i1, g_i2, ttl_i);
  nce_final<<<64, 256, 0, stream>>>(g_u1, g_u2, ttl_u, acc + 3);
  nce_final<<<64, 256, 0, stream>>>(g_i1, g_i2, ttl_i, acc + 4);
  finalize_kernel<<<1, 1, 0, stream>>>(acc, out);
}

// Round 10
// 902.039 us; speedup vs baseline: 8.7702x; 1.1362x over previous
//
#include <hip/hip_runtime.h>
#include <stdint.h>

#define NUSERS  200000
#define NITEMS  100000
#define NTOT    300000
#define DIM     64
#define NU64    (NUSERS * DIM)
#define NNZC    3000000
#define BATCH   4096
#define B64     (BATCH * DIM)
#define EPSP    0.1f
#define INV_TEMP 5.0f   // 1 / 0.2
#define SCAN_ELEMS 1024
#define IB 64
#define JB 128
#define LDA 65
#define GELEMS ((size_t)7 * B64 + 2 * BATCH + 8)

// ---- binned CSR build params ----
#define BSHIFT 11
#define BROWS  (1 << BSHIFT)                       // 2048 rows per bucket
#define NB     ((NTOT + BROWS - 1) / BROWS)        // 147 buckets
#define CHUNK  4096
#define NCHUNK ((NNZC + CHUNK - 1) / CHUNK)        // 733
#define NH     (NB * NCHUNK)                       // 107751

// ---------------- bf16 storage helpers (RNE) ----------------
__device__ __forceinline__ float b2f(unsigned short h) {
  return __uint_as_float(((uint32_t)h) << 16);
}
__device__ __forceinline__ unsigned short f2b(float f) {
  uint32_t b = __float_as_uint(f);
  uint32_t r = b + 0x7FFFu + ((b >> 16) & 1u);
  return (unsigned short)(r >> 16);
}

// ---------------- Threefry-2x32 (JAX-compatible) ----------------
__device__ __forceinline__ uint32_t rotl32(uint32_t v, int r) {
  return (v << r) | (v >> (32 - r));
}

__device__ __forceinline__ void tf2x32(uint32_t k0, uint32_t k1,
                                       uint32_t x0, uint32_t x1,
                                       uint32_t &o0, uint32_t &o1) {
  uint32_t k2 = k0 ^ k1 ^ 0x1BD11BDAu;
#define TFR(r) { x0 += x1; x1 = rotl32(x1, (r)); x1 ^= x0; }
  x0 += k0; x1 += k1;
  TFR(13) TFR(15) TFR(26) TFR(6)
  x0 += k1; x1 += k2 + 1u;
  TFR(17) TFR(29) TFR(16) TFR(24)
  x0 += k2; x1 += k0 + 2u;
  TFR(13) TFR(15) TFR(26) TFR(6)
  x0 += k0; x1 += k1 + 3u;
  TFR(17) TFR(29) TFR(16) TFR(24)
  x0 += k1; x1 += k2 + 4u;
  TFR(13) TFR(15) TFR(26) TFR(6)
  x0 += k2; x1 += k0 + 5u;
#undef TFR
  o0 = x0; o1 = x1;
}

__device__ __forceinline__ float tf_unif(uint32_t k0, uint32_t k1, uint32_t e) {
  uint32_t b0, b1;
  tf2x32(k0, k1, 0u, e, b0, b1);
  return __uint_as_float(((b0 ^ b1) >> 9) | 0x3F800000u) - 1.0f;
}

__device__ __forceinline__ float sgnf(float a) {
  return (a > 0.f) ? 1.f : ((a < 0.f) ? -1.f : 0.f);
}

// ---------------- partA: per-chunk bucket histogram (LDS only) ----------------
__global__ __launch_bounds__(256) void partA(const int* __restrict__ rows,
                                             int* __restrict__ Hcnt) {
  __shared__ int bc[256];
  int c = blockIdx.x, t = threadIdx.x;
  bc[t] = 0;
  __syncthreads();
  int base = c * CHUNK;
  for (int i = t; i < CHUNK; i += 256) {
    int e = base + i;
    if (e < NNZC) atomicAdd(&bc[rows[e] >> BSHIFT], 1);
  }
  __syncthreads();
  if (t < NB) Hcnt[t * NCHUNK + c] = bc[t];
}

// ---------------- generic hierarchical exclusive scan ----------------
__global__ void scan_block(const int* __restrict__ cnt, int* __restrict__ out,
                           int* __restrict__ bsums, int n) {
  __shared__ int tmp[SCAN_ELEMS];
  int base = blockIdx.x * SCAN_ELEMS;
  int t = threadIdx.x;                 // 256 threads
  #pragma unroll
  for (int q = 0; q < 4; ++q) {
    int k = t + q * 256, i = base + k;
    tmp[k] = (i < n) ? cnt[i] : 0;
  }
  __syncthreads();
  for (int off = 1; off < SCAN_ELEMS; off <<= 1) {
    int v[4];
    #pragma unroll
    for (int q = 0; q < 4; ++q) {
      int k = t + q * 256;
      v[q] = (k >= off) ? tmp[k - off] : 0;
    }
    __syncthreads();
    #pragma unroll
    for (int q = 0; q < 4; ++q) tmp[t + q * 256] += v[q];
    __syncthreads();
  }
  #pragma unroll
  for (int q = 0; q < 4; ++q) {
    int k = t + q * 256, i = base + k;
    if (i < n) out[i] = (k == 0) ? 0 : tmp[k - 1];
  }
  if (t == 0) bsums[blockIdx.x] = tmp[SCAN_ELEMS - 1];
}

__global__ void scan_sums(int* __restrict__ bsums, int nb) {
  __shared__ int tmp[512];
  int t = threadIdx.x;
  tmp[t] = (t < nb) ? bsums[t] : 0;
  __syncthreads();
  for (int off = 1; off < 512; off <<= 1) {
    int v = (t >= off) ? tmp[t - off] : 0;
    __syncthreads();
    tmp[t] += v;
    __syncthreads();
  }
  if (t < nb) bsums[t] = (t == 0) ? 0 : tmp[t - 1];
}

__global__ void add_offsets(int* __restrict__ out, const int* __restrict__ bsums,
                            int n) {
  int i = blockIdx.x * blockDim.x + threadIdx.x;
  if (i < n) out[i] += bsums[i / SCAN_ELEMS];
}

// ---------------- partB: LDS-bin chunk, write bucket-contiguous, coalesced ----
__global__ __launch_bounds__(256) void partB(const float* __restrict__ vals,
                                             const int* __restrict__ rows,
                                             const int* __restrict__ cols,
                                             const int* __restrict__ Hofs,
                                             int2* __restrict__ midp,
                                             int* __restrict__ midr) {
  __shared__ int2 stv[CHUNK];     // 32 KB
  __shared__ int  str_[CHUNK];    // 16 KB
  __shared__ int  cnt[256];
  __shared__ int  sc[256];
  __shared__ int  adj[NB];
  int c = blockIdx.x, t = threadIdx.x;
  cnt[t] = 0;
  __syncthreads();
  int base = c * CHUNK;
  for (int i = t; i < CHUNK; i += 256) {
    int e = base + i;
    if (e < NNZC) atomicAdd(&cnt[rows[e] >> BSHIFT], 1);
  }
  __syncthreads();
  sc[t] = cnt[t];
  __syncthreads();
  for (int off = 1; off < 256; off <<= 1) {
    int u = (t >= off) ? sc[t - off] : 0;
    __syncthreads();
    sc[t] += u;
    __syncthreads();
  }
  int excl = sc[t] - cnt[t];
  cnt[t] = excl;                          // becomes LDS cursor
  if (t < NB) adj[t] = Hofs[t * NCHUNK + c] - excl;
  __syncthreads();
  for (int i = t; i < CHUNK; i += 256) {
    int e = base + i;
    if (e < NNZC) {
      int r = rows[e];
      int b = r >> BSHIFT;
      int p = atomicAdd(&cnt[b], 1);
      stv[p] = make_int2(__float_as_int(vals[e]), cols[e] * DIM);
      str_[p] = r;
    }
  }
  __syncthreads();
  int n = NNZC - base;
  if (n > CHUNK) n = CHUNK;
  for (int p = t; p < n; p += 256) {
    int r = str_[p];
    int b = r >> BSHIFT;
    int dst = adj[b] + p;
    midp[dst] = stv[p];
    midr[dst] = r;
  }
}

// ---------------- partC: per-bucket row-hist + scan -> rs slice + placement ---
__global__ __launch_bounds__(256) void partC(const int2* __restrict__ midp,
                                             const int* __restrict__ midr,
                                             const int* __restrict__ Hofs,
                                             int* __restrict__ rs,
                                             int2* __restrict__ pairs) {
  __shared__ int h[BROWS];        // histogram -> cursors
  __shared__ int tsum[256];
  int b = blockIdx.x, t = threadIdx.x;
  int row0 = b << BSHIFT;
  for (int i = t; i < BROWS; i += 256) h[i] = 0;
  __syncthreads();
  int s = Hofs[b * NCHUNK];
  int e = (b + 1 < NB) ? Hofs[(b + 1) * NCHUNK] : NNZC;
  for (int p = s + t; p < e; p += 256)
    atomicAdd(&h[midr[p] - row0], 1);
  __syncthreads();
  // scan: thread t owns h[t*8 .. t*8+8)
  int loc[8], run = 0;
  #pragma unroll
  for (int k = 0; k < 8; ++k) { loc[k] = run; run += h[t * 8 + k]; }
  tsum[t] = run;
  __syncthreads();
  for (int off = 1; off < 256; off <<= 1) {
    int v = (t >= off) ? tsum[t - off] : 0;
    __syncthreads();
    tsum[t] += v;
    __syncthreads();
  }
  int baseT = (t == 0) ? 0 : tsum[t - 1];
  #pragma unroll
  for (int k = 0; k < 8; ++k) {
    int i = t * 8 + k;
    int pos = s + baseT + loc[k];
    if (row0 + i < NTOT) rs[row0 + i] = pos;
    h[i] = pos;                        // cursor
  }
  if (b == NB - 1 && t == 0) rs[NTOT] = NNZC;
  __syncthreads();
  for (int p = s + t; p < e; p += 256) {
    int r = midr[p];
    int2 v = midp[p];
    int pos = atomicAdd(&h[r - row0], 1);
    pairs[pos] = v;
  }
}

// ---------------- full SpMM, 4 rows/wave, 16 lanes ----------------
// HOP0 reads the f32 virtual concat; otherwise reads bf16 x. Output bf16.
template <bool PERT, bool HOP0>
__global__ __launch_bounds__(256) void spmm_hop(
    const int2* __restrict__ pairs, const int* __restrict__ rs,
    const float* __restrict__ xf, const float* __restrict__ xfb,
    const unsigned short* __restrict__ x,
    unsigned short* __restrict__ y, uint32_t seed, uint32_t hop) {
  int tid  = threadIdx.x;
  int lane = tid & 63;
  int q    = lane & 15;
  int wave = (blockIdx.x * 256 + tid) >> 6;
  int r    = wave * 4 + (lane >> 4);           // grid exact
  int s    = rs[r];
  int e    = rs[r + 1];
  int q4 = q * 4;
  float a0[4] = {0.f, 0.f, 0.f, 0.f};
  for (int j = s; j < e; j += 8) {
    int2 p[8];
    #pragma unroll
    for (int k = 0; k < 8; ++k)
      p[k] = (j + k < e) ? pairs[j + k] : make_int2(0, 0);
    #pragma unroll
    for (int k = 0; k < 8; ++k) {
      float v = __int_as_float(p[k].x);
      unsigned o = (unsigned)(p[k].y + q4);
      if (HOP0) {
        const float4* p4 = (o < (unsigned)NU64)
                         ? (const float4*)(xf + o)
                         : (const float4*)(xfb + (o - (unsigned)NU64));
        float4 f = *p4;
        a0[0] = fmaf(v, f.x, a0[0]); a0[1] = fmaf(v, f.y, a0[1]);
        a0[2] = fmaf(v, f.z, a0[2]); a0[3] = fmaf(v, f.w, a0[3]);
      } else {
        ushort4 h = *(const ushort4*)(x + o);
        a0[0] = fmaf(v, b2f(h.x), a0[0]); a0[1] = fmaf(v, b2f(h.y), a0[1]);
        a0[2] = fmaf(v, b2f(h.z), a0[2]); a0[3] = fmaf(v, b2f(h.w), a0[3]);
      }
    }
  }
  int ebase = r * 64 + q4;
  if (PERT) {
    uint32_t k0, k1;
    tf2x32(0u, seed, 0u, hop, k0, k1);
    float u[4], ss = 0.f;
    #pragma unroll
    for (int k = 0; k < 4; ++k) {
      u[k] = tf_unif(k0, k1, (uint32_t)(ebase + k));
      ss += u[k] * u[k];
    }
    #pragma unroll
    for (int msk = 1; msk < 16; msk <<= 1) ss += __shfl_xor(ss, msk);
    float sc = EPSP / fmaxf(sqrtf(ss), 1e-12f);
    #pragma unroll
    for (int k = 0; k < 4; ++k) a0[k] += sgnf(a0[k]) * u[k] * sc;
  }
  ushort4 st;
  st.x = f2b(a0[0]); st.y = f2b(a0[1]); st.z = f2b(a0[2]); st.w = f2b(a0[3]);
  *(ushort4*)(y + ebase) = st;
}

// ---------------- in-place hop-0 noise apply / swap (bf16 buffer) -------------
template <bool REVERT>
__global__ __launch_bounds__(256) void perturb(unsigned short* __restrict__ A,
                                               uint32_t seedRm, uint32_t seedAdd) {
  int tid  = threadIdx.x;
  int lane = tid & 63;
  int q    = lane & 15;
  int wave = (blockIdx.x * 256 + tid) >> 6;
  int r    = wave * 4 + (lane >> 4);
  int ebase = r * 64 + q * 4;
  ushort4 h4 = *(ushort4*)(A + ebase);
  float av[4] = {b2f(h4.x), b2f(h4.y), b2f(h4.z), b2f(h4.w)};
  if (REVERT) {
    uint32_t k0, k1;
    tf2x32(0u, seedRm, 0u, 0u, k0, k1);
    float u[4], ss = 0.f;
    #pragma unroll
    for (int k = 0; k < 4; ++k) {
      u[k] = tf_unif(k0, k1, (uint32_t)(ebase + k));
      ss += u[k] * u[k];
    }
    #pragma unroll
    for (int msk = 1; msk < 16; msk <<= 1) ss += __shfl_xor(ss, msk);
    float sc = EPSP / fmaxf(sqrtf(ss), 1e-12f);
    #pragma unroll
    for (int k = 0; k < 4; ++k) av[k] -= sgnf(av[k]) * u[k] * sc;  // sign preserved
  }
  {
    uint32_t k0, k1;
    tf2x32(0u, seedAdd, 0u, 0u, k0, k1);
    float u[4], ss = 0.f;
    #pragma unroll
    for (int k = 0; k < 4; ++k) {
      u[k] = tf_unif(k0, k1, (uint32_t)(ebase + k));
      ss += u[k] * u[k];
    }
    #pragma unroll
    for (int msk = 1; msk < 16; msk <<= 1) ss += __shfl_xor(ss, msk);
    float sc = EPSP / fmaxf(sqrtf(ss), 1e-12f);
    #pragma unroll
    for (int k = 0; k < 4; ++k) av[k] += sgnf(av[k]) * u[k] * sc;
  }
  ushort4 st;
  st.x = f2b(av[0]); st.y = f2b(av[1]); st.z = f2b(av[2]); st.w = f2b(av[3]);
  *(ushort4*)(A + ebase) = st;
}

// ---------------- hop-2 gathered SpMM, fused A/B gathers (+noise [+norm]) -----
// g_out[slot] = A[row] + B[row] + (hop2 [+ noise]); optional row-normalize.
template <bool PERT, bool NORM>
__global__ __launch_bounds__(256) void hop2g(
    const int2* __restrict__ pairs, const int* __restrict__ rs,
    const unsigned short* __restrict__ Abuf,
    const unsigned short* __restrict__ Bbuf,
    const int* __restrict__ i0, const int* __restrict__ i1,
    const int* __restrict__ i2,
    float* __restrict__ o0, float* __restrict__ o1, float* __restrict__ o2,
    int b0, int b1, int b2, uint32_t seed) {
  int seg = blockIdx.y;
  const int* idx = (seg == 0) ? i0 : ((seg == 1) ? i1 : i2);
  float* o = (seg == 0) ? o0 : ((seg == 1) ? o1 : o2);
  int base = (seg == 0) ? b0 : ((seg == 1) ? b1 : b2);
  int tid  = threadIdx.x;
  int lane = tid & 63;
  int q    = lane & 15;
  int q4 = q * 4;
  int slot = blockIdx.x * 16 + (tid >> 6) * 4 + (lane >> 4);   // 0..4095
  int row  = base + idx[slot];
  int s    = rs[row];
  int e    = rs[row + 1];
  float a0[4] = {0.f, 0.f, 0.f, 0.f};
  for (int j = s; j < e; j += 8) {
    int2 p[8];
    #pragma unroll
    for (int k = 0; k < 8; ++k)
      p[k] = (j + k < e) ? pairs[j + k] : make_int2(0, 0);
    #pragma unroll
    for (int k = 0; k < 8; ++k) {
      float v = __int_as_float(p[k].x);
      unsigned of = (unsigned)(p[k].y + q4);
      ushort4 h = *(const ushort4*)(Bbuf + of);
      a0[0] = fmaf(v, b2f(h.x), a0[0]); a0[1] = fmaf(v, b2f(h.y), a0[1]);
      a0[2] = fmaf(v, b2f(h.z), a0[2]); a0[3] = fmaf(v, b2f(h.w), a0[3]);
    }
  }
  if (PERT) {
    uint32_t k0, k1;
    tf2x32(0u, seed, 0u, 2u, k0, k1);          // hop 2 noise
    int en = row * 64 + q4;                    // element ids use the GLOBAL row
    float u[4], ss = 0.f;
    #pragma unroll
    for (int k = 0; k < 4; ++k) {
      u[k] = tf_unif(k0, k1, (uint32_t)(en + k));
      ss += u[k] * u[k];
    }
    #pragma unroll
    for (int msk = 1; msk < 16; msk <<= 1) ss += __shfl_xor(ss, msk);
    float sc = EPSP / fmaxf(sqrtf(ss), 1e-12f);
    #pragma unroll
    for (int k = 0; k < 4; ++k) a0[k] += sgnf(a0[k]) * u[k] * sc;
  }
  // fused hop0/hop1 gathers: A[row] + B[row]
  size_t rb = (size_t)row * DIM + q4;
  ushort4 ha = *(const ushort4*)(Abuf + rb);
  ushort4 hb = *(const ushort4*)(Bbuf + rb);
  float rv[4];
  rv[0] = (b2f(ha.x) + b2f(hb.x)) + a0[0];
  rv[1] = (b2f(ha.y) + b2f(hb.y)) + a0[1];
  rv[2] = (b2f(ha.z) + b2f(hb.z)) + a0[2];
  rv[3] = (b2f(ha.w) + b2f(hb.w)) + a0[3];
  if (NORM) {
    float ss = rv[0]*rv[0] + rv[1]*rv[1] + rv[2]*rv[2] + rv[3]*rv[3];
    #pragma unroll
    for (int msk = 1; msk < 16; msk <<= 1) ss += __shfl_xor(ss, msk);
    float inv = 1.0f / fmaxf(sqrtf(ss), 1e-12f);
    #pragma unroll
    for (int k = 0; k < 4; ++k) rv[k] *= inv;
  }
  int og = slot * 64 + q4;
  *(float4*)(o + og) = make_float4(rv[0], rv[1], rv[2], rv[3]);
}

// ---------------- InfoNCE phase 1: tiled exp-GEMM row sums (both branches) ----
__global__ __launch_bounds__(256) void nce_ttl(
    const float* __restrict__ u1, const float* __restrict__ u2,
    float* __restrict__ tu,
    const float* __restrict__ w1, const float* __restrict__ w2,
    float* __restrict__ tw) {
  const float* v1 = (blockIdx.z == 0) ? u1 : w1;
  const float* v2 = (blockIdx.z == 0) ? u2 : w2;
  float* ttl      = (blockIdx.z == 0) ? tu : tw;
  __shared__ float s1[IB * LDA];
  __shared__ float s2[JB * LDA];
  __shared__ float tsum[IB];
  int tid = threadIdx.x;
  const float4* v1v = (const float4*)(v1 + (size_t)blockIdx.x * IB * DIM);
  #pragma unroll
  for (int p = 0; p < 4; ++p) {
    int e = tid + p * 256;
    int r = e >> 4, q = e & 15;
    float4 f = v1v[e];
    float* d = &s1[r * LDA + q * 4];
    d[0] = f.x; d[1] = f.y; d[2] = f.z; d[3] = f.w;
  }
  const float4* v2v = (const float4*)(v2 + (size_t)blockIdx.y * JB * DIM);
  #pragma unroll
  for (int p = 0; p < 8; ++p) {
    int e = tid + p * 256;
    int r = e >> 4, q = e & 15;
    float4 f = v2v[e];
    float* d = &s2[r * LDA + q * 4];
    d[0] = f.x; d[1] = f.y; d[2] = f.z; d[3] = f.w;
  }
  if (tid < IB) tsum[tid] = 0.0f;
  __syncthreads();

  int i0 = (tid & 15) * 4;
  int j0 = (tid >> 4) * 8;
  float acc[4][8];
  #pragma unroll
  for (int m = 0; m < 4; ++m)
    #pragma unroll
    for (int n = 0; n < 8; ++n) acc[m][n] = 0.0f;
  #pragma unroll 4
  for (int k = 0; k < DIM; ++k) {
    float a[4], b[8];
    #pragma unroll
    for (int m = 0; m < 4; ++m) a[m] = s1[(i0 + m) * LDA + k];
    #pragma unroll
    for (int n = 0; n < 8; ++n) b[n] = s2[(j0 + n) * LDA + k];
    #pragma unroll
    for (int m = 0; m < 4; ++m)
      #pragma unroll
      for (int n = 0; n < 8; ++n) acc[m][n] = fmaf(a[m], b[n], acc[m][n]);
  }
  #pragma unroll
  for (int m = 0; m < 4; ++m) {
    float ts = 0.0f;
    #pragma unroll
    for (int n = 0; n < 8; ++n) ts += __expf(acc[m][n] * INV_TEMP);
    atomicAdd(&tsum[i0 + m], ts);
  }
  __syncthreads();
  if (tid < IB) atomicAdd(&ttl[blockIdx.x * IB + tid], tsum[tid]);
}

// ---------------- InfoNCE phase 2: diagonal + log, block-reduced --------------
__global__ __launch_bounds__(256) void nce_final(const float* __restrict__ v1,
                                                 const float* __restrict__ v2,
                                                 const float* __restrict__ ttl,
                                                 float* __restrict__ acc) {
  __shared__ float red[4];
  int tid = threadIdx.x, lane = tid & 63, wv = tid >> 6;
  int gw = blockIdx.x * 4 + wv;          // 256 waves total
  float l = 0.f;
  for (int r = gw; r < BATCH; r += 256) {
    int gid = r * 64 + lane;
    float p = v1[gid] * v2[gid];
    #pragma unroll
    for (int m = 32; m; m >>= 1) p += __shfl_xor(p, m);
    if (lane == 0) l += -logf(__expf(p * INV_TEMP) / ttl[r] + 1e-5f);
  }
  if (lane == 0) red[wv] = l;
  __syncthreads();
  if (tid == 0) atomicAdd(acc, red[0] + red[1] + red[2] + red[3]);
}

// ---------------- BPR rec loss + reg, block-reduced ----------------
__global__ __launch_bounds__(256) void rec_kernel(const float* __restrict__ ue,
                                                  const float* __restrict__ pe,
                                                  const float* __restrict__ ne,
                                                  float* __restrict__ acc) {
  __shared__ float red[3][4];
  int tid = threadIdx.x, lane = tid & 63, wv = tid >> 6;
  int gw = blockIdx.x * 4 + wv;          // 256 waves total
  const float third = 1.0f / 3.0f;
  float l = 0.f, su = 0.f, sp = 0.f;
  for (int r = gw; r < BATCH; r += 256) {
    int gid = r * 64 + lane;
    float u = ue[gid] * third, p = pe[gid] * third, n = ne[gid] * third;
    float ps = u * p, ns = u * n;
    su += u * u; sp += p * p;
    #pragma unroll
    for (int m = 32; m; m >>= 1) { ps += __shfl_xor(ps, m); ns += __shfl_xor(ns, m); }
    if (lane == 0) {
      float sig = 1.0f / (1.0f + __expf(-(ps - ns)));
      l += -logf(1e-5f + sig);
    }
  }
  #pragma unroll
  for (int m = 32; m; m >>= 1) { su += __shfl_xor(su, m); sp += __shfl_xor(sp, m); }
  if (lane == 0) { red[0][wv] = l; red[1][wv] = su; red[2][wv] = sp; }
  __syncthreads();
  if (tid == 0) {
    atomicAdd(acc + 0, red[0][0] + red[0][1] + red[0][2] + red[0][3]);
    atomicAdd(acc + 1, red[1][0] + red[1][1] + red[1][2] + red[1][3]);
    atomicAdd(acc + 2, red[2][0] + red[2][1] + red[2][2] + red[2][3]);
  }
}

__global__ void finalize_kernel(const float* __restrict__ acc, float* __restrict__ out) {
  out[0] = acc[0] * (1.0f / BATCH)
         + 1e-4f * (sqrtf(acc[1]) + sqrtf(acc[2]))
         + 0.5f * (acc[3] + acc[4]) * (1.0f / BATCH);
}

extern "C" void kernel_launch(void* const* d_in, const int* in_sizes, int n_in,
                              void* d_out, int out_size, void* d_ws, size_t ws_size,
                              hipStream_t stream) {
  (void)in_sizes; (void)n_in; (void)out_size; (void)ws_size;
  const float* user_embed = (const float*)d_in[0];
  const float* item_embed = (const float*)d_in[1];
  const float* adj_vals   = (const float*)d_in[2];
  const int*   adj_rows   = (const int*)d_in[3];
  const int*   adj_cols   = (const int*)d_in[4];
  const int*   users      = (const int*)d_in[5];
  const int*   pos_items  = (const int*)d_in[6];
  const int*   neg_items  = (const int*)d_in[7];
  float* out = (float*)d_out;

  const size_t bufElems = (size_t)NTOT * DIM;

  // ---- workspace layout (bf16 hop buffers: 2 × 38.4 MB) ----
  unsigned short* A = (unsigned short*)d_ws;      // bufElems bf16
  unsigned short* B = A + bufElems;               // bufElems bf16
  int2*  pairs = (int2*)(B + bufElems);           // NNZC
  float* g     = (float*)(pairs + NNZC);          // GELEMS
  float* g_ue = g + 0 * (size_t)B64;
  float* g_pe = g + 1 * (size_t)B64;
  float* g_ne = g + 2 * (size_t)B64;
  float* g_u1 = g + 3 * (size_t)B64;
  float* g_i1 = g + 4 * (size_t)B64;
  float* g_u2 = g + 5 * (size_t)B64;
  float* g_i2 = g + 6 * (size_t)B64;
  float* ttl_u = g + 7 * (size_t)B64;
  float* ttl_i = ttl_u + BATCH;
  float* acc   = ttl_i + BATCH;       // 8 scalars
  int* rs     = (int*)(g + GELEMS);   // NTOT+1
  int* bsums  = rs + (NTOT + 1);      // 512

  // build-time scratch aliased into A+B region (36.9 MB < 76.8 MB available)
  int2* midp = (int2*)A;              // NNZC int2
  int*  midr = (int*)(midp + NNZC);   // NNZC int
  int*  Hcnt = midr + NNZC;           // NH
  int*  Hofs = Hcnt + NH;             // NH

  // only ttl_u/ttl_i/acc need zeroing (g_* written directly by hop2g)
  hipMemsetAsync(ttl_u, 0, (2 * BATCH + 8) * sizeof(float), stream);

  // ---- CSR build: bucket hist -> NH scan -> bin -> per-bucket place+rs ----
  partA<<<NCHUNK, 256, 0, stream>>>(adj_rows, Hcnt);
  const int nhb = (NH + SCAN_ELEMS - 1) / SCAN_ELEMS;
  scan_block<<<nhb, 256, 0, stream>>>(Hcnt, Hofs, bsums, NH);
  scan_sums<<<1, 512, 0, stream>>>(bsums, nhb);
  add_offsets<<<(NH + 255) / 256, 256, 0, stream>>>(Hofs, bsums, NH);
  partB<<<NCHUNK, 256, 0, stream>>>(adj_vals, adj_rows, adj_cols, Hofs, midp, midr);
  partC<<<NB, 256, 0, stream>>>(midp, midr, Hofs, rs, pairs);

  const int spmm_blocks = NTOT / 16;           // 18750
  dim3 h2g3(BATCH / 16, 3), h2g2(BATCH / 16, 2);

  // ---- branch 0 (clean) ----
  spmm_hop<false, true><<<spmm_blocks, 256, 0, stream>>>(
      pairs, rs, user_embed, item_embed, nullptr, A, 0u, 0u);   // hop0 -> A
  spmm_hop<false, false><<<spmm_blocks, 256, 0, stream>>>(
      pairs, rs, nullptr, nullptr, A, B, 0u, 0u);               // hop1 -> B
  hop2g<false, false><<<h2g3, 256, 0, stream>>>(
      pairs, rs, A, B, users, pos_items, neg_items,
      g_ue, g_pe, g_ne, 0, NUSERS, NUSERS, 0u);

  // ---- branch 1 (seed 101) ----
  perturb<false><<<spmm_blocks, 256, 0, stream>>>(A, 0u, 101u); // A = hop0 + n(101,0)
  spmm_hop<true, false><<<spmm_blocks, 256, 0, stream>>>(
      pairs, rs, nullptr, nullptr, A, B, 101u, 1u);             // hop1 + n(101,1)
  hop2g<true, true><<<h2g2, 256, 0, stream>>>(
      pairs, rs, A, B, users, pos_items, nullptr,
      g_u1, g_i1, nullptr, 0, NUSERS, 0, 101u);                 // + fused rownorm

  // ---- branch 2 (seed 202) ----
  perturb<true><<<spmm_blocks, 256, 0, stream>>>(A, 101u, 202u); // swap noise views
  spmm_hop<true, false><<<spmm_blocks, 256, 0, stream>>>(
      pairs, rs, nullptr, nullptr, A, B, 202u, 1u);
  hop2g<true, true><<<h2g2, 256, 0, stream>>>(
      pairs, rs, A, B, users, pos_items, nullptr,
      g_u2, g_i2, nullptr, 0, NUSERS, 0, 202u);                 // + fused rownorm

  // ---- losses ----
  rec_kernel<<<64, 256, 0, stream>>>(g_ue, g_pe, g_ne, acc);
  dim3 nce_grid(BATCH / IB, BATCH / JB, 2);
  nce_ttl<<<nce_grid, 256, 0, stream>>>(g_u1, g_u2, ttl_u, g_i1, g_i2, ttl_i);
  nce_final<<<64, 256, 0, stream>>>(g_u1, g_u2, ttl_u, acc + 3);
  nce_final<<<64, 256, 0, stream>>>(g_i1, g_i2, ttl_i, acc + 4);
  finalize_kernel<<<1, 1, 0, stream>>>(acc, out);
}